// Round 5
// baseline (485.170 us; speedup 1.0000x reference)
//
#include <hip/hip_runtime.h>
#include <hip/hip_bf16.h>

#define BN_EPS 1e-5
#define PB 256   // partition blocks for edge binning

typedef __attribute__((ext_vector_type(8))) short short8;
typedef __attribute__((ext_vector_type(4))) float floatx4;

// ---------------- bf16 helpers ----------------

__device__ __forceinline__ unsigned short f2bf(float f) {
    union { float f; unsigned u; } v; v.f = f;
    unsigned r = v.u + 0x7FFF + ((v.u >> 16) & 1);   // RNE
    return (unsigned short)(r >> 16);
}
__device__ __forceinline__ float bf2f(unsigned short h) {
    union { unsigned u; float f; } v; v.u = ((unsigned)h) << 16;
    return v.f;
}

// ---------------- scans ----------------

__global__ void scan1_kernel(const int* __restrict__ in, int* __restrict__ part,
                             int* __restrict__ bsum, int n) {
    __shared__ int s[1024];
    int t = threadIdx.x;
    int i = blockIdx.x * 1024 + t;
    int v = (i < n) ? in[i] : 0;
    s[t] = v;
    __syncthreads();
    for (int off = 1; off < 1024; off <<= 1) {
        int x = (t >= off) ? s[t - off] : 0;
        __syncthreads();
        s[t] += x;
        __syncthreads();
    }
    if (i < n) part[i] = s[t] - v;
    if (t == 1023) bsum[blockIdx.x] = s[1023];
}

__global__ void scan2_kernel(int* __restrict__ bsum, int nb) {
    __shared__ int s[64];
    int t = threadIdx.x;
    int v = (t < nb) ? bsum[t] : 0;
    s[t] = v;
    __syncthreads();
    for (int off = 1; off < 64; off <<= 1) {
        int x = (t >= off) ? s[t - off] : 0;
        __syncthreads();
        s[t] += x;
        __syncthreads();
    }
    if (t < nb) bsum[t] = s[t] - v;
}

__global__ void scan3_rowptr(int* __restrict__ rowptr, const int* __restrict__ bsum,
                             int n, int E) {
    int i = blockIdx.x * blockDim.x + threadIdx.x;
    if (i < n) rowptr[i] += bsum[i >> 10];
    if (i == 0) rowptr[n] = E;
}

__global__ void scan3_add(int* __restrict__ arr, const int* __restrict__ bsum, int n) {
    int i = blockIdx.x * blockDim.x + threadIdx.x;
    if (i < n) arr[i] += bsum[i >> 10];
}

// ---------------- ownership-based CSR build ----------------

__global__ void hist_kernel(const int* __restrict__ dst, int* __restrict__ hist,
                            int E, int cpb, int NB) {
    __shared__ int h[256];
    int t = threadIdx.x;
    if (t < NB) h[t] = 0;
    __syncthreads();
    int base = blockIdx.x * cpb;
    int end = base + cpb; if (end > E) end = E;
    int e = base + t * 4;
    for (; e + 3 < end; e += 1024) {
        int4 d = *(const int4*)(dst + e);
        atomicAdd(&h[d.x >> 8], 1);
        atomicAdd(&h[d.y >> 8], 1);
        atomicAdd(&h[d.z >> 8], 1);
        atomicAdd(&h[d.w >> 8], 1);
    }
    for (; e < end; ++e) atomicAdd(&h[dst[e] >> 8], 1);
    __syncthreads();
    if (t < NB) hist[t * PB + blockIdx.x] = h[t];
}

__global__ void scatter_kernel(const int* __restrict__ src, const int* __restrict__ dst,
                               const int* __restrict__ offs, unsigned* __restrict__ part,
                               int E, int cpb, int NB) {
    __shared__ int cur[256];
    int t = threadIdx.x;
    if (t < NB) cur[t] = offs[t * PB + blockIdx.x];
    __syncthreads();
    int base = blockIdx.x * cpb;
    int end = base + cpb; if (end > E) end = E;
    int e = base + t * 4;
    for (; e + 3 < end; e += 1024) {
        int4 d4 = *(const int4*)(dst + e);
        int4 s4 = *(const int4*)(src + e);
        int dd[4] = {d4.x, d4.y, d4.z, d4.w};
        int sv[4] = {s4.x, s4.y, s4.z, s4.w};
#pragma unroll
        for (int i = 0; i < 4; ++i) {
            int pos = atomicAdd(&cur[dd[i] >> 8], 1);
            part[pos] = ((unsigned)sv[i] << 8) | (unsigned)(dd[i] & 255);
        }
    }
    for (; e < end; ++e) {
        int d = dst[e];
        int pos = atomicAdd(&cur[d >> 8], 1);
        part[pos] = ((unsigned)src[e] << 8) | (unsigned)(d & 255);
    }
}

__global__ void bucket_count(const unsigned* __restrict__ part, const int* __restrict__ offs,
                             int* __restrict__ cnt, float* __restrict__ dinv,
                             int E, int N, int NB) {
    __shared__ int cw[256];
    int b = blockIdx.x;
    int t = threadIdx.x;
    cw[t] = 0;
    __syncthreads();
    int bstart = offs[b * PB];
    int bend = (b + 1 < NB) ? offs[(b + 1) * PB] : E;
    for (int e = bstart + t; e < bend; e += 256)
        atomicAdd(&cw[part[e] & 255u], 1);
    __syncthreads();
    int node = (b << 8) + t;
    if (node < N) {
        int c = cw[t];
        cnt[node] = c;
        dinv[node] = rsqrtf((float)(c + 1));   // +1 self loop
    }
}

__global__ void bucket_fill(const unsigned* __restrict__ part, const int* __restrict__ offs,
                            const int* __restrict__ rowptr, int* __restrict__ csr,
                            int E, int N, int NB) {
    __shared__ int cur[256];
    int b = blockIdx.x;
    int t = threadIdx.x;
    int node = (b << 8) + t;
    cur[t] = (node < N) ? rowptr[node] : 0;
    __syncthreads();
    int bstart = offs[b * PB];
    int bend = (b + 1 < NB) ? offs[(b + 1) * PB] : E;
    for (int e = bstart + t; e < bend; e += 256) {
        unsigned pr = part[e];
        int pos = atomicAdd(&cur[pr & 255u], 1);
        csr[pos] = (int)(pr >> 8);
    }
}

// ---------------- GCN pieces ----------------

// ys [2][N][32] slice-major bf16: ys[(p*N + r)*32 + c] = x[r][p*32+c] * dinv[r]
__global__ void prescale64_bf(const float* __restrict__ x, const float* __restrict__ dinv,
                              unsigned short* __restrict__ ys, int N) {
    int t = blockIdx.x * blockDim.x + threadIdx.x;
    int total = N * 8;
    if (t >= total) return;
    int r = t >> 3;
    int k = t & 7;
    float d = dinv[r];
    float4 a = ((const float4*)x)[t * 2];
    float4 b = ((const float4*)x)[t * 2 + 1];
    uint4 o;
    o.x = (unsigned)f2bf(a.x * d) | ((unsigned)f2bf(a.y * d) << 16);
    o.y = (unsigned)f2bf(a.z * d) | ((unsigned)f2bf(a.w * d) << 16);
    o.z = (unsigned)f2bf(b.x * d) | ((unsigned)f2bf(b.y * d) << 16);
    o.w = (unsigned)f2bf(b.z * d) | ((unsigned)f2bf(b.w * d) << 16);
    int p = k >> 2;
    unsigned short* dstp = ys + ((size_t)(p * N + r)) * 32 + (k & 3) * 8;
    *(uint4*)dstp = o;
}

// sliced aggregation: P passes of 32 channels; slice p resident in each XCD L2.
// Wave handles 2 nodes: lanes 0-31 -> node0, lanes 32-63 -> node1; ch = lane&31.
// out A16[node][C] at channel offset p*32 (node-major for the GEMM).
__global__ __launch_bounds__(256) void agg_sliced(
    const unsigned short* __restrict__ ys, const int* __restrict__ rowptr,
    const int* __restrict__ csr, const float* __restrict__ dinv,
    unsigned short* __restrict__ A16, int N, int C, int bpp) {
    int pass = blockIdx.x / bpp;
    int blk  = blockIdx.x - pass * bpp;
    int wv   = blk * 4 + (threadIdx.x >> 6);
    int lane = threadIdx.x & 63;
    int ch   = lane & 31;
    int node = wv * 2 + (lane >> 5);
    bool valid = node < N;
    int nd = valid ? node : N - 1;
    const unsigned short* yp = ys + (size_t)pass * N * 32;
    float acc = bf2f(yp[(size_t)nd * 32 + ch]);
    int b = rowptr[nd];
    int len = rowptr[nd + 1] - b;
    int lmax = max(len, __shfl(len, lane ^ 32));
    int j = 0;
    for (; j + 3 < lmax; j += 4) {
        int i0 = b + ((j + 0) < len ? (j + 0) : 0);
        int i1 = b + ((j + 1) < len ? (j + 1) : 0);
        int i2 = b + ((j + 2) < len ? (j + 2) : 0);
        int i3 = b + ((j + 3) < len ? (j + 3) : 0);
        int s0 = __builtin_nontemporal_load(csr + i0);
        int s1 = __builtin_nontemporal_load(csr + i1);
        int s2 = __builtin_nontemporal_load(csr + i2);
        int s3 = __builtin_nontemporal_load(csr + i3);
        float v0 = bf2f(yp[(size_t)s0 * 32 + ch]);
        float v1 = bf2f(yp[(size_t)s1 * 32 + ch]);
        float v2 = bf2f(yp[(size_t)s2 * 32 + ch]);
        float v3 = bf2f(yp[(size_t)s3 * 32 + ch]);
        acc += ((j + 0) < len ? v0 : 0.f) + ((j + 1) < len ? v1 : 0.f);
        acc += ((j + 2) < len ? v2 : 0.f) + ((j + 3) < len ? v3 : 0.f);
    }
    for (; j < lmax; ++j) {
        int i0 = b + (j < len ? j : 0);
        int s0 = __builtin_nontemporal_load(csr + i0);
        float v0 = bf2f(yp[(size_t)s0 * 32 + ch]);
        acc += (j < len ? v0 : 0.f);
    }
    if (valid) {
        unsigned short o = f2bf(acc * dinv[node]);
        __builtin_nontemporal_store(o, A16 + (size_t)node * C + pass * 32 + ch);
    }
}

// pack W[K][128] fp32 -> Wp[kb][c] = uint4 of 8 bf16 (k = kb*8+j)
__global__ void wpack_kernel(const float* __restrict__ W, uint4* __restrict__ Wp, int K) {
    int i = blockIdx.x * blockDim.x + threadIdx.x;
    int total = K * 16;
    if (i >= total) return;
    int c = i & 127;
    int kb = i >> 7;
    unsigned short h[8];
#pragma unroll
    for (int j = 0; j < 8; ++j) h[j] = f2bf(W[(size_t)(kb * 8 + j) * 128 + c]);
    uint4 o;
    o.x = (unsigned)h[0] | ((unsigned)h[1] << 16);
    o.y = (unsigned)h[2] | ((unsigned)h[3] << 16);
    o.z = (unsigned)h[4] | ((unsigned)h[5] << 16);
    o.w = (unsigned)h[6] | ((unsigned)h[7] << 16);
    Wp[kb * 128 + c] = o;
}

// MFMA GEMM: A16[N][K] bf16 @ Wp -> out[N][128] fp32 (no bias; BN absorbs it)
template <int K>
__global__ __launch_bounds__(256) void mfma_gemm(const unsigned short* __restrict__ A16,
                                                 const uint4* __restrict__ Bp,
                                                 float* __restrict__ out, int N) {
    constexpr int KS = K / 32;
    int w = threadIdx.x >> 6, l = threadIdx.x & 63;
    int cl = l & 15, sub = l >> 4;
    int r0 = blockIdx.x * 64 + w * 16;
    int ra = r0 + cl; if (ra > N - 1) ra = N - 1;

    short8 a[KS];
    const unsigned short* ap = A16 + (size_t)ra * K + sub * 8;
#pragma unroll
    for (int ks = 0; ks < KS; ++ks) a[ks] = *(const short8*)(ap + ks * 32);

    floatx4 acc[8] = {};
#pragma unroll
    for (int cb = 0; cb < 8; ++cb) {
#pragma unroll
        for (int ks = 0; ks < KS; ++ks) {
            short8 b = *(const short8*)&Bp[(ks * 4 + sub) * 128 + cb * 16 + cl];
            acc[cb] = __builtin_amdgcn_mfma_f32_16x16x32_bf16(a[ks], b, acc[cb], 0, 0, 0);
        }
    }
#pragma unroll
    for (int cb = 0; cb < 8; ++cb) {
#pragma unroll
        for (int j = 0; j < 4; ++j) {
            int row = r0 + sub * 4 + j;
            if (row < N) out[(size_t)row * 128 + cb * 16 + cl] = acc[cb][j];
        }
    }
}

// column sum / sumsq -> double accumulators st[0..C) and st[C..2C)
__global__ void colstats_kernel(const float* __restrict__ h, int N, int C, int logC,
                                double* __restrict__ st) {
    int c = threadIdx.x & (C - 1);
    int sub = threadIdx.x >> logC;
    int rpb = 256 >> logC;
    float s = 0.f, s2 = 0.f;
    for (int r = blockIdx.x * rpb + sub; r < N; r += gridDim.x * rpb) {
        float v = h[(size_t)r * C + c];
        s += v;
        s2 += v * v;
    }
    atomicAdd(&st[c], (double)s);
    atomicAdd(&st[C + c], (double)s2);
}

__global__ void bnfin_kernel(const double* __restrict__ st, const float* __restrict__ gamma,
                             const float* __restrict__ beta, float2* __restrict__ ss,
                             int N, int C) {
    int c = blockIdx.x * blockDim.x + threadIdx.x;
    if (c >= C) return;
    double mean = st[c] / N;
    double var = st[C + c] / N - mean * mean;
    float sc = (float)((double)gamma[c] / sqrt(var + BN_EPS));
    float sh = beta[c] - (float)mean * sc;
    ss[c] = make_float2(sc, sh);
}

// c16s [4][N][32] slice-major bf16 = bf16(relu(h*scale+shift) * dinv[row])
__global__ void normrelu_bf(const float* __restrict__ h, const float2* __restrict__ ss,
                            const float* __restrict__ dinv, unsigned short* __restrict__ c16s,
                            int N) {
    int t = blockIdx.x * blockDim.x + threadIdx.x;
    int total = N * 16;
    if (t >= total) return;
    int r = t >> 4;
    int k = t & 15;
    int j = k << 3;
    float d = dinv[r];
    float4 a = ((const float4*)h)[t * 2];
    float4 b = ((const float4*)h)[t * 2 + 1];
    float2 s0 = ss[j], s1 = ss[j + 1], s2 = ss[j + 2], s3 = ss[j + 3];
    float2 s4 = ss[j + 4], s5 = ss[j + 5], s6 = ss[j + 6], s7 = ss[j + 7];
    float v0 = fmaxf(a.x * s0.x + s0.y, 0.f) * d;
    float v1 = fmaxf(a.y * s1.x + s1.y, 0.f) * d;
    float v2 = fmaxf(a.z * s2.x + s2.y, 0.f) * d;
    float v3 = fmaxf(a.w * s3.x + s3.y, 0.f) * d;
    float v4 = fmaxf(b.x * s4.x + s4.y, 0.f) * d;
    float v5 = fmaxf(b.y * s5.x + s5.y, 0.f) * d;
    float v6 = fmaxf(b.z * s6.x + s6.y, 0.f) * d;
    float v7 = fmaxf(b.w * s7.x + s7.y, 0.f) * d;
    uint4 o;
    o.x = (unsigned)f2bf(v0) | ((unsigned)f2bf(v1) << 16);
    o.y = (unsigned)f2bf(v2) | ((unsigned)f2bf(v3) << 16);
    o.z = (unsigned)f2bf(v4) | ((unsigned)f2bf(v5) << 16);
    o.w = (unsigned)f2bf(v6) | ((unsigned)f2bf(v7) << 16);
    int p = k >> 2;
    unsigned short* dstp = c16s + ((size_t)(p * N + r)) * 32 + (k & 3) * 8;
    *(uint4*)dstp = o;
}

// out = relu(h*scale+shift), f32 (layer 2 output for pooling)
__global__ void normrelu_kernel(const float* __restrict__ h, const float2* __restrict__ ss,
                                float* __restrict__ out, int N, int C) {
    int qpr = C >> 2;
    int t = blockIdx.x * blockDim.x + threadIdx.x;
    int total = N * qpr;
    if (t >= total) return;
    int r = t / qpr;
    int j = (t - r * qpr) << 2;
    float4 v = ((const float4*)h)[t];
    float2 s0 = ss[j], s1 = ss[j + 1], s2 = ss[j + 2], s3 = ss[j + 3];
    v.x = fmaxf(v.x * s0.x + s0.y, 0.f);
    v.y = fmaxf(v.y * s1.x + s1.y, 0.f);
    v.z = fmaxf(v.z * s2.x + s2.y, 0.f);
    v.w = fmaxf(v.w * s3.x + s3.y, 0.f);
    ((float4*)out)[t] = v;
}

// graph boundaries from sorted batch
__global__ void bounds_kernel(const int* __restrict__ batch, int* __restrict__ gstart,
                              int N, int G) {
    int i = blockIdx.x * blockDim.x + threadIdx.x;
    if (i >= N) return;
    int bi = batch[i];
    int bp = (i == 0) ? -1 : batch[i - 1];
    for (int g = bp + 1; g <= bi; ++g) gstart[g] = i;
    if (i == N - 1) {
        for (int g = bi + 1; g <= G; ++g) gstart[g] = N;
    }
}

// per-graph mean over rows of h [N,128] -> pooled [G,128]
__global__ void pool_kernel(const float* __restrict__ h, const int* __restrict__ gstart,
                            float* __restrict__ pooled) {
    int g = blockIdx.x;
    int c = threadIdx.x;
    int b = gstart[g], e = gstart[g + 1];
    float acc = 0.f;
    for (int r = b; r < e; ++r) acc += h[(size_t)r * 128 + c];
    pooled[(size_t)g * 128 + c] = acc / fmaxf((float)(e - b), 1.0f);
}

// head gemm (fp32, small): A[N,K] @ W[K,C] + bias -> out[N,C]
template <int K>
__global__ __launch_bounds__(256) void gemm_bias_kernel(const float* __restrict__ A,
                                                        const float* __restrict__ W,
                                                        const float* __restrict__ bias,
                                                        float* __restrict__ out, int N, int C) {
    __shared__ float Wl[K * 128];
    const int ct = blockIdx.y << 7;
    for (int idx = threadIdx.x; idx < K * 128; idx += 256) {
        int kk = idx >> 7, cc = idx & 127;
        Wl[idx] = W[(size_t)kk * C + ct + cc];
    }
    __syncthreads();
    const int cq = (threadIdx.x & 31) << 2;
    const int rg = threadIdx.x >> 5;
    const int r0 = blockIdx.x * 32 + (rg << 2);

    const float* Ap[4];
#pragma unroll
    for (int i = 0; i < 4; ++i) {
        int r = r0 + i;
        Ap[i] = A + (size_t)(r < N ? r : 0) * K;
    }
    float acc[4][4] = {};
#pragma unroll 4
    for (int k = 0; k < K; ++k) {
        float a0 = Ap[0][k];
        float a1 = Ap[1][k];
        float a2 = Ap[2][k];
        float a3 = Ap[3][k];
        float4 w = *(const float4*)&Wl[k * 128 + cq];
        acc[0][0] += a0 * w.x; acc[0][1] += a0 * w.y; acc[0][2] += a0 * w.z; acc[0][3] += a0 * w.w;
        acc[1][0] += a1 * w.x; acc[1][1] += a1 * w.y; acc[1][2] += a1 * w.z; acc[1][3] += a1 * w.w;
        acc[2][0] += a2 * w.x; acc[2][1] += a2 * w.y; acc[2][2] += a2 * w.z; acc[2][3] += a2 * w.w;
        acc[3][0] += a3 * w.x; acc[3][1] += a3 * w.y; acc[3][2] += a3 * w.z; acc[3][3] += a3 * w.w;
    }
    float4 bv = *(const float4*)&bias[ct + cq];
#pragma unroll
    for (int i = 0; i < 4; ++i) {
        int r = r0 + i;
        if (r < N) {
            float4 o = make_float4(acc[i][0] + bv.x, acc[i][1] + bv.y,
                                   acc[i][2] + bv.z, acc[i][3] + bv.w);
            *(float4*)&out[(size_t)r * C + ct + cq] = o;
        }
    }
}

// final: out[g][j] = sum_c relu(bn(z))[g][c] * W4[c][j] + b4[j]
__global__ void head_kernel(const float* __restrict__ z, const float2* __restrict__ ss,
                            const float* __restrict__ W4, const float* __restrict__ b4,
                            float* __restrict__ out, int G) {
    __shared__ float zr[256];
    int g = blockIdx.x;
    int t = threadIdx.x;
    float v = z[(size_t)g * 256 + t];
    zr[t] = fmaxf(v * ss[t].x + ss[t].y, 0.f);
    __syncthreads();
    if (t < 10) {
        float acc = b4[t];
        for (int c = 0; c < 256; ++c) acc += zr[c] * W4[c * 10 + t];
        out[(size_t)g * 10 + t] = acc;
    }
}

// ---------------- launch ----------------

extern "C" void kernel_launch(void* const* d_in, const int* in_sizes, int n_in,
                              void* d_out, int out_size, void* d_ws, size_t ws_size,
                              hipStream_t stream) {
    const int N = in_sizes[0] / 64;
    const int E = in_sizes[1] / 2;
    const int G = out_size / 10;

    const float* x     = (const float*)d_in[0];
    const int*   ei    = (const int*)d_in[1];
    const int*   batch = (const int*)d_in[2];
    const float* W1 = (const float*)d_in[3];
    const float* g1 = (const float*)d_in[5];
    const float* be1 = (const float*)d_in[6];
    const float* W2 = (const float*)d_in[7];
    const float* g2 = (const float*)d_in[9];
    const float* be2 = (const float*)d_in[10];
    const float* W3 = (const float*)d_in[11];
    const float* b3 = (const float*)d_in[12];
    const float* g3 = (const float*)d_in[13];
    const float* be3 = (const float*)d_in[14];
    const float* W4 = (const float*)d_in[15];
    const float* b4 = (const float*)d_in[16];
    float* out = (float*)d_out;

    const int* srcp = ei;        // edge_index[0]
    const int* dstp = ei + E;    // edge_index[1]

    // workspace layout
    char* p = (char*)d_ws;
    auto alloc = [&](size_t bytes) {
        void* r = (void*)p;
        p += (bytes + 255) & ~(size_t)255;
        return r;
    };
    unsigned short* A16 = (unsigned short*)alloc((size_t)N * 128 * 2);
    float* Bb = (float*)alloc((size_t)N * 128 * 4);
    char* R3  = (char*)alloc((size_t)N * 128 * 4);   // c16s | y16s | later Cc f32
    int* csr      = (int*)alloc((size_t)E * 4);
    unsigned* part = (unsigned*)alloc((size_t)E * 4);
    int* cnt    = (int*)alloc((size_t)N * 4);
    int* rowptr = (int*)alloc((size_t)(N + 1) * 4);
    float* dinv = (float*)alloc((size_t)N * 4);
    int* hist   = (int*)alloc((size_t)256 * PB * 4);
    int* offs   = (int*)alloc((size_t)256 * PB * 4);
    int* bsums  = (int*)alloc(64 * 4);
    uint4* w1p  = (uint4*)alloc((size_t)64 * 128 * 2);
    uint4* w2p  = (uint4*)alloc((size_t)128 * 128 * 2);
    int* gstart = (int*)alloc((size_t)(G + 1) * 4);
    float* pooled = (float*)alloc((size_t)G * 128 * 4);
    float* z      = (float*)alloc((size_t)G * 256 * 4);
    double* st    = (double*)alloc(1024 * 8);
    float2* ss    = (float2*)alloc(512 * 8);
    (void)ws_size; (void)n_in;

    unsigned short* c16s = (unsigned short*)R3;                         // [4][N][32] bf16
    unsigned short* y16s = (unsigned short*)(R3 + (size_t)N * 128 * 2); // [2][N][32] bf16
    float* Cc = (float*)R3;                                             // [N*128] f32 (later)

    double* stA = st;
    double* stB = st + 256;
    double* stC = st + 512;
    float2* ssA = ss;
    float2* ssB = ss + 128;
    float2* ssC = ss + 256;

    hipMemsetAsync(st, 0, 1024 * 8, stream);

    const int nb = (N + 255) / 256;
    const int nchunks = (N + 1023) / 1024;
    const int NB = (N + 255) >> 8;
    const int cpb = (((E + PB - 1) / PB) + 3) & ~3;
    const int n2 = NB * PB;
    const int nch2 = (n2 + 1023) / 1024;
    const int bpp = ((N + 1) / 2 + 3) / 4;   // blocks per agg pass (4 waves/block, 2 nodes/wave)

    // weight packing (independent)
    wpack_kernel<<<4, 256, 0, stream>>>(W1, w1p, 64);
    wpack_kernel<<<8, 256, 0, stream>>>(W2, w2p, 128);

    // partition edges by dst bucket (no global atomics)
    hist_kernel<<<PB, 256, 0, stream>>>(dstp, hist, E, cpb, NB);
    scan1_kernel<<<nch2, 1024, 0, stream>>>(hist, offs, bsums, n2);
    scan2_kernel<<<1, 64, 0, stream>>>(bsums, nch2);
    scan3_add<<<(n2 + 255) / 256, 256, 0, stream>>>(offs, bsums, n2);
    scatter_kernel<<<PB, 256, 0, stream>>>(srcp, dstp, offs, part, E, cpb, NB);

    // degrees + dinv from partition
    bucket_count<<<NB, 256, 0, stream>>>(part, offs, cnt, dinv, E, N, NB);

    // rowptr = exscan(cnt), then CSR fill
    scan1_kernel<<<nchunks, 1024, 0, stream>>>(cnt, rowptr, bsums, N);
    scan2_kernel<<<1, 64, 0, stream>>>(bsums, nchunks);
    scan3_rowptr<<<nb, 256, 0, stream>>>(rowptr, bsums, N, E);
    bucket_fill<<<NB, 256, 0, stream>>>(part, offs, rowptr, csr, E, N, NB);

    // Layer 1: slice-major prescale, 2-pass sliced agg, MFMA gemm
    prescale64_bf<<<(N * 8 + 255) / 256, 256, 0, stream>>>(x, dinv, y16s, N);
    agg_sliced<<<bpp * 2, 256, 0, stream>>>(y16s, rowptr, csr, dinv, A16, N, 64, bpp);
    mfma_gemm<64><<<(N + 63) / 64, 256, 0, stream>>>(A16, w1p, Bb, N);
    colstats_kernel<<<128, 256, 0, stream>>>(Bb, N, 128, 7, stA);
    bnfin_kernel<<<1, 128, 0, stream>>>(stA, g1, be1, ssA, N, 128);
    normrelu_bf<<<(N * 16 + 255) / 256, 256, 0, stream>>>(Bb, ssA, dinv, c16s, N);

    // Layer 2: 4-pass sliced agg, MFMA gemm
    agg_sliced<<<bpp * 4, 256, 0, stream>>>(c16s, rowptr, csr, dinv, A16, N, 128, bpp);
    mfma_gemm<128><<<(N + 63) / 64, 256, 0, stream>>>(A16, w2p, Bb, N);
    colstats_kernel<<<128, 256, 0, stream>>>(Bb, N, 128, 7, stB);
    bnfin_kernel<<<1, 128, 0, stream>>>(stB, g2, be2, ssB, N, 128);
    normrelu_kernel<<<(N * 32 + 255) / 256, 256, 0, stream>>>(Bb, ssB, Cc, N, 128);

    // Pool
    bounds_kernel<<<nb, 256, 0, stream>>>(batch, gstart, N, G);
    pool_kernel<<<G, 128, 0, stream>>>(Cc, gstart, pooled);

    // Head
    gemm_bias_kernel<128><<<dim3((G + 31) / 32, 2), 256, 0, stream>>>(pooled, W3, b3, z, G, 256);
    colstats_kernel<<<64, 256, 0, stream>>>(z, G, 256, 8, stC);
    bnfin_kernel<<<1, 256, 0, stream>>>(stC, g3, be3, ssC, G, 256);
    head_kernel<<<G, 256, 0, stream>>>(z, ssC, W4, b4, out, G);
}

// Round 6
// 313.050 us; speedup vs baseline: 1.5498x; 1.5498x over previous
//
#include <hip/hip_runtime.h>
#include <hip/hip_bf16.h>

#define BN_EPS 1e-5
#define PB 256   // partition blocks for edge binning

typedef __attribute__((ext_vector_type(8))) short short8;
typedef __attribute__((ext_vector_type(4))) float floatx4;

// ---------------- bf16 helpers ----------------

__device__ __forceinline__ unsigned short f2bf(float f) {
    union { float f; unsigned u; } v; v.f = f;
    unsigned r = v.u + 0x7FFF + ((v.u >> 16) & 1);   // RNE
    return (unsigned short)(r >> 16);
}
__device__ __forceinline__ float bf2f(unsigned short h) {
    union { unsigned u; float f; } v; v.u = ((unsigned)h) << 16;
    return v.f;
}

// ---------------- scans ----------------

__global__ void scan1_kernel(const int* __restrict__ in, int* __restrict__ part,
                             int* __restrict__ bsum, int n) {
    __shared__ int s[1024];
    int t = threadIdx.x;
    int i = blockIdx.x * 1024 + t;
    int v = (i < n) ? in[i] : 0;
    s[t] = v;
    __syncthreads();
    for (int off = 1; off < 1024; off <<= 1) {
        int x = (t >= off) ? s[t - off] : 0;
        __syncthreads();
        s[t] += x;
        __syncthreads();
    }
    if (i < n) part[i] = s[t] - v;
    if (t == 1023) bsum[blockIdx.x] = s[1023];
}

__global__ void scan2_kernel(int* __restrict__ bsum, int nb) {
    __shared__ int s[64];
    int t = threadIdx.x;
    int v = (t < nb) ? bsum[t] : 0;
    s[t] = v;
    __syncthreads();
    for (int off = 1; off < 64; off <<= 1) {
        int x = (t >= off) ? s[t - off] : 0;
        __syncthreads();
        s[t] += x;
        __syncthreads();
    }
    if (t < nb) bsum[t] = s[t] - v;
}

__global__ void scan3_rowptr(int* __restrict__ rowptr, const int* __restrict__ bsum,
                             int n, int E) {
    int i = blockIdx.x * blockDim.x + threadIdx.x;
    if (i < n) rowptr[i] += bsum[i >> 10];
    if (i == 0) rowptr[n] = E;
}

__global__ void scan3_add(int* __restrict__ arr, const int* __restrict__ bsum, int n) {
    int i = blockIdx.x * blockDim.x + threadIdx.x;
    if (i < n) arr[i] += bsum[i >> 10];
}

// ---------------- ownership-based CSR build ----------------

__global__ void hist_kernel(const int* __restrict__ dst, int* __restrict__ hist,
                            int E, int cpb, int NB) {
    __shared__ int h[256];
    int t = threadIdx.x;
    if (t < NB) h[t] = 0;
    __syncthreads();
    int base = blockIdx.x * cpb;
    int end = base + cpb; if (end > E) end = E;
    int e = base + t * 4;
    for (; e + 3 < end; e += 1024) {
        int4 d = *(const int4*)(dst + e);
        atomicAdd(&h[d.x >> 8], 1);
        atomicAdd(&h[d.y >> 8], 1);
        atomicAdd(&h[d.z >> 8], 1);
        atomicAdd(&h[d.w >> 8], 1);
    }
    for (; e < end; ++e) atomicAdd(&h[dst[e] >> 8], 1);
    __syncthreads();
    if (t < NB) hist[t * PB + blockIdx.x] = h[t];
}

__global__ void scatter_kernel(const int* __restrict__ src, const int* __restrict__ dst,
                               const int* __restrict__ offs, unsigned* __restrict__ part,
                               int E, int cpb, int NB) {
    __shared__ int cur[256];
    int t = threadIdx.x;
    if (t < NB) cur[t] = offs[t * PB + blockIdx.x];
    __syncthreads();
    int base = blockIdx.x * cpb;
    int end = base + cpb; if (end > E) end = E;
    int e = base + t * 4;
    for (; e + 3 < end; e += 1024) {
        int4 d4 = *(const int4*)(dst + e);
        int4 s4 = *(const int4*)(src + e);
        int dd[4] = {d4.x, d4.y, d4.z, d4.w};
        int sv[4] = {s4.x, s4.y, s4.z, s4.w};
#pragma unroll
        for (int i = 0; i < 4; ++i) {
            int pos = atomicAdd(&cur[dd[i] >> 8], 1);
            part[pos] = ((unsigned)sv[i] << 8) | (unsigned)(dd[i] & 255);
        }
    }
    for (; e < end; ++e) {
        int d = dst[e];
        int pos = atomicAdd(&cur[d >> 8], 1);
        part[pos] = ((unsigned)src[e] << 8) | (unsigned)(d & 255);
    }
}

__global__ void bucket_count(const unsigned* __restrict__ part, const int* __restrict__ offs,
                             int* __restrict__ cnt, float* __restrict__ dinv,
                             int E, int N, int NB) {
    __shared__ int cw[256];
    int b = blockIdx.x;
    int t = threadIdx.x;
    cw[t] = 0;
    __syncthreads();
    int bstart = offs[b * PB];
    int bend = (b + 1 < NB) ? offs[(b + 1) * PB] : E;
    for (int e = bstart + t; e < bend; e += 256)
        atomicAdd(&cw[part[e] & 255u], 1);
    __syncthreads();
    int node = (b << 8) + t;
    if (node < N) {
        int c = cw[t];
        cnt[node] = c;
        dinv[node] = rsqrtf((float)(c + 1));   // +1 self loop
    }
}

__global__ void bucket_fill(const unsigned* __restrict__ part, const int* __restrict__ offs,
                            const int* __restrict__ rowptr, int* __restrict__ csr,
                            int E, int N, int NB) {
    __shared__ int cur[256];
    int b = blockIdx.x;
    int t = threadIdx.x;
    int node = (b << 8) + t;
    cur[t] = (node < N) ? rowptr[node] : 0;
    __syncthreads();
    int bstart = offs[b * PB];
    int bend = (b + 1 < NB) ? offs[(b + 1) * PB] : E;
    for (int e = bstart + t; e < bend; e += 256) {
        unsigned pr = part[e];
        int pos = atomicAdd(&cur[pr & 255u], 1);
        csr[pos] = (int)(pr >> 8);
    }
}

// ---------------- GCN pieces ----------------

// y16[v][c] = bf16(x[v][c] * dinv[v]), C=64
__global__ void prescale64_bf(const float* __restrict__ x, const float* __restrict__ dinv,
                              unsigned short* __restrict__ y, int N) {
    int t = blockIdx.x * blockDim.x + threadIdx.x;
    int total = N * 8;
    if (t >= total) return;
    int r = t >> 3;
    float d = dinv[r];
    float4 a = ((const float4*)x)[t * 2];
    float4 b = ((const float4*)x)[t * 2 + 1];
    uint4 o;
    o.x = (unsigned)f2bf(a.x * d) | ((unsigned)f2bf(a.y * d) << 16);
    o.y = (unsigned)f2bf(a.z * d) | ((unsigned)f2bf(a.w * d) << 16);
    o.z = (unsigned)f2bf(b.x * d) | ((unsigned)f2bf(b.y * d) << 16);
    o.w = (unsigned)f2bf(b.z * d) | ((unsigned)f2bf(b.w * d) << 16);
    ((uint4*)y)[t] = o;
}

// one wave per node, 64 ch, unroll-8: A16[v] = bf16(dinv[v]*(y[v] + sum y[src]))
__global__ void agg64_bf(const unsigned short* __restrict__ y, const int* __restrict__ rowptr,
                         const int* __restrict__ csr, const float* __restrict__ dinv,
                         unsigned short* __restrict__ A16, int N) {
    int wid = (blockIdx.x * blockDim.x + threadIdx.x) >> 6;
    int lane = threadIdx.x & 63;
    if (wid >= N) return;
    float acc = bf2f(y[(size_t)wid * 64 + lane]);
    int b = rowptr[wid], e = rowptr[wid + 1];
    int i = b;
    for (; i + 7 < e; i += 8) {
        int s0 = csr[i], s1 = csr[i + 1], s2 = csr[i + 2], s3 = csr[i + 3];
        int s4 = csr[i + 4], s5 = csr[i + 5], s6 = csr[i + 6], s7 = csr[i + 7];
        float v0 = bf2f(y[(size_t)s0 * 64 + lane]);
        float v1 = bf2f(y[(size_t)s1 * 64 + lane]);
        float v2 = bf2f(y[(size_t)s2 * 64 + lane]);
        float v3 = bf2f(y[(size_t)s3 * 64 + lane]);
        float v4 = bf2f(y[(size_t)s4 * 64 + lane]);
        float v5 = bf2f(y[(size_t)s5 * 64 + lane]);
        float v6 = bf2f(y[(size_t)s6 * 64 + lane]);
        float v7 = bf2f(y[(size_t)s7 * 64 + lane]);
        acc += ((v0 + v1) + (v2 + v3)) + ((v4 + v5) + (v6 + v7));
    }
    for (; i + 3 < e; i += 4) {
        int s0 = csr[i], s1 = csr[i + 1], s2 = csr[i + 2], s3 = csr[i + 3];
        float v0 = bf2f(y[(size_t)s0 * 64 + lane]);
        float v1 = bf2f(y[(size_t)s1 * 64 + lane]);
        float v2 = bf2f(y[(size_t)s2 * 64 + lane]);
        float v3 = bf2f(y[(size_t)s3 * 64 + lane]);
        acc += (v0 + v1) + (v2 + v3);
    }
    for (; i < e; ++i) acc += bf2f(y[(size_t)csr[i] * 64 + lane]);
    A16[(size_t)wid * 64 + lane] = f2bf(acc * dinv[wid]);
}

// one wave per node, 128 ch (2 bf16 = 1 uint per lane), unroll-8
__global__ void agg128_bf(const unsigned short* __restrict__ y, const int* __restrict__ rowptr,
                          const int* __restrict__ csr, const float* __restrict__ dinv,
                          unsigned short* __restrict__ A16, int N) {
    int wid = (blockIdx.x * blockDim.x + threadIdx.x) >> 6;
    int lane = threadIdx.x & 63;
    if (wid >= N) return;
    const unsigned* yp = (const unsigned*)y;
    unsigned v = yp[(size_t)wid * 64 + lane];
    float ax = bf2f((unsigned short)(v & 0xffff));
    float ay = bf2f((unsigned short)(v >> 16));
    int b = rowptr[wid], e = rowptr[wid + 1];
    int i = b;
    for (; i + 7 < e; i += 8) {
        int s0 = csr[i], s1 = csr[i + 1], s2 = csr[i + 2], s3 = csr[i + 3];
        int s4 = csr[i + 4], s5 = csr[i + 5], s6 = csr[i + 6], s7 = csr[i + 7];
        unsigned v0 = yp[(size_t)s0 * 64 + lane];
        unsigned v1 = yp[(size_t)s1 * 64 + lane];
        unsigned v2 = yp[(size_t)s2 * 64 + lane];
        unsigned v3 = yp[(size_t)s3 * 64 + lane];
        unsigned v4 = yp[(size_t)s4 * 64 + lane];
        unsigned v5 = yp[(size_t)s5 * 64 + lane];
        unsigned v6 = yp[(size_t)s6 * 64 + lane];
        unsigned v7 = yp[(size_t)s7 * 64 + lane];
        ax += ((bf2f((unsigned short)(v0 & 0xffff)) + bf2f((unsigned short)(v1 & 0xffff)))
             + (bf2f((unsigned short)(v2 & 0xffff)) + bf2f((unsigned short)(v3 & 0xffff))))
            + ((bf2f((unsigned short)(v4 & 0xffff)) + bf2f((unsigned short)(v5 & 0xffff)))
             + (bf2f((unsigned short)(v6 & 0xffff)) + bf2f((unsigned short)(v7 & 0xffff))));
        ay += ((bf2f((unsigned short)(v0 >> 16)) + bf2f((unsigned short)(v1 >> 16)))
             + (bf2f((unsigned short)(v2 >> 16)) + bf2f((unsigned short)(v3 >> 16))))
            + ((bf2f((unsigned short)(v4 >> 16)) + bf2f((unsigned short)(v5 >> 16)))
             + (bf2f((unsigned short)(v6 >> 16)) + bf2f((unsigned short)(v7 >> 16))));
    }
    for (; i + 3 < e; i += 4) {
        int s0 = csr[i], s1 = csr[i + 1], s2 = csr[i + 2], s3 = csr[i + 3];
        unsigned v0 = yp[(size_t)s0 * 64 + lane];
        unsigned v1 = yp[(size_t)s1 * 64 + lane];
        unsigned v2 = yp[(size_t)s2 * 64 + lane];
        unsigned v3 = yp[(size_t)s3 * 64 + lane];
        ax += (bf2f((unsigned short)(v0 & 0xffff)) + bf2f((unsigned short)(v1 & 0xffff)))
            + (bf2f((unsigned short)(v2 & 0xffff)) + bf2f((unsigned short)(v3 & 0xffff)));
        ay += (bf2f((unsigned short)(v0 >> 16)) + bf2f((unsigned short)(v1 >> 16)))
            + (bf2f((unsigned short)(v2 >> 16)) + bf2f((unsigned short)(v3 >> 16)));
    }
    for (; i < e; ++i) {
        unsigned v0 = yp[(size_t)csr[i] * 64 + lane];
        ax += bf2f((unsigned short)(v0 & 0xffff));
        ay += bf2f((unsigned short)(v0 >> 16));
    }
    float d = dinv[wid];
    ((unsigned*)A16)[(size_t)wid * 64 + lane] =
        (unsigned)f2bf(ax * d) | ((unsigned)f2bf(ay * d) << 16);
}

// pack W[K][128] fp32 -> Wp[kb][c] = uint4 of 8 bf16 (k = kb*8+j)
__global__ void wpack_kernel(const float* __restrict__ W, uint4* __restrict__ Wp, int K) {
    int i = blockIdx.x * blockDim.x + threadIdx.x;
    int total = K * 16;
    if (i >= total) return;
    int c = i & 127;
    int kb = i >> 7;
    unsigned short h[8];
#pragma unroll
    for (int j = 0; j < 8; ++j) h[j] = f2bf(W[(size_t)(kb * 8 + j) * 128 + c]);
    uint4 o;
    o.x = (unsigned)h[0] | ((unsigned)h[1] << 16);
    o.y = (unsigned)h[2] | ((unsigned)h[3] << 16);
    o.z = (unsigned)h[4] | ((unsigned)h[5] << 16);
    o.w = (unsigned)h[6] | ((unsigned)h[7] << 16);
    Wp[kb * 128 + c] = o;
}

// MFMA GEMM: A16[N][K] bf16 @ Wp -> out[N][128] fp32 (no bias; BN absorbs it)
template <int K>
__global__ __launch_bounds__(256) void mfma_gemm(const unsigned short* __restrict__ A16,
                                                 const uint4* __restrict__ Bp,
                                                 float* __restrict__ out, int N) {
    constexpr int KS = K / 32;
    int w = threadIdx.x >> 6, l = threadIdx.x & 63;
    int cl = l & 15, sub = l >> 4;
    int r0 = blockIdx.x * 64 + w * 16;
    int ra = r0 + cl; if (ra > N - 1) ra = N - 1;

    short8 a[KS];
    const unsigned short* ap = A16 + (size_t)ra * K + sub * 8;
#pragma unroll
    for (int ks = 0; ks < KS; ++ks) a[ks] = *(const short8*)(ap + ks * 32);

    floatx4 acc[8] = {};
#pragma unroll
    for (int cb = 0; cb < 8; ++cb) {
#pragma unroll
        for (int ks = 0; ks < KS; ++ks) {
            short8 b = *(const short8*)&Bp[(ks * 4 + sub) * 128 + cb * 16 + cl];
            acc[cb] = __builtin_amdgcn_mfma_f32_16x16x32_bf16(a[ks], b, acc[cb], 0, 0, 0);
        }
    }
#pragma unroll
    for (int cb = 0; cb < 8; ++cb) {
#pragma unroll
        for (int j = 0; j < 4; ++j) {
            int row = r0 + sub * 4 + j;
            if (row < N) out[(size_t)row * 128 + cb * 16 + cl] = acc[cb][j];
        }
    }
}

// C=128 column sum/sumsq, 512 blocks, LDS block-reduce, one double-atomic/col/block
__global__ __launch_bounds__(256) void colstats128(const float* __restrict__ h, int N,
                                                   double* __restrict__ st) {
    __shared__ float ls[2][128], ls2[2][128];
    int c = threadIdx.x & 127;
    int sub = threadIdx.x >> 7;     // 0..1
    float s = 0.f, s2 = 0.f;
    for (int r = blockIdx.x * 2 + sub; r < N; r += gridDim.x * 2) {
        float v = h[(size_t)r * 128 + c];
        s += v;
        s2 += v * v;
    }
    ls[sub][c] = s;
    ls2[sub][c] = s2;
    __syncthreads();
    if (threadIdx.x < 128) {
        int cc = threadIdx.x;
        atomicAdd(&st[cc], (double)(ls[0][cc] + ls[1][cc]));
        atomicAdd(&st[128 + cc], (double)(ls2[0][cc] + ls2[1][cc]));
    }
}

// generic colstats (head, C=256)
__global__ void colstats_kernel(const float* __restrict__ h, int N, int C, int logC,
                                double* __restrict__ st) {
    int c = threadIdx.x & (C - 1);
    int sub = threadIdx.x >> logC;
    int rpb = 256 >> logC;
    float s = 0.f, s2 = 0.f;
    for (int r = blockIdx.x * rpb + sub; r < N; r += gridDim.x * rpb) {
        float v = h[(size_t)r * C + c];
        s += v;
        s2 += v * v;
    }
    atomicAdd(&st[c], (double)s);
    atomicAdd(&st[C + c], (double)s2);
}

__global__ void bnfin_kernel(const double* __restrict__ st, const float* __restrict__ gamma,
                             const float* __restrict__ beta, float2* __restrict__ ss,
                             int N, int C) {
    int c = blockIdx.x * blockDim.x + threadIdx.x;
    if (c >= C) return;
    double mean = st[c] / N;
    double var = st[C + c] / N - mean * mean;
    float sc = (float)((double)gamma[c] / sqrt(var + BN_EPS));
    float sh = beta[c] - (float)mean * sc;
    ss[c] = make_float2(sc, sh);
}

// out16 = bf16(relu(h*scale+shift) * dinv[row]), C=128
__global__ void normrelu_bf(const float* __restrict__ h, const float2* __restrict__ ss,
                            const float* __restrict__ dinv, unsigned short* __restrict__ out,
                            int N) {
    int t = blockIdx.x * blockDim.x + threadIdx.x;
    int total = N * 16;
    if (t >= total) return;
    int r = t >> 4;
    int j = (t & 15) << 3;
    float d = dinv[r];
    float4 a = ((const float4*)h)[t * 2];
    float4 b = ((const float4*)h)[t * 2 + 1];
    float2 s0 = ss[j], s1 = ss[j + 1], s2 = ss[j + 2], s3 = ss[j + 3];
    float2 s4 = ss[j + 4], s5 = ss[j + 5], s6 = ss[j + 6], s7 = ss[j + 7];
    float v0 = fmaxf(a.x * s0.x + s0.y, 0.f) * d;
    float v1 = fmaxf(a.y * s1.x + s1.y, 0.f) * d;
    float v2 = fmaxf(a.z * s2.x + s2.y, 0.f) * d;
    float v3 = fmaxf(a.w * s3.x + s3.y, 0.f) * d;
    float v4 = fmaxf(b.x * s4.x + s4.y, 0.f) * d;
    float v5 = fmaxf(b.y * s5.x + s5.y, 0.f) * d;
    float v6 = fmaxf(b.z * s6.x + s6.y, 0.f) * d;
    float v7 = fmaxf(b.w * s7.x + s7.y, 0.f) * d;
    uint4 o;
    o.x = (unsigned)f2bf(v0) | ((unsigned)f2bf(v1) << 16);
    o.y = (unsigned)f2bf(v2) | ((unsigned)f2bf(v3) << 16);
    o.z = (unsigned)f2bf(v4) | ((unsigned)f2bf(v5) << 16);
    o.w = (unsigned)f2bf(v6) | ((unsigned)f2bf(v7) << 16);
    ((uint4*)out)[t] = o;
}

// out = relu(h*scale+shift), f32 (layer 2 output for pooling)
__global__ void normrelu_kernel(const float* __restrict__ h, const float2* __restrict__ ss,
                                float* __restrict__ out, int N, int C) {
    int qpr = C >> 2;
    int t = blockIdx.x * blockDim.x + threadIdx.x;
    int total = N * qpr;
    if (t >= total) return;
    int r = t / qpr;
    int j = (t - r * qpr) << 2;
    float4 v = ((const float4*)h)[t];
    float2 s0 = ss[j], s1 = ss[j + 1], s2 = ss[j + 2], s3 = ss[j + 3];
    v.x = fmaxf(v.x * s0.x + s0.y, 0.f);
    v.y = fmaxf(v.y * s1.x + s1.y, 0.f);
    v.z = fmaxf(v.z * s2.x + s2.y, 0.f);
    v.w = fmaxf(v.w * s3.x + s3.y, 0.f);
    ((float4*)out)[t] = v;
}

// graph boundaries from sorted batch
__global__ void bounds_kernel(const int* __restrict__ batch, int* __restrict__ gstart,
                              int N, int G) {
    int i = blockIdx.x * blockDim.x + threadIdx.x;
    if (i >= N) return;
    int bi = batch[i];
    int bp = (i == 0) ? -1 : batch[i - 1];
    for (int g = bp + 1; g <= bi; ++g) gstart[g] = i;
    if (i == N - 1) {
        for (int g = bi + 1; g <= G; ++g) gstart[g] = N;
    }
}

// per-graph mean over rows of h [N,128] -> pooled [G,128]
__global__ void pool_kernel(const float* __restrict__ h, const int* __restrict__ gstart,
                            float* __restrict__ pooled) {
    int g = blockIdx.x;
    int c = threadIdx.x;
    int b = gstart[g], e = gstart[g + 1];
    float acc = 0.f;
    for (int r = b; r < e; ++r) acc += h[(size_t)r * 128 + c];
    pooled[(size_t)g * 128 + c] = acc / fmaxf((float)(e - b), 1.0f);
}

// head gemm (fp32, small): A[N,K] @ W[K,C] + bias -> out[N,C]
template <int K>
__global__ __launch_bounds__(256) void gemm_bias_kernel(const float* __restrict__ A,
                                                        const float* __restrict__ W,
                                                        const float* __restrict__ bias,
                                                        float* __restrict__ out, int N, int C) {
    __shared__ float Wl[K * 128];
    const int ct = blockIdx.y << 7;
    for (int idx = threadIdx.x; idx < K * 128; idx += 256) {
        int kk = idx >> 7, cc = idx & 127;
        Wl[idx] = W[(size_t)kk * C + ct + cc];
    }
    __syncthreads();
    const int cq = (threadIdx.x & 31) << 2;
    const int rg = threadIdx.x >> 5;
    const int r0 = blockIdx.x * 32 + (rg << 2);

    const float* Ap[4];
#pragma unroll
    for (int i = 0; i < 4; ++i) {
        int r = r0 + i;
        Ap[i] = A + (size_t)(r < N ? r : 0) * K;
    }
    float acc[4][4] = {};
#pragma unroll 4
    for (int k = 0; k < K; ++k) {
        float a0 = Ap[0][k];
        float a1 = Ap[1][k];
        float a2 = Ap[2][k];
        float a3 = Ap[3][k];
        float4 w = *(const float4*)&Wl[k * 128 + cq];
        acc[0][0] += a0 * w.x; acc[0][1] += a0 * w.y; acc[0][2] += a0 * w.z; acc[0][3] += a0 * w.w;
        acc[1][0] += a1 * w.x; acc[1][1] += a1 * w.y; acc[1][2] += a1 * w.z; acc[1][3] += a1 * w.w;
        acc[2][0] += a2 * w.x; acc[2][1] += a2 * w.y; acc[2][2] += a2 * w.z; acc[2][3] += a2 * w.w;
        acc[3][0] += a3 * w.x; acc[3][1] += a3 * w.y; acc[3][2] += a3 * w.z; acc[3][3] += a3 * w.w;
    }
    float4 bv = *(const float4*)&bias[ct + cq];
#pragma unroll
    for (int i = 0; i < 4; ++i) {
        int r = r0 + i;
        if (r < N) {
            float4 o = make_float4(acc[i][0] + bv.x, acc[i][1] + bv.y,
                                   acc[i][2] + bv.z, acc[i][3] + bv.w);
            *(float4*)&out[(size_t)r * C + ct + cq] = o;
        }
    }
}

// final: out[g][j] = sum_c relu(bn(z))[g][c] * W4[c][j] + b4[j]
__global__ void head_kernel(const float* __restrict__ z, const float2* __restrict__ ss,
                            const float* __restrict__ W4, const float* __restrict__ b4,
                            float* __restrict__ out, int G) {
    __shared__ float zr[256];
    int g = blockIdx.x;
    int t = threadIdx.x;
    float v = z[(size_t)g * 256 + t];
    zr[t] = fmaxf(v * ss[t].x + ss[t].y, 0.f);
    __syncthreads();
    if (t < 10) {
        float acc = b4[t];
        for (int c = 0; c < 256; ++c) acc += zr[c] * W4[c * 10 + t];
        out[(size_t)g * 10 + t] = acc;
    }
}

// ---------------- launch ----------------

extern "C" void kernel_launch(void* const* d_in, const int* in_sizes, int n_in,
                              void* d_out, int out_size, void* d_ws, size_t ws_size,
                              hipStream_t stream) {
    const int N = in_sizes[0] / 64;
    const int E = in_sizes[1] / 2;
    const int G = out_size / 10;

    const float* x     = (const float*)d_in[0];
    const int*   ei    = (const int*)d_in[1];
    const int*   batch = (const int*)d_in[2];
    const float* W1 = (const float*)d_in[3];
    const float* g1 = (const float*)d_in[5];
    const float* be1 = (const float*)d_in[6];
    const float* W2 = (const float*)d_in[7];
    const float* g2 = (const float*)d_in[9];
    const float* be2 = (const float*)d_in[10];
    const float* W3 = (const float*)d_in[11];
    const float* b3 = (const float*)d_in[12];
    const float* g3 = (const float*)d_in[13];
    const float* be3 = (const float*)d_in[14];
    const float* W4 = (const float*)d_in[15];
    const float* b4 = (const float*)d_in[16];
    float* out = (float*)d_out;

    const int* srcp = ei;        // edge_index[0]
    const int* dstp = ei + E;    // edge_index[1]

    // workspace layout
    char* p = (char*)d_ws;
    auto alloc = [&](size_t bytes) {
        void* r = (void*)p;
        p += (bytes + 255) & ~(size_t)255;
        return r;
    };
    unsigned short* A16 = (unsigned short*)alloc((size_t)N * 128 * 2);
    float* Bb = (float*)alloc((size_t)N * 128 * 4);
    char* R3  = (char*)alloc((size_t)N * 128 * 4);   // c16 | y16 | later Cc f32
    int* csr      = (int*)alloc((size_t)E * 4);
    unsigned* part = (unsigned*)alloc((size_t)E * 4);
    int* cnt    = (int*)alloc((size_t)N * 4);
    int* rowptr = (int*)alloc((size_t)(N + 1) * 4);
    float* dinv = (float*)alloc((size_t)N * 4);
    int* hist   = (int*)alloc((size_t)256 * PB * 4);
    int* offs   = (int*)alloc((size_t)256 * PB * 4);
    int* bsums  = (int*)alloc(64 * 4);
    uint4* w1p  = (uint4*)alloc((size_t)64 * 128 * 2);
    uint4* w2p  = (uint4*)alloc((size_t)128 * 128 * 2);
    int* gstart = (int*)alloc((size_t)(G + 1) * 4);
    float* pooled = (float*)alloc((size_t)G * 128 * 4);
    float* z      = (float*)alloc((size_t)G * 256 * 4);
    double* st    = (double*)alloc(1024 * 8);
    float2* ss    = (float2*)alloc(512 * 8);
    (void)ws_size; (void)n_in;

    unsigned short* c16 = (unsigned short*)R3;                         // [N*128] bf16
    unsigned short* y16 = (unsigned short*)(R3 + (size_t)N * 128 * 2); // [N*64] bf16
    float* Cc = (float*)R3;                                            // [N*128] f32 (later)

    double* stA = st;
    double* stB = st + 256;
    double* stC = st + 512;
    float2* ssA = ss;
    float2* ssB = ss + 128;
    float2* ssC = ss + 256;

    hipMemsetAsync(st, 0, 1024 * 8, stream);

    const int nb = (N + 255) / 256;
    const int nchunks = (N + 1023) / 1024;
    const int NB = (N + 255) >> 8;
    const int cpb = (((E + PB - 1) / PB) + 3) & ~3;
    const int n2 = NB * PB;
    const int nch2 = (n2 + 1023) / 1024;

    // weight packing (independent)
    wpack_kernel<<<4, 256, 0, stream>>>(W1, w1p, 64);
    wpack_kernel<<<8, 256, 0, stream>>>(W2, w2p, 128);

    // partition edges by dst bucket (no global atomics)
    hist_kernel<<<PB, 256, 0, stream>>>(dstp, hist, E, cpb, NB);
    scan1_kernel<<<nch2, 1024, 0, stream>>>(hist, offs, bsums, n2);
    scan2_kernel<<<1, 64, 0, stream>>>(bsums, nch2);
    scan3_add<<<(n2 + 255) / 256, 256, 0, stream>>>(offs, bsums, n2);
    scatter_kernel<<<PB, 256, 0, stream>>>(srcp, dstp, offs, part, E, cpb, NB);

    // degrees + dinv from partition
    bucket_count<<<NB, 256, 0, stream>>>(part, offs, cnt, dinv, E, N, NB);

    // rowptr = exscan(cnt), then CSR fill
    scan1_kernel<<<nchunks, 1024, 0, stream>>>(cnt, rowptr, bsums, N);
    scan2_kernel<<<1, 64, 0, stream>>>(bsums, nchunks);
    scan3_rowptr<<<nb, 256, 0, stream>>>(rowptr, bsums, N, E);
    bucket_fill<<<NB, 256, 0, stream>>>(part, offs, rowptr, csr, E, N, NB);

    // Layer 1
    prescale64_bf<<<(N * 8 + 255) / 256, 256, 0, stream>>>(x, dinv, y16, N);
    agg64_bf<<<(N * 64 + 255) / 256, 256, 0, stream>>>(y16, rowptr, csr, dinv, A16, N);
    mfma_gemm<64><<<(N + 63) / 64, 256, 0, stream>>>(A16, w1p, Bb, N);
    colstats128<<<512, 256, 0, stream>>>(Bb, N, stA);
    bnfin_kernel<<<1, 128, 0, stream>>>(stA, g1, be1, ssA, N, 128);
    normrelu_bf<<<(N * 16 + 255) / 256, 256, 0, stream>>>(Bb, ssA, dinv, c16, N);

    // Layer 2
    agg128_bf<<<(N * 64 + 255) / 256, 256, 0, stream>>>(c16, rowptr, csr, dinv, A16, N);
    mfma_gemm<128><<<(N + 63) / 64, 256, 0, stream>>>(A16, w2p, Bb, N);
    colstats128<<<512, 256, 0, stream>>>(Bb, N, stB);
    bnfin_kernel<<<1, 128, 0, stream>>>(stB, g2, be2, ssB, N, 128);
    normrelu_kernel<<<(N * 32 + 255) / 256, 256, 0, stream>>>(Bb, ssB, Cc, N, 128);

    // Pool
    bounds_kernel<<<nb, 256, 0, stream>>>(batch, gstart, N, G);
    pool_kernel<<<G, 128, 0, stream>>>(Cc, gstart, pooled);

    // Head
    gemm_bias_kernel<128><<<dim3((G + 31) / 32, 2), 256, 0, stream>>>(pooled, W3, b3, z, G, 256);
    colstats_kernel<<<64, 256, 0, stream>>>(z, G, 256, 8, stC);
    bnfin_kernel<<<1, 256, 0, stream>>>(stC, g3, be3, ssC, G, 256);
    head_kernel<<<G, 256, 0, stream>>>(z, ssC, W4, b4, out, G);
}

// Round 7
// 272.386 us; speedup vs baseline: 1.7812x; 1.1493x over previous
//
#include <hip/hip_runtime.h>
#include <hip/hip_bf16.h>

#define BN_EPS 1e-5
#define PB 256   // partition blocks for edge binning

typedef __attribute__((ext_vector_type(8))) short short8;
typedef __attribute__((ext_vector_type(4))) float floatx4;

// ---------------- bf16 helpers ----------------

__device__ __forceinline__ unsigned short f2bf(float f) {
    union { float f; unsigned u; } v; v.f = f;
    unsigned r = v.u + 0x7FFF + ((v.u >> 16) & 1);   // RNE
    return (unsigned short)(r >> 16);
}
__device__ __forceinline__ float bf2f(unsigned short h) {
    union { unsigned u; float f; } v; v.u = ((unsigned)h) << 16;
    return v.f;
}
__device__ __forceinline__ float lo16(unsigned u) { return bf2f((unsigned short)(u & 0xffff)); }
__device__ __forceinline__ float hi16(unsigned u) { return bf2f((unsigned short)(u >> 16)); }

// ---------------- scans ----------------

__global__ void scan1_kernel(const int* __restrict__ in, int* __restrict__ part,
                             int* __restrict__ bsum, int n) {
    __shared__ int s[1024];
    int t = threadIdx.x;
    int i = blockIdx.x * 1024 + t;
    int v = (i < n) ? in[i] : 0;
    s[t] = v;
    __syncthreads();
    for (int off = 1; off < 1024; off <<= 1) {
        int x = (t >= off) ? s[t - off] : 0;
        __syncthreads();
        s[t] += x;
        __syncthreads();
    }
    if (i < n) part[i] = s[t] - v;
    if (t == 1023) bsum[blockIdx.x] = s[1023];
}

__global__ void scan2_kernel(int* __restrict__ bsum, int nb) {
    __shared__ int s[64];
    int t = threadIdx.x;
    int v = (t < nb) ? bsum[t] : 0;
    s[t] = v;
    __syncthreads();
    for (int off = 1; off < 64; off <<= 1) {
        int x = (t >= off) ? s[t - off] : 0;
        __syncthreads();
        s[t] += x;
        __syncthreads();
    }
    if (t < nb) bsum[t] = s[t] - v;
}

__global__ void scan3_rowptr(int* __restrict__ rowptr, const int* __restrict__ bsum,
                             int n, int E) {
    int i = blockIdx.x * blockDim.x + threadIdx.x;
    if (i < n) rowptr[i] += bsum[i >> 10];
    if (i == 0) rowptr[n] = E;
}

__global__ void scan3_add(int* __restrict__ arr, const int* __restrict__ bsum, int n) {
    int i = blockIdx.x * blockDim.x + threadIdx.x;
    if (i < n) arr[i] += bsum[i >> 10];
}

// ---------------- ownership-based CSR build ----------------

__global__ void hist_kernel(const int* __restrict__ dst, int* __restrict__ hist,
                            int E, int cpb, int NB) {
    __shared__ int h[256];
    int t = threadIdx.x;
    if (t < NB) h[t] = 0;
    __syncthreads();
    int base = blockIdx.x * cpb;
    int end = base + cpb; if (end > E) end = E;
    int e = base + t * 4;
    for (; e + 3 < end; e += 1024) {
        int4 d = *(const int4*)(dst + e);
        atomicAdd(&h[d.x >> 8], 1);
        atomicAdd(&h[d.y >> 8], 1);
        atomicAdd(&h[d.z >> 8], 1);
        atomicAdd(&h[d.w >> 8], 1);
    }
    for (; e < end; ++e) atomicAdd(&h[dst[e] >> 8], 1);
    __syncthreads();
    if (t < NB) hist[t * PB + blockIdx.x] = h[t];
}

__global__ void scatter_kernel(const int* __restrict__ src, const int* __restrict__ dst,
                               const int* __restrict__ offs, unsigned* __restrict__ part,
                               int E, int cpb, int NB) {
    __shared__ int cur[256];
    int t = threadIdx.x;
    if (t < NB) cur[t] = offs[t * PB + blockIdx.x];
    __syncthreads();
    int base = blockIdx.x * cpb;
    int end = base + cpb; if (end > E) end = E;
    int e = base + t * 4;
    for (; e + 3 < end; e += 1024) {
        int4 d4 = *(const int4*)(dst + e);
        int4 s4 = *(const int4*)(src + e);
        int dd[4] = {d4.x, d4.y, d4.z, d4.w};
        int sv[4] = {s4.x, s4.y, s4.z, s4.w};
#pragma unroll
        for (int i = 0; i < 4; ++i) {
            int pos = atomicAdd(&cur[dd[i] >> 8], 1);
            part[pos] = ((unsigned)sv[i] << 8) | (unsigned)(dd[i] & 255);
        }
    }
    for (; e < end; ++e) {
        int d = dst[e];
        int pos = atomicAdd(&cur[d >> 8], 1);
        part[pos] = ((unsigned)src[e] << 8) | (unsigned)(d & 255);
    }
}

__global__ void bucket_count(const unsigned* __restrict__ part, const int* __restrict__ offs,
                             int* __restrict__ cnt, float* __restrict__ dinv,
                             int E, int N, int NB) {
    __shared__ int cw[256];
    int b = blockIdx.x;
    int t = threadIdx.x;
    cw[t] = 0;
    __syncthreads();
    int bstart = offs[b * PB];
    int bend = (b + 1 < NB) ? offs[(b + 1) * PB] : E;
    for (int e = bstart + t; e < bend; e += 256)
        atomicAdd(&cw[part[e] & 255u], 1);
    __syncthreads();
    int node = (b << 8) + t;
    if (node < N) {
        int c = cw[t];
        cnt[node] = c;
        dinv[node] = rsqrtf((float)(c + 1));   // +1 self loop
    }
}

__global__ void bucket_fill(const unsigned* __restrict__ part, const int* __restrict__ offs,
                            const int* __restrict__ rowptr, int* __restrict__ csr,
                            int E, int N, int NB) {
    __shared__ int cur[256];
    int b = blockIdx.x;
    int t = threadIdx.x;
    int node = (b << 8) + t;
    cur[t] = (node < N) ? rowptr[node] : 0;
    __syncthreads();
    int bstart = offs[b * PB];
    int bend = (b + 1 < NB) ? offs[(b + 1) * PB] : E;
    for (int e = bstart + t; e < bend; e += 256) {
        unsigned pr = part[e];
        int pos = atomicAdd(&cur[pr & 255u], 1);
        csr[pos] = (int)(pr >> 8);
    }
}

// ---------------- GCN pieces ----------------

// y16[v][c] = bf16(x[v][c] * dinv[v]), C=64
__global__ void prescale64_bf(const float* __restrict__ x, const float* __restrict__ dinv,
                              unsigned short* __restrict__ y, int N) {
    int t = blockIdx.x * blockDim.x + threadIdx.x;
    int total = N * 8;
    if (t >= total) return;
    int r = t >> 3;
    float d = dinv[r];
    float4 a = ((const float4*)x)[t * 2];
    float4 b = ((const float4*)x)[t * 2 + 1];
    uint4 o;
    o.x = (unsigned)f2bf(a.x * d) | ((unsigned)f2bf(a.y * d) << 16);
    o.y = (unsigned)f2bf(a.z * d) | ((unsigned)f2bf(a.w * d) << 16);
    o.z = (unsigned)f2bf(b.x * d) | ((unsigned)f2bf(b.y * d) << 16);
    o.w = (unsigned)f2bf(b.z * d) | ((unsigned)f2bf(b.w * d) << 16);
    ((uint4*)y)[t] = o;
}

// 2 nodes per wave, 64 ch: half-wave per node, uint (2ch) per lane, unroll-8
__global__ __launch_bounds__(256) void agg64_bf(
    const unsigned short* __restrict__ y, const int* __restrict__ rowptr,
    const int* __restrict__ csr, const float* __restrict__ dinv,
    unsigned short* __restrict__ A16, int N) {
    int wv = (blockIdx.x * blockDim.x + threadIdx.x) >> 6;
    int lane = threadIdx.x & 63;
    int node = wv * 2 + (lane >> 5);
    if (node >= N) return;
    int cu = lane & 31;
    const unsigned* yp = (const unsigned*)y;     // 32 uints per row
    unsigned v = yp[(size_t)node * 32 + cu];
    float a0 = lo16(v), a1 = hi16(v);
    int b = rowptr[node], e = rowptr[node + 1];
    int i = b;
    for (; i + 7 < e; i += 8) {
        int s0 = csr[i], s1 = csr[i + 1], s2 = csr[i + 2], s3 = csr[i + 3];
        int s4 = csr[i + 4], s5 = csr[i + 5], s6 = csr[i + 6], s7 = csr[i + 7];
        unsigned v0 = yp[(size_t)s0 * 32 + cu];
        unsigned v1 = yp[(size_t)s1 * 32 + cu];
        unsigned v2 = yp[(size_t)s2 * 32 + cu];
        unsigned v3 = yp[(size_t)s3 * 32 + cu];
        unsigned v4 = yp[(size_t)s4 * 32 + cu];
        unsigned v5 = yp[(size_t)s5 * 32 + cu];
        unsigned v6 = yp[(size_t)s6 * 32 + cu];
        unsigned v7 = yp[(size_t)s7 * 32 + cu];
        a0 += ((lo16(v0) + lo16(v1)) + (lo16(v2) + lo16(v3)))
            + ((lo16(v4) + lo16(v5)) + (lo16(v6) + lo16(v7)));
        a1 += ((hi16(v0) + hi16(v1)) + (hi16(v2) + hi16(v3)))
            + ((hi16(v4) + hi16(v5)) + (hi16(v6) + hi16(v7)));
    }
    for (; i + 3 < e; i += 4) {
        int s0 = csr[i], s1 = csr[i + 1], s2 = csr[i + 2], s3 = csr[i + 3];
        unsigned v0 = yp[(size_t)s0 * 32 + cu];
        unsigned v1 = yp[(size_t)s1 * 32 + cu];
        unsigned v2 = yp[(size_t)s2 * 32 + cu];
        unsigned v3 = yp[(size_t)s3 * 32 + cu];
        a0 += (lo16(v0) + lo16(v1)) + (lo16(v2) + lo16(v3));
        a1 += (hi16(v0) + hi16(v1)) + (hi16(v2) + hi16(v3));
    }
    for (; i < e; ++i) {
        unsigned v0 = yp[(size_t)csr[i] * 32 + cu];
        a0 += lo16(v0);
        a1 += hi16(v0);
    }
    float d = dinv[node];
    ((unsigned*)A16)[(size_t)node * 32 + cu] =
        (unsigned)f2bf(a0 * d) | ((unsigned)f2bf(a1 * d) << 16);
}

// 2 nodes per wave, 128 ch: half-wave per node, uint2 (4ch) per lane, unroll-8
__global__ __launch_bounds__(256) void agg128_bf(
    const unsigned short* __restrict__ y, const int* __restrict__ rowptr,
    const int* __restrict__ csr, const float* __restrict__ dinv,
    unsigned short* __restrict__ A16, int N) {
    int wv = (blockIdx.x * blockDim.x + threadIdx.x) >> 6;
    int lane = threadIdx.x & 63;
    int node = wv * 2 + (lane >> 5);
    if (node >= N) return;
    int c2 = lane & 31;
    const uint2* yp = (const uint2*)y;           // 32 uint2 per row
    uint2 v = yp[(size_t)node * 32 + c2];
    float a0 = lo16(v.x), a1 = hi16(v.x), a2 = lo16(v.y), a3 = hi16(v.y);
    int b = rowptr[node], e = rowptr[node + 1];
    int i = b;
    for (; i + 7 < e; i += 8) {
        int s0 = csr[i], s1 = csr[i + 1], s2 = csr[i + 2], s3 = csr[i + 3];
        int s4 = csr[i + 4], s5 = csr[i + 5], s6 = csr[i + 6], s7 = csr[i + 7];
        uint2 v0 = yp[(size_t)s0 * 32 + c2];
        uint2 v1 = yp[(size_t)s1 * 32 + c2];
        uint2 v2 = yp[(size_t)s2 * 32 + c2];
        uint2 v3 = yp[(size_t)s3 * 32 + c2];
        uint2 v4 = yp[(size_t)s4 * 32 + c2];
        uint2 v5 = yp[(size_t)s5 * 32 + c2];
        uint2 v6 = yp[(size_t)s6 * 32 + c2];
        uint2 v7 = yp[(size_t)s7 * 32 + c2];
        a0 += ((lo16(v0.x) + lo16(v1.x)) + (lo16(v2.x) + lo16(v3.x)))
            + ((lo16(v4.x) + lo16(v5.x)) + (lo16(v6.x) + lo16(v7.x)));
        a1 += ((hi16(v0.x) + hi16(v1.x)) + (hi16(v2.x) + hi16(v3.x)))
            + ((hi16(v4.x) + hi16(v5.x)) + (hi16(v6.x) + hi16(v7.x)));
        a2 += ((lo16(v0.y) + lo16(v1.y)) + (lo16(v2.y) + lo16(v3.y)))
            + ((lo16(v4.y) + lo16(v5.y)) + (lo16(v6.y) + lo16(v7.y)));
        a3 += ((hi16(v0.y) + hi16(v1.y)) + (hi16(v2.y) + hi16(v3.y)))
            + ((hi16(v4.y) + hi16(v5.y)) + (hi16(v6.y) + hi16(v7.y)));
    }
    for (; i + 3 < e; i += 4) {
        int s0 = csr[i], s1 = csr[i + 1], s2 = csr[i + 2], s3 = csr[i + 3];
        uint2 v0 = yp[(size_t)s0 * 32 + c2];
        uint2 v1 = yp[(size_t)s1 * 32 + c2];
        uint2 v2 = yp[(size_t)s2 * 32 + c2];
        uint2 v3 = yp[(size_t)s3 * 32 + c2];
        a0 += (lo16(v0.x) + lo16(v1.x)) + (lo16(v2.x) + lo16(v3.x));
        a1 += (hi16(v0.x) + hi16(v1.x)) + (hi16(v2.x) + hi16(v3.x));
        a2 += (lo16(v0.y) + lo16(v1.y)) + (lo16(v2.y) + lo16(v3.y));
        a3 += (hi16(v0.y) + hi16(v1.y)) + (hi16(v2.y) + hi16(v3.y));
    }
    for (; i < e; ++i) {
        uint2 v0 = yp[(size_t)csr[i] * 32 + c2];
        a0 += lo16(v0.x);
        a1 += hi16(v0.x);
        a2 += lo16(v0.y);
        a3 += hi16(v0.y);
    }
    float d = dinv[node];
    uint2 o;
    o.x = (unsigned)f2bf(a0 * d) | ((unsigned)f2bf(a1 * d) << 16);
    o.y = (unsigned)f2bf(a2 * d) | ((unsigned)f2bf(a3 * d) << 16);
    ((uint2*)A16)[(size_t)node * 32 + c2] = o;
}

// pack W[K][128] fp32 -> Wp[kb][c] = uint4 of 8 bf16 (k = kb*8+j)
__global__ void wpack_kernel(const float* __restrict__ W, uint4* __restrict__ Wp, int K) {
    int i = blockIdx.x * blockDim.x + threadIdx.x;
    int total = K * 16;
    if (i >= total) return;
    int c = i & 127;
    int kb = i >> 7;
    unsigned short h[8];
#pragma unroll
    for (int j = 0; j < 8; ++j) h[j] = f2bf(W[(size_t)(kb * 8 + j) * 128 + c]);
    uint4 o;
    o.x = (unsigned)h[0] | ((unsigned)h[1] << 16);
    o.y = (unsigned)h[2] | ((unsigned)h[3] << 16);
    o.z = (unsigned)h[4] | ((unsigned)h[5] << 16);
    o.w = (unsigned)h[6] | ((unsigned)h[7] << 16);
    Wp[kb * 128 + c] = o;
}

// MFMA GEMM + fused column stats: A16[N][K] bf16 @ Wp -> out[N][128] fp32,
// col sum/sumsq accumulated into st[0..128)/st[128..256) via LDS + double atomics.
template <int K>
__global__ __launch_bounds__(256) void mfma_gemm(const unsigned short* __restrict__ A16,
                                                 const uint4* __restrict__ Bp,
                                                 float* __restrict__ out,
                                                 double* __restrict__ st, int N) {
    constexpr int KS = K / 32;
    __shared__ float cs[128], cs2[128];
    if (threadIdx.x < 128) { cs[threadIdx.x] = 0.f; cs2[threadIdx.x] = 0.f; }
    int w = threadIdx.x >> 6, l = threadIdx.x & 63;
    int cl = l & 15, sub = l >> 4;
    int r0 = blockIdx.x * 64 + w * 16;
    int ra = r0 + cl; if (ra > N - 1) ra = N - 1;

    short8 a[KS];
    const unsigned short* ap = A16 + (size_t)ra * K + sub * 8;
#pragma unroll
    for (int ks = 0; ks < KS; ++ks) a[ks] = *(const short8*)(ap + ks * 32);

    floatx4 acc[8] = {};
#pragma unroll
    for (int cb = 0; cb < 8; ++cb) {
#pragma unroll
        for (int ks = 0; ks < KS; ++ks) {
            short8 b = *(const short8*)&Bp[(ks * 4 + sub) * 128 + cb * 16 + cl];
            acc[cb] = __builtin_amdgcn_mfma_f32_16x16x32_bf16(a[ks], b, acc[cb], 0, 0, 0);
        }
    }
    __syncthreads();   // cs/cs2 init visible
#pragma unroll
    for (int cb = 0; cb < 8; ++cb) {
        float s = 0.f, s2 = 0.f;
#pragma unroll
        for (int j = 0; j < 4; ++j) {
            int row = r0 + sub * 4 + j;
            if (row < N) {
                float val = acc[cb][j];
                out[(size_t)row * 128 + cb * 16 + cl] = val;
                s += val;
                s2 += val * val;
            }
        }
        atomicAdd(&cs[cb * 16 + cl], s);
        atomicAdd(&cs2[cb * 16 + cl], s2);
    }
    __syncthreads();
    if (threadIdx.x < 128) {
        atomicAdd(&st[threadIdx.x], (double)cs[threadIdx.x]);
        atomicAdd(&st[128 + threadIdx.x], (double)cs2[threadIdx.x]);
    }
}

// generic colstats (head, C=256)
__global__ void colstats_kernel(const float* __restrict__ h, int N, int C, int logC,
                                double* __restrict__ st) {
    int c = threadIdx.x & (C - 1);
    int sub = threadIdx.x >> logC;
    int rpb = 256 >> logC;
    float s = 0.f, s2 = 0.f;
    for (int r = blockIdx.x * rpb + sub; r < N; r += gridDim.x * rpb) {
        float v = h[(size_t)r * C + c];
        s += v;
        s2 += v * v;
    }
    atomicAdd(&st[c], (double)s);
    atomicAdd(&st[C + c], (double)s2);
}

__global__ void bnfin_kernel(const double* __restrict__ st, const float* __restrict__ gamma,
                             const float* __restrict__ beta, float2* __restrict__ ss,
                             int N, int C) {
    int c = blockIdx.x * blockDim.x + threadIdx.x;
    if (c >= C) return;
    double mean = st[c] / N;
    double var = st[C + c] / N - mean * mean;
    float sc = (float)((double)gamma[c] / sqrt(var + BN_EPS));
    float sh = beta[c] - (float)mean * sc;
    ss[c] = make_float2(sc, sh);
}

// out16 = bf16(relu(h*scale+shift) * dinv[row]), C=128
__global__ void normrelu_bf(const float* __restrict__ h, const float2* __restrict__ ss,
                            const float* __restrict__ dinv, unsigned short* __restrict__ out,
                            int N) {
    int t = blockIdx.x * blockDim.x + threadIdx.x;
    int total = N * 16;
    if (t >= total) return;
    int r = t >> 4;
    int j = (t & 15) << 3;
    float d = dinv[r];
    float4 a = ((const float4*)h)[t * 2];
    float4 b = ((const float4*)h)[t * 2 + 1];
    float2 s0 = ss[j], s1 = ss[j + 1], s2 = ss[j + 2], s3 = ss[j + 3];
    float2 s4 = ss[j + 4], s5 = ss[j + 5], s6 = ss[j + 6], s7 = ss[j + 7];
    float v0 = fmaxf(a.x * s0.x + s0.y, 0.f) * d;
    float v1 = fmaxf(a.y * s1.x + s1.y, 0.f) * d;
    float v2 = fmaxf(a.z * s2.x + s2.y, 0.f) * d;
    float v3 = fmaxf(a.w * s3.x + s3.y, 0.f) * d;
    float v4 = fmaxf(b.x * s4.x + s4.y, 0.f) * d;
    float v5 = fmaxf(b.y * s5.x + s5.y, 0.f) * d;
    float v6 = fmaxf(b.z * s6.x + s6.y, 0.f) * d;
    float v7 = fmaxf(b.w * s7.x + s7.y, 0.f) * d;
    uint4 o;
    o.x = (unsigned)f2bf(v0) | ((unsigned)f2bf(v1) << 16);
    o.y = (unsigned)f2bf(v2) | ((unsigned)f2bf(v3) << 16);
    o.z = (unsigned)f2bf(v4) | ((unsigned)f2bf(v5) << 16);
    o.w = (unsigned)f2bf(v6) | ((unsigned)f2bf(v7) << 16);
    ((uint4*)out)[t] = o;
}

// graph boundaries from sorted batch
__global__ void bounds_kernel(const int* __restrict__ batch, int* __restrict__ gstart,
                              int N, int G) {
    int i = blockIdx.x * blockDim.x + threadIdx.x;
    if (i >= N) return;
    int bi = batch[i];
    int bp = (i == 0) ? -1 : batch[i - 1];
    for (int g = bp + 1; g <= bi; ++g) gstart[g] = i;
    if (i == N - 1) {
        for (int g = bi + 1; g <= G; ++g) gstart[g] = N;
    }
}

// per-graph mean of relu(bn(h)) over rows, fused BN: pooled[G][128]
__global__ void pool_bn_kernel(const float* __restrict__ h, const float2* __restrict__ ss,
                               const int* __restrict__ gstart, float* __restrict__ pooled) {
    int g = blockIdx.x;
    int c = threadIdx.x;
    float2 sc = ss[c];
    int b = gstart[g], e = gstart[g + 1];
    float acc = 0.f;
    int r = b;
    for (; r + 1 < e; r += 2) {
        float v0 = h[(size_t)r * 128 + c];
        float v1 = h[(size_t)(r + 1) * 128 + c];
        acc += fmaxf(v0 * sc.x + sc.y, 0.f) + fmaxf(v1 * sc.x + sc.y, 0.f);
    }
    if (r < e) acc += fmaxf(h[(size_t)r * 128 + c] * sc.x + sc.y, 0.f);
    pooled[(size_t)g * 128 + c] = acc / fmaxf((float)(e - b), 1.0f);
}

// head gemm (fp32, small): A[N,K] @ W[K,C] + bias -> out[N,C]
template <int K>
__global__ __launch_bounds__(256) void gemm_bias_kernel(const float* __restrict__ A,
                                                        const float* __restrict__ W,
                                                        const float* __restrict__ bias,
                                                        float* __restrict__ out, int N, int C) {
    __shared__ float Wl[K * 128];
    const int ct = blockIdx.y << 7;
    for (int idx = threadIdx.x; idx < K * 128; idx += 256) {
        int kk = idx >> 7, cc = idx & 127;
        Wl[idx] = W[(size_t)kk * C + ct + cc];
    }
    __syncthreads();
    const int cq = (threadIdx.x & 31) << 2;
    const int rg = threadIdx.x >> 5;
    const int r0 = blockIdx.x * 32 + (rg << 2);

    const float* Ap[4];
#pragma unroll
    for (int i = 0; i < 4; ++i) {
        int r = r0 + i;
        Ap[i] = A + (size_t)(r < N ? r : 0) * K;
    }
    float acc[4][4] = {};
#pragma unroll 4
    for (int k = 0; k < K; ++k) {
        float a0 = Ap[0][k];
        float a1 = Ap[1][k];
        float a2 = Ap[2][k];
        float a3 = Ap[3][k];
        float4 w = *(const float4*)&Wl[k * 128 + cq];
        acc[0][0] += a0 * w.x; acc[0][1] += a0 * w.y; acc[0][2] += a0 * w.z; acc[0][3] += a0 * w.w;
        acc[1][0] += a1 * w.x; acc[1][1] += a1 * w.y; acc[1][2] += a1 * w.z; acc[1][3] += a1 * w.w;
        acc[2][0] += a2 * w.x; acc[2][1] += a2 * w.y; acc[2][2] += a2 * w.z; acc[2][3] += a2 * w.w;
        acc[3][0] += a3 * w.x; acc[3][1] += a3 * w.y; acc[3][2] += a3 * w.z; acc[3][3] += a3 * w.w;
    }
    float4 bv = *(const float4*)&bias[ct + cq];
#pragma unroll
    for (int i = 0; i < 4; ++i) {
        int r = r0 + i;
        if (r < N) {
            float4 o = make_float4(acc[i][0] + bv.x, acc[i][1] + bv.y,
                                   acc[i][2] + bv.z, acc[i][3] + bv.w);
            *(float4*)&out[(size_t)r * C + ct + cq] = o;
        }
    }
}

// final: out[g][j] = sum_c relu(bn(z))[g][c] * W4[c][j] + b4[j]
// 10 outputs x 16 lanes, shuffle-reduced
__global__ void head_kernel(const float* __restrict__ z, const float2* __restrict__ ss,
                            const float* __restrict__ W4, const float* __restrict__ b4,
                            float* __restrict__ out, int G) {
    __shared__ float zr[256];
    int g = blockIdx.x;
    int t = threadIdx.x;
    float v = z[(size_t)g * 256 + t];
    zr[t] = fmaxf(v * ss[t].x + ss[t].y, 0.f);
    __syncthreads();
    int j = t >> 4;
    int part = t & 15;
    if (j < 10) {
        float acc = 0.f;
#pragma unroll
        for (int k = 0; k < 16; ++k) {
            int c = part + k * 16;
            acc += zr[c] * W4[c * 10 + j];
        }
#pragma unroll
        for (int off = 8; off; off >>= 1) acc += __shfl_down(acc, off);
        if (part == 0) out[(size_t)g * 10 + j] = acc + b4[j];
    }
}

// ---------------- launch ----------------

extern "C" void kernel_launch(void* const* d_in, const int* in_sizes, int n_in,
                              void* d_out, int out_size, void* d_ws, size_t ws_size,
                              hipStream_t stream) {
    const int N = in_sizes[0] / 64;
    const int E = in_sizes[1] / 2;
    const int G = out_size / 10;

    const float* x     = (const float*)d_in[0];
    const int*   ei    = (const int*)d_in[1];
    const int*   batch = (const int*)d_in[2];
    const float* W1 = (const float*)d_in[3];
    const float* g1 = (const float*)d_in[5];
    const float* be1 = (const float*)d_in[6];
    const float* W2 = (const float*)d_in[7];
    const float* g2 = (const float*)d_in[9];
    const float* be2 = (const float*)d_in[10];
    const float* W3 = (const float*)d_in[11];
    const float* b3 = (const float*)d_in[12];
    const float* g3 = (const float*)d_in[13];
    const float* be3 = (const float*)d_in[14];
    const float* W4 = (const float*)d_in[15];
    const float* b4 = (const float*)d_in[16];
    float* out = (float*)d_out;

    const int* srcp = ei;        // edge_index[0]
    const int* dstp = ei + E;    // edge_index[1]

    // workspace layout
    char* p = (char*)d_ws;
    auto alloc = [&](size_t bytes) {
        void* r = (void*)p;
        p += (bytes + 255) & ~(size_t)255;
        return r;
    };
    unsigned short* A16 = (unsigned short*)alloc((size_t)N * 128 * 2);
    float* Bb = (float*)alloc((size_t)N * 128 * 4);
    char* R3  = (char*)alloc((size_t)N * 128 * 4);   // c16 | y16
    int* csr      = (int*)alloc((size_t)E * 4);
    unsigned* part = (unsigned*)alloc((size_t)E * 4);
    int* cnt    = (int*)alloc((size_t)N * 4);
    int* rowptr = (int*)alloc((size_t)(N + 1) * 4);
    float* dinv = (float*)alloc((size_t)N * 4);
    int* hist   = (int*)alloc((size_t)256 * PB * 4);
    int* offs   = (int*)alloc((size_t)256 * PB * 4);
    int* bsums  = (int*)alloc(64 * 4);
    uint4* w1p  = (uint4*)alloc((size_t)64 * 128 * 2);
    uint4* w2p  = (uint4*)alloc((size_t)128 * 128 * 2);
    int* gstart = (int*)alloc((size_t)(G + 1) * 4);
    float* pooled = (float*)alloc((size_t)G * 128 * 4);
    float* z      = (float*)alloc((size_t)G * 256 * 4);
    double* st    = (double*)alloc(1024 * 8);
    float2* ss    = (float2*)alloc(512 * 8);
    (void)ws_size; (void)n_in;

    unsigned short* c16 = (unsigned short*)R3;                         // [N*128] bf16
    unsigned short* y16 = (unsigned short*)(R3 + (size_t)N * 128 * 2); // [N*64] bf16

    double* stA = st;
    double* stB = st + 256;
    double* stC = st + 512;
    float2* ssA = ss;
    float2* ssB = ss + 128;
    float2* ssC = ss + 256;

    hipMemsetAsync(st, 0, 1024 * 8, stream);

    const int nb = (N + 255) / 256;
    const int nchunks = (N + 1023) / 1024;
    const int NB = (N + 255) >> 8;
    const int cpb = (((E + PB - 1) / PB) + 3) & ~3;
    const int n2 = NB * PB;
    const int nch2 = (n2 + 1023) / 1024;
    const int aggblocks = (N + 7) / 8;   // 4 waves/block, 2 nodes/wave

    // weight packing (independent)
    wpack_kernel<<<4, 256, 0, stream>>>(W1, w1p, 64);
    wpack_kernel<<<8, 256, 0, stream>>>(W2, w2p, 128);

    // partition edges by dst bucket (no global atomics)
    hist_kernel<<<PB, 256, 0, stream>>>(dstp, hist, E, cpb, NB);
    scan1_kernel<<<nch2, 1024, 0, stream>>>(hist, offs, bsums, n2);
    scan2_kernel<<<1, 64, 0, stream>>>(bsums, nch2);
    scan3_add<<<(n2 + 255) / 256, 256, 0, stream>>>(offs, bsums, n2);
    scatter_kernel<<<PB, 256, 0, stream>>>(srcp, dstp, offs, part, E, cpb, NB);

    // degrees + dinv from partition
    bucket_count<<<NB, 256, 0, stream>>>(part, offs, cnt, dinv, E, N, NB);

    // rowptr = exscan(cnt), then CSR fill
    scan1_kernel<<<nchunks, 1024, 0, stream>>>(cnt, rowptr, bsums, N);
    scan2_kernel<<<1, 64, 0, stream>>>(bsums, nchunks);
    scan3_rowptr<<<nb, 256, 0, stream>>>(rowptr, bsums, N, E);
    bucket_fill<<<NB, 256, 0, stream>>>(part, offs, rowptr, csr, E, N, NB);

    // Layer 1
    prescale64_bf<<<(N * 8 + 255) / 256, 256, 0, stream>>>(x, dinv, y16, N);
    agg64_bf<<<aggblocks, 256, 0, stream>>>(y16, rowptr, csr, dinv, A16, N);
    mfma_gemm<64><<<(N + 63) / 64, 256, 0, stream>>>(A16, w1p, Bb, stA, N);
    bnfin_kernel<<<1, 128, 0, stream>>>(stA, g1, be1, ssA, N, 128);
    normrelu_bf<<<(N * 16 + 255) / 256, 256, 0, stream>>>(Bb, ssA, dinv, c16, N);

    // Layer 2
    agg128_bf<<<aggblocks, 256, 0, stream>>>(c16, rowptr, csr, dinv, A16, N);
    mfma_gemm<128><<<(N + 63) / 64, 256, 0, stream>>>(A16, w2p, Bb, stB, N);
    bnfin_kernel<<<1, 128, 0, stream>>>(stB, g2, be2, ssB, N, 128);

    // Pool (BN+ReLU fused)
    bounds_kernel<<<nb, 256, 0, stream>>>(batch, gstart, N, G);
    pool_bn_kernel<<<G, 128, 0, stream>>>(Bb, ssB, gstart, pooled);

    // Head
    gemm_bias_kernel<128><<<dim3((G + 31) / 32, 2), 256, 0, stream>>>(pooled, W3, b3, z, G, 256);
    colstats_kernel<<<64, 256, 0, stream>>>(z, G, 256, 8, stC);
    bnfin_kernel<<<1, 256, 0, stream>>>(stC, g3, be3, ssC, G, 256);
    head_kernel<<<G, 256, 0, stream>>>(z, ssC, W4, b4, out, G);
}

// Round 8
// 270.591 us; speedup vs baseline: 1.7930x; 1.0066x over previous
//
#include <hip/hip_runtime.h>
#include <hip/hip_bf16.h>

#define BN_EPS 1e-5
#define PB 256   // partition blocks for edge binning

typedef __attribute__((ext_vector_type(8))) short short8;
typedef __attribute__((ext_vector_type(4))) float floatx4;

// ---------------- bf16 helpers ----------------

__device__ __forceinline__ unsigned short f2bf(float f) {
    union { float f; unsigned u; } v; v.f = f;
    unsigned r = v.u + 0x7FFF + ((v.u >> 16) & 1);   // RNE
    return (unsigned short)(r >> 16);
}
__device__ __forceinline__ float bf2f(unsigned short h) {
    union { unsigned u; float f; } v; v.u = ((unsigned)h) << 16;
    return v.f;
}
__device__ __forceinline__ float lo16(unsigned u) { return bf2f((unsigned short)(u & 0xffff)); }
__device__ __forceinline__ float hi16(unsigned u) { return bf2f((unsigned short)(u >> 16)); }

// ---------------- scans ----------------

__global__ void scan1_kernel(const int* __restrict__ in, int* __restrict__ part,
                             int* __restrict__ bsum, int n) {
    __shared__ int s[1024];
    int t = threadIdx.x;
    int i = blockIdx.x * 1024 + t;
    int v = (i < n) ? in[i] : 0;
    s[t] = v;
    __syncthreads();
    for (int off = 1; off < 1024; off <<= 1) {
        int x = (t >= off) ? s[t - off] : 0;
        __syncthreads();
        s[t] += x;
        __syncthreads();
    }
    if (i < n) part[i] = s[t] - v;
    if (t == 1023) bsum[blockIdx.x] = s[1023];
}

// fixup with inline exscan of <=64 block sums (merges old scan2+scan3)
__global__ void scan23_add(int* __restrict__ arr, const int* __restrict__ bsum,
                           int nb, int n) {
    __shared__ int s[64];
    int t = threadIdx.x;
    if (t < 64) s[t] = (t < nb) ? bsum[t] : 0;
    __syncthreads();
    for (int off = 1; off < 64; off <<= 1) {
        int x = (t < 64 && t >= off) ? s[t - off] : 0;
        __syncthreads();
        if (t < 64) s[t] += x;
        __syncthreads();
    }
    int i = blockIdx.x * blockDim.x + t;
    if (i < n) {
        int ch = i >> 10;
        int pre = (ch == 0) ? 0 : s[ch - 1];
        arr[i] += pre;
    }
}

// ---------------- ownership-based CSR build ----------------

__global__ void hist_kernel(const int* __restrict__ dst, int* __restrict__ hist,
                            int E, int cpb, int NB) {
    __shared__ int h[256];
    int t = threadIdx.x;
    if (t < NB) h[t] = 0;
    __syncthreads();
    int base = blockIdx.x * cpb;
    int end = base + cpb; if (end > E) end = E;
    int e = base + t * 4;
    for (; e + 3 < end; e += 1024) {
        int4 d = *(const int4*)(dst + e);
        atomicAdd(&h[d.x >> 8], 1);
        atomicAdd(&h[d.y >> 8], 1);
        atomicAdd(&h[d.z >> 8], 1);
        atomicAdd(&h[d.w >> 8], 1);
    }
    for (; e < end; ++e) atomicAdd(&h[dst[e] >> 8], 1);
    __syncthreads();
    if (t < NB) hist[t * PB + blockIdx.x] = h[t];
}

__global__ void scatter_kernel(const int* __restrict__ src, const int* __restrict__ dst,
                               const int* __restrict__ offs, unsigned* __restrict__ part,
                               int E, int cpb, int NB) {
    __shared__ int cur[256];
    int t = threadIdx.x;
    if (t < NB) cur[t] = offs[t * PB + blockIdx.x];
    __syncthreads();
    int base = blockIdx.x * cpb;
    int end = base + cpb; if (end > E) end = E;
    int e = base + t * 4;
    for (; e + 3 < end; e += 1024) {
        int4 d4 = *(const int4*)(dst + e);
        int4 s4 = *(const int4*)(src + e);
        int dd[4] = {d4.x, d4.y, d4.z, d4.w};
        int sv[4] = {s4.x, s4.y, s4.z, s4.w};
#pragma unroll
        for (int i = 0; i < 4; ++i) {
            int pos = atomicAdd(&cur[dd[i] >> 8], 1);
            part[pos] = ((unsigned)sv[i] << 8) | (unsigned)(dd[i] & 255);
        }
    }
    for (; e < end; ++e) {
        int d = dst[e];
        int pos = atomicAdd(&cur[d >> 8], 1);
        part[pos] = ((unsigned)src[e] << 8) | (unsigned)(d & 255);
    }
}

// one block per bucket: per-node degree via LDS counts + LDS exscan -> rowptr, dinv.
// bucket b's CSR range starts at offs[b*PB] (partition order == dst-bucket order).
__global__ void bucket_rowptr(const unsigned* __restrict__ part, const int* __restrict__ offs,
                              int* __restrict__ rowptr, float* __restrict__ dinv,
                              int E, int N, int NB) {
    __shared__ int cw[256], sc[256];
    int b = blockIdx.x;
    int t = threadIdx.x;
    cw[t] = 0;
    __syncthreads();
    int bstart = offs[b * PB];
    int bend = (b + 1 < NB) ? offs[(b + 1) * PB] : E;
    for (int e = bstart + t; e < bend; e += 256)
        atomicAdd(&cw[part[e] & 255u], 1);
    __syncthreads();
    int c = cw[t];
    sc[t] = c;
    __syncthreads();
    for (int off = 1; off < 256; off <<= 1) {
        int x = (t >= off) ? sc[t - off] : 0;
        __syncthreads();
        sc[t] += x;
        __syncthreads();
    }
    int node = (b << 8) + t;
    if (node < N) {
        rowptr[node] = bstart + sc[t] - c;
        dinv[node] = rsqrtf((float)(c + 1));   // +1 self loop
    }
    if (b == NB - 1 && t == 255) rowptr[N] = E;
}

__global__ void bucket_fill(const unsigned* __restrict__ part, const int* __restrict__ offs,
                            const int* __restrict__ rowptr, int* __restrict__ csr,
                            int E, int N, int NB) {
    __shared__ int cur[256];
    int b = blockIdx.x;
    int t = threadIdx.x;
    int node = (b << 8) + t;
    cur[t] = (node < N) ? rowptr[node] : 0;
    __syncthreads();
    int bstart = offs[b * PB];
    int bend = (b + 1 < NB) ? offs[(b + 1) * PB] : E;
    for (int e = bstart + t; e < bend; e += 256) {
        unsigned pr = part[e];
        int pos = atomicAdd(&cur[pr & 255u], 1);
        csr[pos] = (int)(pr >> 8);
    }
}

// ---------------- GCN pieces ----------------

// y16[v][c] = bf16(x[v][c] * dinv[v]), C=64
__global__ void prescale64_bf(const float* __restrict__ x, const float* __restrict__ dinv,
                              unsigned short* __restrict__ y, int N) {
    int t = blockIdx.x * blockDim.x + threadIdx.x;
    int total = N * 8;
    if (t >= total) return;
    int r = t >> 3;
    float d = dinv[r];
    float4 a = ((const float4*)x)[t * 2];
    float4 b = ((const float4*)x)[t * 2 + 1];
    uint4 o;
    o.x = (unsigned)f2bf(a.x * d) | ((unsigned)f2bf(a.y * d) << 16);
    o.y = (unsigned)f2bf(a.z * d) | ((unsigned)f2bf(a.w * d) << 16);
    o.z = (unsigned)f2bf(b.x * d) | ((unsigned)f2bf(b.y * d) << 16);
    o.w = (unsigned)f2bf(b.z * d) | ((unsigned)f2bf(b.w * d) << 16);
    ((uint4*)y)[t] = o;
}

// 2 nodes per wave, 64 ch: half-wave per node, uint (2ch)/lane, software-pipelined idx
__global__ __launch_bounds__(256) void agg64_bf(
    const unsigned short* __restrict__ y, const int* __restrict__ rowptr,
    const int* __restrict__ csr, const float* __restrict__ dinv,
    unsigned short* __restrict__ A16, int N) {
    int wv = (blockIdx.x * blockDim.x + threadIdx.x) >> 6;
    int lane = threadIdx.x & 63;
    int node = wv * 2 + (lane >> 5);
    if (node >= N) return;
    int cu = lane & 31;
    const unsigned* yp = (const unsigned*)y;     // 32 uints per row
    unsigned v = yp[(size_t)node * 32 + cu];
    float a0 = lo16(v), a1 = hi16(v);
    int b = rowptr[node], e = rowptr[node + 1];
    int i = b;
    int n0, n1, n2, n3, n4, n5, n6, n7;
    if (i + 7 < e) {
        n0 = __builtin_nontemporal_load(csr + i);
        n1 = __builtin_nontemporal_load(csr + i + 1);
        n2 = __builtin_nontemporal_load(csr + i + 2);
        n3 = __builtin_nontemporal_load(csr + i + 3);
        n4 = __builtin_nontemporal_load(csr + i + 4);
        n5 = __builtin_nontemporal_load(csr + i + 5);
        n6 = __builtin_nontemporal_load(csr + i + 6);
        n7 = __builtin_nontemporal_load(csr + i + 7);
    }
    for (; i + 15 < e; i += 8) {
        int c0 = n0, c1 = n1, c2 = n2, c3 = n3, c4 = n4, c5 = n5, c6 = n6, c7 = n7;
        n0 = __builtin_nontemporal_load(csr + i + 8);
        n1 = __builtin_nontemporal_load(csr + i + 9);
        n2 = __builtin_nontemporal_load(csr + i + 10);
        n3 = __builtin_nontemporal_load(csr + i + 11);
        n4 = __builtin_nontemporal_load(csr + i + 12);
        n5 = __builtin_nontemporal_load(csr + i + 13);
        n6 = __builtin_nontemporal_load(csr + i + 14);
        n7 = __builtin_nontemporal_load(csr + i + 15);
        unsigned v0 = yp[(size_t)c0 * 32 + cu];
        unsigned v1 = yp[(size_t)c1 * 32 + cu];
        unsigned v2 = yp[(size_t)c2 * 32 + cu];
        unsigned v3 = yp[(size_t)c3 * 32 + cu];
        unsigned v4 = yp[(size_t)c4 * 32 + cu];
        unsigned v5 = yp[(size_t)c5 * 32 + cu];
        unsigned v6 = yp[(size_t)c6 * 32 + cu];
        unsigned v7 = yp[(size_t)c7 * 32 + cu];
        a0 += ((lo16(v0) + lo16(v1)) + (lo16(v2) + lo16(v3)))
            + ((lo16(v4) + lo16(v5)) + (lo16(v6) + lo16(v7)));
        a1 += ((hi16(v0) + hi16(v1)) + (hi16(v2) + hi16(v3)))
            + ((hi16(v4) + hi16(v5)) + (hi16(v6) + hi16(v7)));
    }
    if (i + 7 < e) {
        unsigned v0 = yp[(size_t)n0 * 32 + cu];
        unsigned v1 = yp[(size_t)n1 * 32 + cu];
        unsigned v2 = yp[(size_t)n2 * 32 + cu];
        unsigned v3 = yp[(size_t)n3 * 32 + cu];
        unsigned v4 = yp[(size_t)n4 * 32 + cu];
        unsigned v5 = yp[(size_t)n5 * 32 + cu];
        unsigned v6 = yp[(size_t)n6 * 32 + cu];
        unsigned v7 = yp[(size_t)n7 * 32 + cu];
        a0 += ((lo16(v0) + lo16(v1)) + (lo16(v2) + lo16(v3)))
            + ((lo16(v4) + lo16(v5)) + (lo16(v6) + lo16(v7)));
        a1 += ((hi16(v0) + hi16(v1)) + (hi16(v2) + hi16(v3)))
            + ((hi16(v4) + hi16(v5)) + (hi16(v6) + hi16(v7)));
        i += 8;
    }
    for (; i + 3 < e; i += 4) {
        int s0 = __builtin_nontemporal_load(csr + i);
        int s1 = __builtin_nontemporal_load(csr + i + 1);
        int s2 = __builtin_nontemporal_load(csr + i + 2);
        int s3 = __builtin_nontemporal_load(csr + i + 3);
        unsigned v0 = yp[(size_t)s0 * 32 + cu];
        unsigned v1 = yp[(size_t)s1 * 32 + cu];
        unsigned v2 = yp[(size_t)s2 * 32 + cu];
        unsigned v3 = yp[(size_t)s3 * 32 + cu];
        a0 += (lo16(v0) + lo16(v1)) + (lo16(v2) + lo16(v3));
        a1 += (hi16(v0) + hi16(v1)) + (hi16(v2) + hi16(v3));
    }
    for (; i < e; ++i) {
        unsigned v0 = yp[(size_t)__builtin_nontemporal_load(csr + i) * 32 + cu];
        a0 += lo16(v0);
        a1 += hi16(v0);
    }
    float d = dinv[node];
    ((unsigned*)A16)[(size_t)node * 32 + cu] =
        (unsigned)f2bf(a0 * d) | ((unsigned)f2bf(a1 * d) << 16);
}

// 2 nodes per wave, 128 ch: half-wave per node, uint2 (4ch)/lane, software-pipelined idx
__global__ __launch_bounds__(256) void agg128_bf(
    const unsigned short* __restrict__ y, const int* __restrict__ rowptr,
    const int* __restrict__ csr, const float* __restrict__ dinv,
    unsigned short* __restrict__ A16, int N) {
    int wv = (blockIdx.x * blockDim.x + threadIdx.x) >> 6;
    int lane = threadIdx.x & 63;
    int node = wv * 2 + (lane >> 5);
    if (node >= N) return;
    int c2 = lane & 31;
    const uint2* yp = (const uint2*)y;           // 32 uint2 per row
    uint2 v = yp[(size_t)node * 32 + c2];
    float a0 = lo16(v.x), a1 = hi16(v.x), a2 = lo16(v.y), a3 = hi16(v.y);
    int b = rowptr[node], e = rowptr[node + 1];
    int i = b;
    int n0, n1, n2, n3, n4, n5, n6, n7;
    if (i + 7 < e) {
        n0 = __builtin_nontemporal_load(csr + i);
        n1 = __builtin_nontemporal_load(csr + i + 1);
        n2 = __builtin_nontemporal_load(csr + i + 2);
        n3 = __builtin_nontemporal_load(csr + i + 3);
        n4 = __builtin_nontemporal_load(csr + i + 4);
        n5 = __builtin_nontemporal_load(csr + i + 5);
        n6 = __builtin_nontemporal_load(csr + i + 6);
        n7 = __builtin_nontemporal_load(csr + i + 7);
    }
    for (; i + 15 < e; i += 8) {
        int c0 = n0, c1 = n1, c2i = n2, c3 = n3, c4 = n4, c5 = n5, c6 = n6, c7 = n7;
        n0 = __builtin_nontemporal_load(csr + i + 8);
        n1 = __builtin_nontemporal_load(csr + i + 9);
        n2 = __builtin_nontemporal_load(csr + i + 10);
        n3 = __builtin_nontemporal_load(csr + i + 11);
        n4 = __builtin_nontemporal_load(csr + i + 12);
        n5 = __builtin_nontemporal_load(csr + i + 13);
        n6 = __builtin_nontemporal_load(csr + i + 14);
        n7 = __builtin_nontemporal_load(csr + i + 15);
        uint2 v0 = yp[(size_t)c0 * 32 + c2];
        uint2 v1 = yp[(size_t)c1 * 32 + c2];
        uint2 v2 = yp[(size_t)c2i * 32 + c2];
        uint2 v3 = yp[(size_t)c3 * 32 + c2];
        uint2 v4 = yp[(size_t)c4 * 32 + c2];
        uint2 v5 = yp[(size_t)c5 * 32 + c2];
        uint2 v6 = yp[(size_t)c6 * 32 + c2];
        uint2 v7 = yp[(size_t)c7 * 32 + c2];
        a0 += ((lo16(v0.x) + lo16(v1.x)) + (lo16(v2.x) + lo16(v3.x)))
            + ((lo16(v4.x) + lo16(v5.x)) + (lo16(v6.x) + lo16(v7.x)));
        a1 += ((hi16(v0.x) + hi16(v1.x)) + (hi16(v2.x) + hi16(v3.x)))
            + ((hi16(v4.x) + hi16(v5.x)) + (hi16(v6.x) + hi16(v7.x)));
        a2 += ((lo16(v0.y) + lo16(v1.y)) + (lo16(v2.y) + lo16(v3.y)))
            + ((lo16(v4.y) + lo16(v5.y)) + (lo16(v6.y) + lo16(v7.y)));
        a3 += ((hi16(v0.y) + hi16(v1.y)) + (hi16(v2.y) + hi16(v3.y)))
            + ((hi16(v4.y) + hi16(v5.y)) + (hi16(v6.y) + hi16(v7.y)));
    }
    if (i + 7 < e) {
        uint2 v0 = yp[(size_t)n0 * 32 + c2];
        uint2 v1 = yp[(size_t)n1 * 32 + c2];
        uint2 v2 = yp[(size_t)n2 * 32 + c2];
        uint2 v3 = yp[(size_t)n3 * 32 + c2];
        uint2 v4 = yp[(size_t)n4 * 32 + c2];
        uint2 v5 = yp[(size_t)n5 * 32 + c2];
        uint2 v6 = yp[(size_t)n6 * 32 + c2];
        uint2 v7 = yp[(size_t)n7 * 32 + c2];
        a0 += ((lo16(v0.x) + lo16(v1.x)) + (lo16(v2.x) + lo16(v3.x)))
            + ((lo16(v4.x) + lo16(v5.x)) + (lo16(v6.x) + lo16(v7.x)));
        a1 += ((hi16(v0.x) + hi16(v1.x)) + (hi16(v2.x) + hi16(v3.x)))
            + ((hi16(v4.x) + hi16(v5.x)) + (hi16(v6.x) + hi16(v7.x)));
        a2 += ((lo16(v0.y) + lo16(v1.y)) + (lo16(v2.y) + lo16(v3.y)))
            + ((lo16(v4.y) + lo16(v5.y)) + (lo16(v6.y) + lo16(v7.y)));
        a3 += ((hi16(v0.y) + hi16(v1.y)) + (hi16(v2.y) + hi16(v3.y)))
            + ((hi16(v4.y) + hi16(v5.y)) + (hi16(v6.y) + hi16(v7.y)));
        i += 8;
    }
    for (; i + 3 < e; i += 4) {
        int s0 = __builtin_nontemporal_load(csr + i);
        int s1 = __builtin_nontemporal_load(csr + i + 1);
        int s2 = __builtin_nontemporal_load(csr + i + 2);
        int s3 = __builtin_nontemporal_load(csr + i + 3);
        uint2 v0 = yp[(size_t)s0 * 32 + c2];
        uint2 v1 = yp[(size_t)s1 * 32 + c2];
        uint2 v2 = yp[(size_t)s2 * 32 + c2];
        uint2 v3 = yp[(size_t)s3 * 32 + c2];
        a0 += (lo16(v0.x) + lo16(v1.x)) + (lo16(v2.x) + lo16(v3.x));
        a1 += (hi16(v0.x) + hi16(v1.x)) + (hi16(v2.x) + hi16(v3.x));
        a2 += (lo16(v0.y) + lo16(v1.y)) + (lo16(v2.y) + lo16(v3.y));
        a3 += (hi16(v0.y) + hi16(v1.y)) + (hi16(v2.y) + hi16(v3.y));
    }
    for (; i < e; ++i) {
        uint2 v0 = yp[(size_t)__builtin_nontemporal_load(csr + i) * 32 + c2];
        a0 += lo16(v0.x);
        a1 += hi16(v0.x);
        a2 += lo16(v0.y);
        a3 += hi16(v0.y);
    }
    float d = dinv[node];
    uint2 o;
    o.x = (unsigned)f2bf(a0 * d) | ((unsigned)f2bf(a1 * d) << 16);
    o.y = (unsigned)f2bf(a2 * d) | ((unsigned)f2bf(a3 * d) << 16);
    ((uint2*)A16)[(size_t)node * 32 + c2] = o;
}

// pack W[K][128] fp32 -> Wp[kb][c] = uint4 of 8 bf16 (k = kb*8+j)
__global__ void wpack_kernel(const float* __restrict__ W, uint4* __restrict__ Wp, int K) {
    int i = blockIdx.x * blockDim.x + threadIdx.x;
    int total = K * 16;
    if (i >= total) return;
    int c = i & 127;
    int kb = i >> 7;
    unsigned short h[8];
#pragma unroll
    for (int j = 0; j < 8; ++j) h[j] = f2bf(W[(size_t)(kb * 8 + j) * 128 + c]);
    uint4 o;
    o.x = (unsigned)h[0] | ((unsigned)h[1] << 16);
    o.y = (unsigned)h[2] | ((unsigned)h[3] << 16);
    o.z = (unsigned)h[4] | ((unsigned)h[5] << 16);
    o.w = (unsigned)h[6] | ((unsigned)h[7] << 16);
    Wp[kb * 128 + c] = o;
}

// MFMA GEMM + fused column stats
template <int K>
__global__ __launch_bounds__(256) void mfma_gemm(const unsigned short* __restrict__ A16,
                                                 const uint4* __restrict__ Bp,
                                                 float* __restrict__ out,
                                                 double* __restrict__ st, int N) {
    constexpr int KS = K / 32;
    __shared__ float cs[128], cs2[128];
    if (threadIdx.x < 128) { cs[threadIdx.x] = 0.f; cs2[threadIdx.x] = 0.f; }
    int w = threadIdx.x >> 6, l = threadIdx.x & 63;
    int cl = l & 15, sub = l >> 4;
    int r0 = blockIdx.x * 64 + w * 16;
    int ra = r0 + cl; if (ra > N - 1) ra = N - 1;

    short8 a[KS];
    const unsigned short* ap = A16 + (size_t)ra * K + sub * 8;
#pragma unroll
    for (int ks = 0; ks < KS; ++ks) a[ks] = *(const short8*)(ap + ks * 32);

    floatx4 acc[8] = {};
#pragma unroll
    for (int cb = 0; cb < 8; ++cb) {
#pragma unroll
        for (int ks = 0; ks < KS; ++ks) {
            short8 b = *(const short8*)&Bp[(ks * 4 + sub) * 128 + cb * 16 + cl];
            acc[cb] = __builtin_amdgcn_mfma_f32_16x16x32_bf16(a[ks], b, acc[cb], 0, 0, 0);
        }
    }
    __syncthreads();   // cs/cs2 init visible
#pragma unroll
    for (int cb = 0; cb < 8; ++cb) {
        float s = 0.f, s2 = 0.f;
#pragma unroll
        for (int j = 0; j < 4; ++j) {
            int row = r0 + sub * 4 + j;
            if (row < N) {
                float val = acc[cb][j];
                out[(size_t)row * 128 + cb * 16 + cl] = val;
                s += val;
                s2 += val * val;
            }
        }
        atomicAdd(&cs[cb * 16 + cl], s);
        atomicAdd(&cs2[cb * 16 + cl], s2);
    }
    __syncthreads();
    if (threadIdx.x < 128) {
        atomicAdd(&st[threadIdx.x], (double)cs[threadIdx.x]);
        atomicAdd(&st[128 + threadIdx.x], (double)cs2[threadIdx.x]);
    }
}

// generic colstats (head, C=256)
__global__ void colstats_kernel(const float* __restrict__ h, int N, int C, int logC,
                                double* __restrict__ st) {
    int c = threadIdx.x & (C - 1);
    int sub = threadIdx.x >> logC;
    int rpb = 256 >> logC;
    float s = 0.f, s2 = 0.f;
    for (int r = blockIdx.x * rpb + sub; r < N; r += gridDim.x * rpb) {
        float v = h[(size_t)r * C + c];
        s += v;
        s2 += v * v;
    }
    atomicAdd(&st[c], (double)s);
    atomicAdd(&st[C + c], (double)s2);
}

__global__ void bnfin_kernel(const double* __restrict__ st, const float* __restrict__ gamma,
                             const float* __restrict__ beta, float2* __restrict__ ss,
                             int N, int C) {
    int c = blockIdx.x * blockDim.x + threadIdx.x;
    if (c >= C) return;
    double mean = st[c] / N;
    double var = st[C + c] / N - mean * mean;
    float sc = (float)((double)gamma[c] / sqrt(var + BN_EPS));
    float sh = beta[c] - (float)mean * sc;
    ss[c] = make_float2(sc, sh);
}

// out16 = bf16(relu(h*scale+shift) * dinv[row]), C=128
__global__ void normrelu_bf(const float* __restrict__ h, const float2* __restrict__ ss,
                            const float* __restrict__ dinv, unsigned short* __restrict__ out,
                            int N) {
    int t = blockIdx.x * blockDim.x + threadIdx.x;
    int total = N * 16;
    if (t >= total) return;
    int r = t >> 4;
    int j = (t & 15) << 3;
    float d = dinv[r];
    float4 a = ((const float4*)h)[t * 2];
    float4 b = ((const float4*)h)[t * 2 + 1];
    float2 s0 = ss[j], s1 = ss[j + 1], s2 = ss[j + 2], s3 = ss[j + 3];
    float2 s4 = ss[j + 4], s5 = ss[j + 5], s6 = ss[j + 6], s7 = ss[j + 7];
    float v0 = fmaxf(a.x * s0.x + s0.y, 0.f) * d;
    float v1 = fmaxf(a.y * s1.x + s1.y, 0.f) * d;
    float v2 = fmaxf(a.z * s2.x + s2.y, 0.f) * d;
    float v3 = fmaxf(a.w * s3.x + s3.y, 0.f) * d;
    float v4 = fmaxf(b.x * s4.x + s4.y, 0.f) * d;
    float v5 = fmaxf(b.y * s5.x + s5.y, 0.f) * d;
    float v6 = fmaxf(b.z * s6.x + s6.y, 0.f) * d;
    float v7 = fmaxf(b.w * s7.x + s7.y, 0.f) * d;
    uint4 o;
    o.x = (unsigned)f2bf(v0) | ((unsigned)f2bf(v1) << 16);
    o.y = (unsigned)f2bf(v2) | ((unsigned)f2bf(v3) << 16);
    o.z = (unsigned)f2bf(v4) | ((unsigned)f2bf(v5) << 16);
    o.w = (unsigned)f2bf(v6) | ((unsigned)f2bf(v7) << 16);
    ((uint4*)out)[t] = o;
}

// graph boundaries from sorted batch
__global__ void bounds_kernel(const int* __restrict__ batch, int* __restrict__ gstart,
                              int N, int G) {
    int i = blockIdx.x * blockDim.x + threadIdx.x;
    if (i >= N) return;
    int bi = batch[i];
    int bp = (i == 0) ? -1 : batch[i - 1];
    for (int g = bp + 1; g <= bi; ++g) gstart[g] = i;
    if (i == N - 1) {
        for (int g = bi + 1; g <= G; ++g) gstart[g] = N;
    }
}

// per-graph mean of relu(bn(h)) over rows, fused BN: pooled[G][128]
__global__ void pool_bn_kernel(const float* __restrict__ h, const float2* __restrict__ ss,
                               const int* __restrict__ gstart, float* __restrict__ pooled) {
    int g = blockIdx.x;
    int c = threadIdx.x;
    float2 sc = ss[c];
    int b = gstart[g], e = gstart[g + 1];
    float acc = 0.f;
    int r = b;
    for (; r + 1 < e; r += 2) {
        float v0 = h[(size_t)r * 128 + c];
        float v1 = h[(size_t)(r + 1) * 128 + c];
        acc += fmaxf(v0 * sc.x + sc.y, 0.f) + fmaxf(v1 * sc.x + sc.y, 0.f);
    }
    if (r < e) acc += fmaxf(h[(size_t)r * 128 + c] * sc.x + sc.y, 0.f);
    pooled[(size_t)g * 128 + c] = acc / fmaxf((float)(e - b), 1.0f);
}

// head gemm (fp32, small): A[N,K] @ W[K,C] + bias -> out[N,C]
template <int K>
__global__ __launch_bounds__(256) void gemm_bias_kernel(const float* __restrict__ A,
                                                        const float* __restrict__ W,
                                                        const float* __restrict__ bias,
                                                        float* __restrict__ out, int N, int C) {
    __shared__ float Wl[K * 128];
    const int ct = blockIdx.y << 7;
    for (int idx = threadIdx.x; idx < K * 128; idx += 256) {
        int kk = idx >> 7, cc = idx & 127;
        Wl[idx] = W[(size_t)kk * C + ct + cc];
    }
    __syncthreads();
    const int cq = (threadIdx.x & 31) << 2;
    const int rg = threadIdx.x >> 5;
    const int r0 = blockIdx.x * 32 + (rg << 2);

    const float* Ap[4];
#pragma unroll
    for (int i = 0; i < 4; ++i) {
        int r = r0 + i;
        Ap[i] = A + (size_t)(r < N ? r : 0) * K;
    }
    float acc[4][4] = {};
#pragma unroll 4
    for (int k = 0; k < K; ++k) {
        float a0 = Ap[0][k];
        float a1 = Ap[1][k];
        float a2 = Ap[2][k];
        float a3 = Ap[3][k];
        float4 w = *(const float4*)&Wl[k * 128 + cq];
        acc[0][0] += a0 * w.x; acc[0][1] += a0 * w.y; acc[0][2] += a0 * w.z; acc[0][3] += a0 * w.w;
        acc[1][0] += a1 * w.x; acc[1][1] += a1 * w.y; acc[1][2] += a1 * w.z; acc[1][3] += a1 * w.w;
        acc[2][0] += a2 * w.x; acc[2][1] += a2 * w.y; acc[2][2] += a2 * w.z; acc[2][3] += a2 * w.w;
        acc[3][0] += a3 * w.x; acc[3][1] += a3 * w.y; acc[3][2] += a3 * w.z; acc[3][3] += a3 * w.w;
    }
    float4 bv = *(const float4*)&bias[ct + cq];
#pragma unroll
    for (int i = 0; i < 4; ++i) {
        int r = r0 + i;
        if (r < N) {
            float4 o = make_float4(acc[i][0] + bv.x, acc[i][1] + bv.y,
                                   acc[i][2] + bv.z, acc[i][3] + bv.w);
            *(float4*)&out[(size_t)r * C + ct + cq] = o;
        }
    }
}

// final: out[g][j] = sum_c relu(bn(z))[g][c] * W4[c][j] + b4[j]
__global__ void head_kernel(const float* __restrict__ z, const float2* __restrict__ ss,
                            const float* __restrict__ W4, const float* __restrict__ b4,
                            float* __restrict__ out, int G) {
    __shared__ float zr[256];
    int g = blockIdx.x;
    int t = threadIdx.x;
    float v = z[(size_t)g * 256 + t];
    zr[t] = fmaxf(v * ss[t].x + ss[t].y, 0.f);
    __syncthreads();
    int j = t >> 4;
    int part = t & 15;
    if (j < 10) {
        float acc = 0.f;
#pragma unroll
        for (int k = 0; k < 16; ++k) {
            int c = part + k * 16;
            acc += zr[c] * W4[c * 10 + j];
        }
#pragma unroll
        for (int off = 8; off; off >>= 1) acc += __shfl_down(acc, off);
        if (part == 0) out[(size_t)g * 10 + j] = acc + b4[j];
    }
}

// ---------------- launch ----------------

extern "C" void kernel_launch(void* const* d_in, const int* in_sizes, int n_in,
                              void* d_out, int out_size, void* d_ws, size_t ws_size,
                              hipStream_t stream) {
    const int N = in_sizes[0] / 64;
    const int E = in_sizes[1] / 2;
    const int G = out_size / 10;

    const float* x     = (const float*)d_in[0];
    const int*   ei    = (const int*)d_in[1];
    const int*   batch = (const int*)d_in[2];
    const float* W1 = (const float*)d_in[3];
    const float* g1 = (const float*)d_in[5];
    const float* be1 = (const float*)d_in[6];
    const float* W2 = (const float*)d_in[7];
    const float* g2 = (const float*)d_in[9];
    const float* be2 = (const float*)d_in[10];
    const float* W3 = (const float*)d_in[11];
    const float* b3 = (const float*)d_in[12];
    const float* g3 = (const float*)d_in[13];
    const float* be3 = (const float*)d_in[14];
    const float* W4 = (const float*)d_in[15];
    const float* b4 = (const float*)d_in[16];
    float* out = (float*)d_out;

    const int* srcp = ei;        // edge_index[0]
    const int* dstp = ei + E;    // edge_index[1]

    // workspace layout
    char* p = (char*)d_ws;
    auto alloc = [&](size_t bytes) {
        void* r = (void*)p;
        p += (bytes + 255) & ~(size_t)255;
        return r;
    };
    unsigned short* A16 = (unsigned short*)alloc((size_t)N * 128 * 2);
    float* Bb = (float*)alloc((size_t)N * 128 * 4);
    char* R3  = (char*)alloc((size_t)N * 128 * 4);   // c16 | y16
    int* csr      = (int*)alloc((size_t)E * 4);
    unsigned* part = (unsigned*)alloc((size_t)E * 4);
    int* rowptr = (int*)alloc((size_t)(N + 1) * 4);
    float* dinv = (float*)alloc((size_t)N * 4);
    int* hist   = (int*)alloc((size_t)256 * PB * 4);
    int* offs   = (int*)alloc((size_t)256 * PB * 4);
    int* bsums  = (int*)alloc(64 * 4);
    uint4* w1p  = (uint4*)alloc((size_t)64 * 128 * 2);
    uint4* w2p  = (uint4*)alloc((size_t)128 * 128 * 2);
    int* gstart = (int*)alloc((size_t)(G + 1) * 4);
    float* pooled = (float*)alloc((size_t)G * 128 * 4);
    float* z      = (float*)alloc((size_t)G * 256 * 4);
    double* st    = (double*)alloc(1024 * 8);
    float2* ss    = (float2*)alloc(512 * 8);
    (void)ws_size; (void)n_in;

    unsigned short* c16 = (unsigned short*)R3;                         // [N*128] bf16
    unsigned short* y16 = (unsigned short*)(R3 + (size_t)N * 128 * 2); // [N*64] bf16

    double* stA = st;
    double* stB = st + 256;
    double* stC = st + 512;
    float2* ssA = ss;
    float2* ssB = ss + 128;
    float2* ssC = ss + 256;

    hipMemsetAsync(st, 0, 1024 * 8, stream);

    const int nb = (N + 255) / 256;
    const int NB = (N + 255) >> 8;
    const int cpb = (((E + PB - 1) / PB) + 3) & ~3;
    const int n2 = NB * PB;
    const int nch2 = (n2 + 1023) / 1024;
    const int aggblocks = (N + 7) / 8;   // 4 waves/block, 2 nodes/wave

    // weight packing (independent)
    wpack_kernel<<<4, 256, 0, stream>>>(W1, w1p, 64);
    wpack_kernel<<<8, 256, 0, stream>>>(W2, w2p, 128);

    // partition edges by dst bucket (no global atomics)
    hist_kernel<<<PB, 256, 0, stream>>>(dstp, hist, E, cpb, NB);
    scan1_kernel<<<nch2, 1024, 0, stream>>>(hist, offs, bsums, n2);
    scan23_add<<<(n2 + 255) / 256, 256, 0, stream>>>(offs, bsums, nch2, n2);
    scatter_kernel<<<PB, 256, 0, stream>>>(srcp, dstp, offs, part, E, cpb, NB);

    // rowptr + dinv directly from partition (LDS count + exscan)
    bucket_rowptr<<<NB, 256, 0, stream>>>(part, offs, rowptr, dinv, E, N, NB);
    bucket_fill<<<NB, 256, 0, stream>>>(part, offs, rowptr, csr, E, N, NB);

    // Layer 1
    prescale64_bf<<<(N * 8 + 255) / 256, 256, 0, stream>>>(x, dinv, y16, N);
    agg64_bf<<<aggblocks, 256, 0, stream>>>(y16, rowptr, csr, dinv, A16, N);
    mfma_gemm<64><<<(N + 63) / 64, 256, 0, stream>>>(A16, w1p, Bb, stA, N);
    bnfin_kernel<<<1, 128, 0, stream>>>(stA, g1, be1, ssA, N, 128);
    normrelu_bf<<<(N * 16 + 255) / 256, 256, 0, stream>>>(Bb, ssA, dinv, c16, N);

    // Layer 2
    agg128_bf<<<aggblocks, 256, 0, stream>>>(c16, rowptr, csr, dinv, A16, N);
    mfma_gemm<128><<<(N + 63) / 64, 256, 0, stream>>>(A16, w2p, Bb, stB, N);
    bnfin_kernel<<<1, 128, 0, stream>>>(stB, g2, be2, ssB, N, 128);

    // Pool (BN+ReLU fused)
    bounds_kernel<<<nb, 256, 0, stream>>>(batch, gstart, N, G);
    pool_bn_kernel<<<G, 128, 0, stream>>>(Bb, ssB, gstart, pooled);

    // Head
    gemm_bias_kernel<128><<<dim3((G + 31) / 32, 2), 256, 0, stream>>>(pooled, W3, b3, z, G, 256);
    colstats_kernel<<<64, 256, 0, stream>>>(z, G, 256, 8, stC);
    bnfin_kernel<<<1, 256, 0, stream>>>(stC, g3, be3, ssC, G, 256);
    head_kernel<<<G, 256, 0, stream>>>(z, ssC, W4, b4, out, G);
}

// Round 9
// 255.853 us; speedup vs baseline: 1.8963x; 1.0576x over previous
//
#include <hip/hip_runtime.h>
#include <hip/hip_bf16.h>

#define BN_EPS 1e-5
#define PB 256   // partition blocks for edge binning

typedef __attribute__((ext_vector_type(8))) short short8;
typedef __attribute__((ext_vector_type(4))) float floatx4;

// ---------------- bf16 helpers ----------------

__device__ __forceinline__ unsigned short f2bf(float f) {
    union { float f; unsigned u; } v; v.f = f;
    unsigned r = v.u + 0x7FFF + ((v.u >> 16) & 1);   // RNE
    return (unsigned short)(r >> 16);
}
__device__ __forceinline__ float bf2f(unsigned short h) {
    union { unsigned u; float f; } v; v.u = ((unsigned)h) << 16;
    return v.f;
}
__device__ __forceinline__ float lo16(unsigned u) { return bf2f((unsigned short)(u & 0xffff)); }
__device__ __forceinline__ float hi16(unsigned u) { return bf2f((unsigned short)(u >> 16)); }

// ---------------- scans ----------------

__global__ void scan1_kernel(const int* __restrict__ in, int* __restrict__ part,
                             int* __restrict__ bsum, int n) {
    __shared__ int s[1024];
    int t = threadIdx.x;
    int i = blockIdx.x * 1024 + t;
    int v = (i < n) ? in[i] : 0;
    s[t] = v;
    __syncthreads();
    for (int off = 1; off < 1024; off <<= 1) {
        int x = (t >= off) ? s[t - off] : 0;
        __syncthreads();
        s[t] += x;
        __syncthreads();
    }
    if (i < n) part[i] = s[t] - v;
    if (t == 1023) bsum[blockIdx.x] = s[1023];
}

// fixup with inline exscan of <=64 block sums
__global__ void scan23_add(int* __restrict__ arr, const int* __restrict__ bsum,
                           int nb, int n) {
    __shared__ int s[64];
    int t = threadIdx.x;
    if (t < 64) s[t] = (t < nb) ? bsum[t] : 0;
    __syncthreads();
    for (int off = 1; off < 64; off <<= 1) {
        int x = (t < 64 && t >= off) ? s[t - off] : 0;
        __syncthreads();
        if (t < 64) s[t] += x;
        __syncthreads();
    }
    int i = blockIdx.x * blockDim.x + t;
    if (i < n) {
        int ch = i >> 10;
        int pre = (ch == 0) ? 0 : s[ch - 1];
        arr[i] += pre;
    }
}

// ---------------- ownership-based CSR build ----------------

__global__ void hist_kernel(const int* __restrict__ dst, int* __restrict__ hist,
                            int E, int cpb, int NB) {
    __shared__ int h[256];
    int t = threadIdx.x;
    if (t < NB) h[t] = 0;
    __syncthreads();
    int base = blockIdx.x * cpb;
    int end = base + cpb; if (end > E) end = E;
    int e = base + t * 4;
    for (; e + 3 < end; e += 1024) {
        int4 d = *(const int4*)(dst + e);
        atomicAdd(&h[d.x >> 8], 1);
        atomicAdd(&h[d.y >> 8], 1);
        atomicAdd(&h[d.z >> 8], 1);
        atomicAdd(&h[d.w >> 8], 1);
    }
    for (; e < end; ++e) atomicAdd(&h[dst[e] >> 8], 1);
    __syncthreads();
    if (t < NB) hist[t * PB + blockIdx.x] = h[t];
}

__global__ void scatter_kernel(const int* __restrict__ src, const int* __restrict__ dst,
                               const int* __restrict__ offs, unsigned* __restrict__ part,
                               int E, int cpb, int NB) {
    __shared__ int cur[256];
    int t = threadIdx.x;
    if (t < NB) cur[t] = offs[t * PB + blockIdx.x];
    __syncthreads();
    int base = blockIdx.x * cpb;
    int end = base + cpb; if (end > E) end = E;
    int e = base + t * 4;
    for (; e + 3 < end; e += 1024) {
        int4 d4 = *(const int4*)(dst + e);
        int4 s4 = *(const int4*)(src + e);
        int dd[4] = {d4.x, d4.y, d4.z, d4.w};
        int sv[4] = {s4.x, s4.y, s4.z, s4.w};
#pragma unroll
        for (int i = 0; i < 4; ++i) {
            int pos = atomicAdd(&cur[dd[i] >> 8], 1);
            part[pos] = ((unsigned)sv[i] << 8) | (unsigned)(dd[i] & 255);
        }
    }
    for (; e < end; ++e) {
        int d = dst[e];
        int pos = atomicAdd(&cur[d >> 8], 1);
        part[pos] = ((unsigned)src[e] << 8) | (unsigned)(d & 255);
    }
}

// one block per bucket: per-node degree via LDS counts + LDS exscan -> rowptr, dinv
__global__ void bucket_rowptr(const unsigned* __restrict__ part, const int* __restrict__ offs,
                              int* __restrict__ rowptr, float* __restrict__ dinv,
                              int E, int N, int NB) {
    __shared__ int cw[256], sc[256];
    int b = blockIdx.x;
    int t = threadIdx.x;
    cw[t] = 0;
    __syncthreads();
    int bstart = offs[b * PB];
    int bend = (b + 1 < NB) ? offs[(b + 1) * PB] : E;
    for (int e = bstart + t; e < bend; e += 256)
        atomicAdd(&cw[part[e] & 255u], 1);
    __syncthreads();
    int c = cw[t];
    sc[t] = c;
    __syncthreads();
    for (int off = 1; off < 256; off <<= 1) {
        int x = (t >= off) ? sc[t - off] : 0;
        __syncthreads();
        sc[t] += x;
        __syncthreads();
    }
    int node = (b << 8) + t;
    if (node < N) {
        rowptr[node] = bstart + sc[t] - c;
        dinv[node] = rsqrtf((float)(c + 1));   // +1 self loop
    }
    if (b == NB - 1 && t == 255) rowptr[N] = E;
}

__global__ void bucket_fill(const unsigned* __restrict__ part, const int* __restrict__ offs,
                            const int* __restrict__ rowptr, int* __restrict__ csr,
                            int E, int N, int NB) {
    __shared__ int cur[256];
    int b = blockIdx.x;
    int t = threadIdx.x;
    int node = (b << 8) + t;
    cur[t] = (node < N) ? rowptr[node] : 0;
    __syncthreads();
    int bstart = offs[b * PB];
    int bend = (b + 1 < NB) ? offs[(b + 1) * PB] : E;
    for (int e = bstart + t; e < bend; e += 256) {
        unsigned pr = part[e];
        int pos = atomicAdd(&cur[pr & 255u], 1);
        csr[pos] = (int)(pr >> 8);
    }
}

// ---------------- GCN pieces ----------------

// y16[v][c] = bf16(x[v][c] * dinv[v]), C=64
__global__ void prescale64_bf(const float* __restrict__ x, const float* __restrict__ dinv,
                              unsigned short* __restrict__ y, int N) {
    int t = blockIdx.x * blockDim.x + threadIdx.x;
    int total = N * 8;
    if (t >= total) return;
    int r = t >> 3;
    float d = dinv[r];
    float4 a = ((const float4*)x)[t * 2];
    float4 b = ((const float4*)x)[t * 2 + 1];
    uint4 o;
    o.x = (unsigned)f2bf(a.x * d) | ((unsigned)f2bf(a.y * d) << 16);
    o.y = (unsigned)f2bf(a.z * d) | ((unsigned)f2bf(a.w * d) << 16);
    o.z = (unsigned)f2bf(b.x * d) | ((unsigned)f2bf(b.y * d) << 16);
    o.w = (unsigned)f2bf(b.z * d) | ((unsigned)f2bf(b.w * d) << 16);
    ((uint4*)y)[t] = o;
}

// 2 nodes per wave, 64 ch: half-wave per node, uint (2ch)/lane, unroll-8 (round-6 form)
__global__ __launch_bounds__(256) void agg64_bf(
    const unsigned short* __restrict__ y, const int* __restrict__ rowptr,
    const int* __restrict__ csr, const float* __restrict__ dinv,
    unsigned short* __restrict__ A16, int N) {
    int wv = (blockIdx.x * blockDim.x + threadIdx.x) >> 6;
    int lane = threadIdx.x & 63;
    int node = wv * 2 + (lane >> 5);
    if (node >= N) return;
    int cu = lane & 31;
    const unsigned* yp = (const unsigned*)y;     // 32 uints per row
    unsigned v = yp[(size_t)node * 32 + cu];
    float a0 = lo16(v), a1 = hi16(v);
    int b = rowptr[node], e = rowptr[node + 1];
    int i = b;
    for (; i + 7 < e; i += 8) {
        int s0 = csr[i], s1 = csr[i + 1], s2 = csr[i + 2], s3 = csr[i + 3];
        int s4 = csr[i + 4], s5 = csr[i + 5], s6 = csr[i + 6], s7 = csr[i + 7];
        unsigned v0 = yp[(size_t)s0 * 32 + cu];
        unsigned v1 = yp[(size_t)s1 * 32 + cu];
        unsigned v2 = yp[(size_t)s2 * 32 + cu];
        unsigned v3 = yp[(size_t)s3 * 32 + cu];
        unsigned v4 = yp[(size_t)s4 * 32 + cu];
        unsigned v5 = yp[(size_t)s5 * 32 + cu];
        unsigned v6 = yp[(size_t)s6 * 32 + cu];
        unsigned v7 = yp[(size_t)s7 * 32 + cu];
        a0 += ((lo16(v0) + lo16(v1)) + (lo16(v2) + lo16(v3)))
            + ((lo16(v4) + lo16(v5)) + (lo16(v6) + lo16(v7)));
        a1 += ((hi16(v0) + hi16(v1)) + (hi16(v2) + hi16(v3)))
            + ((hi16(v4) + hi16(v5)) + (hi16(v6) + hi16(v7)));
    }
    for (; i + 3 < e; i += 4) {
        int s0 = csr[i], s1 = csr[i + 1], s2 = csr[i + 2], s3 = csr[i + 3];
        unsigned v0 = yp[(size_t)s0 * 32 + cu];
        unsigned v1 = yp[(size_t)s1 * 32 + cu];
        unsigned v2 = yp[(size_t)s2 * 32 + cu];
        unsigned v3 = yp[(size_t)s3 * 32 + cu];
        a0 += (lo16(v0) + lo16(v1)) + (lo16(v2) + lo16(v3));
        a1 += (hi16(v0) + hi16(v1)) + (hi16(v2) + hi16(v3));
    }
    for (; i < e; ++i) {
        unsigned v0 = yp[(size_t)csr[i] * 32 + cu];
        a0 += lo16(v0);
        a1 += hi16(v0);
    }
    float d = dinv[node];
    ((unsigned*)A16)[(size_t)node * 32 + cu] =
        (unsigned)f2bf(a0 * d) | ((unsigned)f2bf(a1 * d) << 16);
}

// 2 nodes per wave, 128 ch: half-wave per node, uint2 (4ch)/lane, unroll-8 (round-6 form)
__global__ __launch_bounds__(256) void agg128_bf(
    const unsigned short* __restrict__ y, const int* __restrict__ rowptr,
    const int* __restrict__ csr, const float* __restrict__ dinv,
    unsigned short* __restrict__ A16, int N) {
    int wv = (blockIdx.x * blockDim.x + threadIdx.x) >> 6;
    int lane = threadIdx.x & 63;
    int node = wv * 2 + (lane >> 5);
    if (node >= N) return;
    int c2 = lane & 31;
    const uint2* yp = (const uint2*)y;           // 32 uint2 per row
    uint2 v = yp[(size_t)node * 32 + c2];
    float a0 = lo16(v.x), a1 = hi16(v.x), a2 = lo16(v.y), a3 = hi16(v.y);
    int b = rowptr[node], e = rowptr[node + 1];
    int i = b;
    for (; i + 7 < e; i += 8) {
        int s0 = csr[i], s1 = csr[i + 1], s2 = csr[i + 2], s3 = csr[i + 3];
        int s4 = csr[i + 4], s5 = csr[i + 5], s6 = csr[i + 6], s7 = csr[i + 7];
        uint2 v0 = yp[(size_t)s0 * 32 + c2];
        uint2 v1 = yp[(size_t)s1 * 32 + c2];
        uint2 v2 = yp[(size_t)s2 * 32 + c2];
        uint2 v3 = yp[(size_t)s3 * 32 + c2];
        uint2 v4 = yp[(size_t)s4 * 32 + c2];
        uint2 v5 = yp[(size_t)s5 * 32 + c2];
        uint2 v6 = yp[(size_t)s6 * 32 + c2];
        uint2 v7 = yp[(size_t)s7 * 32 + c2];
        a0 += ((lo16(v0.x) + lo16(v1.x)) + (lo16(v2.x) + lo16(v3.x)))
            + ((lo16(v4.x) + lo16(v5.x)) + (lo16(v6.x) + lo16(v7.x)));
        a1 += ((hi16(v0.x) + hi16(v1.x)) + (hi16(v2.x) + hi16(v3.x)))
            + ((hi16(v4.x) + hi16(v5.x)) + (hi16(v6.x) + hi16(v7.x)));
        a2 += ((lo16(v0.y) + lo16(v1.y)) + (lo16(v2.y) + lo16(v3.y)))
            + ((lo16(v4.y) + lo16(v5.y)) + (lo16(v6.y) + lo16(v7.y)));
        a3 += ((hi16(v0.y) + hi16(v1.y)) + (hi16(v2.y) + hi16(v3.y)))
            + ((hi16(v4.y) + hi16(v5.y)) + (hi16(v6.y) + hi16(v7.y)));
    }
    for (; i + 3 < e; i += 4) {
        int s0 = csr[i], s1 = csr[i + 1], s2 = csr[i + 2], s3 = csr[i + 3];
        uint2 v0 = yp[(size_t)s0 * 32 + c2];
        uint2 v1 = yp[(size_t)s1 * 32 + c2];
        uint2 v2 = yp[(size_t)s2 * 32 + c2];
        uint2 v3 = yp[(size_t)s3 * 32 + c2];
        a0 += (lo16(v0.x) + lo16(v1.x)) + (lo16(v2.x) + lo16(v3.x));
        a1 += (hi16(v0.x) + hi16(v1.x)) + (hi16(v2.x) + hi16(v3.x));
        a2 += (lo16(v0.y) + lo16(v1.y)) + (lo16(v2.y) + lo16(v3.y));
        a3 += (hi16(v0.y) + hi16(v1.y)) + (hi16(v2.y) + hi16(v3.y));
    }
    for (; i < e; ++i) {
        uint2 v0 = yp[(size_t)csr[i] * 32 + c2];
        a0 += lo16(v0.x);
        a1 += hi16(v0.x);
        a2 += lo16(v0.y);
        a3 += hi16(v0.y);
    }
    float d = dinv[node];
    uint2 o;
    o.x = (unsigned)f2bf(a0 * d) | ((unsigned)f2bf(a1 * d) << 16);
    o.y = (unsigned)f2bf(a2 * d) | ((unsigned)f2bf(a3 * d) << 16);
    ((uint2*)A16)[(size_t)node * 32 + c2] = o;
}

// pack W[K][128] fp32 -> Wp[kb][c] = uint4 of 8 bf16 (k = kb*8+j)
__global__ void wpack_kernel(const float* __restrict__ W, uint4* __restrict__ Wp, int K) {
    int i = blockIdx.x * blockDim.x + threadIdx.x;
    int total = K * 16;
    if (i >= total) return;
    int c = i & 127;
    int kb = i >> 7;
    unsigned short h[8];
#pragma unroll
    for (int j = 0; j < 8; ++j) h[j] = f2bf(W[(size_t)(kb * 8 + j) * 128 + c]);
    uint4 o;
    o.x = (unsigned)h[0] | ((unsigned)h[1] << 16);
    o.y = (unsigned)h[2] | ((unsigned)h[3] << 16);
    o.z = (unsigned)h[4] | ((unsigned)h[5] << 16);
    o.w = (unsigned)h[6] | ((unsigned)h[7] << 16);
    Wp[kb * 128 + c] = o;
}

// MFMA GEMM + fused column stats; output stored bf16 (stats from fp32 acc)
template <int K>
__global__ __launch_bounds__(256) void mfma_gemm(const unsigned short* __restrict__ A16,
                                                 const uint4* __restrict__ Bp,
                                                 unsigned short* __restrict__ out16,
                                                 double* __restrict__ st, int N) {
    constexpr int KS = K / 32;
    __shared__ float cs[128], cs2[128];
    if (threadIdx.x < 128) { cs[threadIdx.x] = 0.f; cs2[threadIdx.x] = 0.f; }
    int w = threadIdx.x >> 6, l = threadIdx.x & 63;
    int cl = l & 15, sub = l >> 4;
    int r0 = blockIdx.x * 64 + w * 16;
    int ra = r0 + cl; if (ra > N - 1) ra = N - 1;

    short8 a[KS];
    const unsigned short* ap = A16 + (size_t)ra * K + sub * 8;
#pragma unroll
    for (int ks = 0; ks < KS; ++ks) a[ks] = *(const short8*)(ap + ks * 32);

    floatx4 acc[8] = {};
#pragma unroll
    for (int cb = 0; cb < 8; ++cb) {
#pragma unroll
        for (int ks = 0; ks < KS; ++ks) {
            short8 b = *(const short8*)&Bp[(ks * 4 + sub) * 128 + cb * 16 + cl];
            acc[cb] = __builtin_amdgcn_mfma_f32_16x16x32_bf16(a[ks], b, acc[cb], 0, 0, 0);
        }
    }
    __syncthreads();   // cs/cs2 init visible
#pragma unroll
    for (int cb = 0; cb < 8; ++cb) {
        float s = 0.f, s2 = 0.f;
#pragma unroll
        for (int j = 0; j < 4; ++j) {
            int row = r0 + sub * 4 + j;
            if (row < N) {
                float val = acc[cb][j];
                out16[(size_t)row * 128 + cb * 16 + cl] = f2bf(val);
                s += val;
                s2 += val * val;
            }
        }
        atomicAdd(&cs[cb * 16 + cl], s);
        atomicAdd(&cs2[cb * 16 + cl], s2);
    }
    __syncthreads();
    if (threadIdx.x < 128) {
        atomicAdd(&st[threadIdx.x], (double)cs[threadIdx.x]);
        atomicAdd(&st[128 + threadIdx.x], (double)cs2[threadIdx.x]);
    }
}

// out16 = bf16(relu(h*sc+sh) * dinv[row]) from bf16 h; BN params computed in LDS from st
__global__ __launch_bounds__(256) void normrelu_bf(
    const unsigned short* __restrict__ h16, const double* __restrict__ st,
    const float* __restrict__ gamma, const float* __restrict__ beta,
    const float* __restrict__ dinv, unsigned short* __restrict__ out, int N) {
    __shared__ float2 ssl[128];
    if (threadIdx.x < 128) {
        int c = threadIdx.x;
        double mean = st[c] / N;
        double var = st[128 + c] / N - mean * mean;
        float sc = (float)((double)gamma[c] / sqrt(var + BN_EPS));
        float sh = beta[c] - (float)mean * sc;
        ssl[c] = make_float2(sc, sh);
    }
    __syncthreads();
    int t = blockIdx.x * blockDim.x + threadIdx.x;
    int total = N * 16;
    if (t >= total) return;
    int r = t >> 4;
    int j = (t & 15) << 3;
    float d = dinv[r];
    uint4 hv = ((const uint4*)h16)[t];
    float2 s0 = ssl[j], s1 = ssl[j + 1], s2 = ssl[j + 2], s3 = ssl[j + 3];
    float2 s4 = ssl[j + 4], s5 = ssl[j + 5], s6 = ssl[j + 6], s7 = ssl[j + 7];
    float v0 = fmaxf(lo16(hv.x) * s0.x + s0.y, 0.f) * d;
    float v1 = fmaxf(hi16(hv.x) * s1.x + s1.y, 0.f) * d;
    float v2 = fmaxf(lo16(hv.y) * s2.x + s2.y, 0.f) * d;
    float v3 = fmaxf(hi16(hv.y) * s3.x + s3.y, 0.f) * d;
    float v4 = fmaxf(lo16(hv.z) * s4.x + s4.y, 0.f) * d;
    float v5 = fmaxf(hi16(hv.z) * s5.x + s5.y, 0.f) * d;
    float v6 = fmaxf(lo16(hv.w) * s6.x + s6.y, 0.f) * d;
    float v7 = fmaxf(hi16(hv.w) * s7.x + s7.y, 0.f) * d;
    uint4 o;
    o.x = (unsigned)f2bf(v0) | ((unsigned)f2bf(v1) << 16);
    o.y = (unsigned)f2bf(v2) | ((unsigned)f2bf(v3) << 16);
    o.z = (unsigned)f2bf(v4) | ((unsigned)f2bf(v5) << 16);
    o.w = (unsigned)f2bf(v6) | ((unsigned)f2bf(v7) << 16);
    ((uint4*)out)[t] = o;
}

// graph boundaries from sorted batch
__global__ void bounds_kernel(const int* __restrict__ batch, int* __restrict__ gstart,
                              int N, int G) {
    int i = blockIdx.x * blockDim.x + threadIdx.x;
    if (i >= N) return;
    int bi = batch[i];
    int bp = (i == 0) ? -1 : batch[i - 1];
    for (int g = bp + 1; g <= bi; ++g) gstart[g] = i;
    if (i == N - 1) {
        for (int g = bi + 1; g <= G; ++g) gstart[g] = N;
    }
}

// per-graph mean of relu(bn(h16)); BN params inline from st (one col per thread)
__global__ void pool_bn_kernel(const unsigned short* __restrict__ h16,
                               const double* __restrict__ st,
                               const float* __restrict__ gamma, const float* __restrict__ beta,
                               const int* __restrict__ gstart, float* __restrict__ pooled,
                               int N) {
    int g = blockIdx.x;
    int c = threadIdx.x;
    double mean = st[c] / N;
    double var = st[128 + c] / N - mean * mean;
    float sc = (float)((double)gamma[c] / sqrt(var + BN_EPS));
    float sh = beta[c] - (float)mean * sc;
    int b = gstart[g], e = gstart[g + 1];
    float acc = 0.f;
    int r = b;
    for (; r + 1 < e; r += 2) {
        float v0 = bf2f(h16[(size_t)r * 128 + c]);
        float v1 = bf2f(h16[(size_t)(r + 1) * 128 + c]);
        acc += fmaxf(v0 * sc + sh, 0.f) + fmaxf(v1 * sc + sh, 0.f);
    }
    if (r < e) acc += fmaxf(bf2f(h16[(size_t)r * 128 + c]) * sc + sh, 0.f);
    pooled[(size_t)g * 128 + c] = acc / fmaxf((float)(e - b), 1.0f);
}

// head gemm (fp32) + fused column stats: z = A@W+bias, st[ct..] += colsum/colsumsq
template <int K>
__global__ __launch_bounds__(256) void gemm_bias_stats(const float* __restrict__ A,
                                                       const float* __restrict__ W,
                                                       const float* __restrict__ bias,
                                                       float* __restrict__ out,
                                                       double* __restrict__ st,
                                                       int N, int C) {
    __shared__ float Wl[K * 128];
    __shared__ float cs[128], cs2[128];
    if (threadIdx.x < 128) { cs[threadIdx.x] = 0.f; cs2[threadIdx.x] = 0.f; }
    const int ct = blockIdx.y << 7;
    for (int idx = threadIdx.x; idx < K * 128; idx += 256) {
        int kk = idx >> 7, cc = idx & 127;
        Wl[idx] = W[(size_t)kk * C + ct + cc];
    }
    __syncthreads();
    const int cq = (threadIdx.x & 31) << 2;
    const int rg = threadIdx.x >> 5;
    const int r0 = blockIdx.x * 32 + (rg << 2);

    const float* Ap[4];
#pragma unroll
    for (int i = 0; i < 4; ++i) {
        int r = r0 + i;
        Ap[i] = A + (size_t)(r < N ? r : 0) * K;
    }
    float acc[4][4] = {};
#pragma unroll 4
    for (int k = 0; k < K; ++k) {
        float a0 = Ap[0][k];
        float a1 = Ap[1][k];
        float a2 = Ap[2][k];
        float a3 = Ap[3][k];
        float4 w = *(const float4*)&Wl[k * 128 + cq];
        acc[0][0] += a0 * w.x; acc[0][1] += a0 * w.y; acc[0][2] += a0 * w.z; acc[0][3] += a0 * w.w;
        acc[1][0] += a1 * w.x; acc[1][1] += a1 * w.y; acc[1][2] += a1 * w.z; acc[1][3] += a1 * w.w;
        acc[2][0] += a2 * w.x; acc[2][1] += a2 * w.y; acc[2][2] += a2 * w.z; acc[2][3] += a2 * w.w;
        acc[3][0] += a3 * w.x; acc[3][1] += a3 * w.y; acc[3][2] += a3 * w.z; acc[3][3] += a3 * w.w;
    }
    float4 bv = *(const float4*)&bias[ct + cq];
    float s[4] = {}, s2[4] = {};
#pragma unroll
    for (int i = 0; i < 4; ++i) {
        int r = r0 + i;
        if (r < N) {
            float o0 = acc[i][0] + bv.x, o1 = acc[i][1] + bv.y;
            float o2 = acc[i][2] + bv.z, o3 = acc[i][3] + bv.w;
            *(float4*)&out[(size_t)r * C + ct + cq] = make_float4(o0, o1, o2, o3);
            s[0] += o0; s2[0] += o0 * o0;
            s[1] += o1; s2[1] += o1 * o1;
            s[2] += o2; s2[2] += o2 * o2;
            s[3] += o3; s2[3] += o3 * o3;
        }
    }
#pragma unroll
    for (int jj = 0; jj < 4; ++jj) {
        atomicAdd(&cs[cq + jj], s[jj]);
        atomicAdd(&cs2[cq + jj], s2[jj]);
    }
    __syncthreads();
    if (threadIdx.x < 128) {
        atomicAdd(&st[ct + threadIdx.x], (double)cs[threadIdx.x]);
        atomicAdd(&st[C + ct + threadIdx.x], (double)cs2[threadIdx.x]);
    }
}

// final: out[g][j] = sum_c relu(bn(z))[g][c] * W4[c][j] + b4[j]; BN inline from st
__global__ void head_kernel(const float* __restrict__ z, const double* __restrict__ st,
                            const float* __restrict__ gamma, const float* __restrict__ beta,
                            const float* __restrict__ W4, const float* __restrict__ b4,
                            float* __restrict__ out, int G) {
    __shared__ float zr[256];
    int g = blockIdx.x;
    int t = threadIdx.x;
    double mean = st[t] / G;
    double var = st[256 + t] / G - mean * mean;
    float sc = (float)((double)gamma[t] / sqrt(var + BN_EPS));
    float sh = beta[t] - (float)mean * sc;
    float v = z[(size_t)g * 256 + t];
    zr[t] = fmaxf(v * sc + sh, 0.f);
    __syncthreads();
    int j = t >> 4;
    int part = t & 15;
    if (j < 10) {
        float acc = 0.f;
#pragma unroll
        for (int k = 0; k < 16; ++k) {
            int c = part + k * 16;
            acc += zr[c] * W4[c * 10 + j];
        }
#pragma unroll
        for (int off = 8; off; off >>= 1) acc += __shfl_down(acc, off);
        if (part == 0) out[(size_t)g * 10 + j] = acc + b4[j];
    }
}

// ---------------- launch ----------------

extern "C" void kernel_launch(void* const* d_in, const int* in_sizes, int n_in,
                              void* d_out, int out_size, void* d_ws, size_t ws_size,
                              hipStream_t stream) {
    const int N = in_sizes[0] / 64;
    const int E = in_sizes[1] / 2;
    const int G = out_size / 10;

    const float* x     = (const float*)d_in[0];
    const int*   ei    = (const int*)d_in[1];
    const int*   batch = (const int*)d_in[2];
    const float* W1 = (const float*)d_in[3];
    const float* g1 = (const float*)d_in[5];
    const float* be1 = (const float*)d_in[6];
    const float* W2 = (const float*)d_in[7];
    const float* g2 = (const float*)d_in[9];
    const float* be2 = (const float*)d_in[10];
    const float* W3 = (const float*)d_in[11];
    const float* b3 = (const float*)d_in[12];
    const float* g3 = (const float*)d_in[13];
    const float* be3 = (const float*)d_in[14];
    const float* W4 = (const float*)d_in[15];
    const float* b4 = (const float*)d_in[16];
    float* out = (float*)d_out;

    const int* srcp = ei;        // edge_index[0]
    const int* dstp = ei + E;    // edge_index[1]

    // workspace layout
    char* p = (char*)d_ws;
    auto alloc = [&](size_t bytes) {
        void* r = (void*)p;
        p += (bytes + 255) & ~(size_t)255;
        return r;
    };
    unsigned short* A16 = (unsigned short*)alloc((size_t)N * 128 * 2);
    unsigned short* h16 = (unsigned short*)alloc((size_t)N * 128 * 2);   // gemm out bf16
    char* R3  = (char*)alloc((size_t)N * 128 * 4);   // c16 | y16
    int* csr      = (int*)alloc((size_t)E * 4);
    unsigned* part = (unsigned*)alloc((size_t)E * 4);
    int* rowptr = (int*)alloc((size_t)(N + 1) * 4);
    float* dinv = (float*)alloc((size_t)N * 4);
    int* hist   = (int*)alloc((size_t)256 * PB * 4);
    int* offs   = (int*)alloc((size_t)256 * PB * 4);
    int* bsums  = (int*)alloc(64 * 4);
    uint4* w1p  = (uint4*)alloc((size_t)64 * 128 * 2);
    uint4* w2p  = (uint4*)alloc((size_t)128 * 128 * 2);
    int* gstart = (int*)alloc((size_t)(G + 1) * 4);
    float* pooled = (float*)alloc((size_t)G * 128 * 4);
    float* z      = (float*)alloc((size_t)G * 256 * 4);
    double* st    = (double*)alloc(1024 * 8);
    (void)ws_size; (void)n_in;

    unsigned short* c16 = (unsigned short*)R3;                         // [N*128] bf16
    unsigned short* y16 = (unsigned short*)(R3 + (size_t)N * 128 * 2); // [N*64] bf16

    double* stA = st;
    double* stB = st + 256;
    double* stC = st + 512;

    hipMemsetAsync(st, 0, 1024 * 8, stream);

    const int nb = (N + 255) / 256;
    const int NB = (N + 255) >> 8;
    const int cpb = (((E + PB - 1) / PB) + 3) & ~3;
    const int n2 = NB * PB;
    const int nch2 = (n2 + 1023) / 1024;
    const int aggblocks = (N + 7) / 8;   // 4 waves/block, 2 nodes/wave

    // weight packing (independent)
    wpack_kernel<<<4, 256, 0, stream>>>(W1, w1p, 64);
    wpack_kernel<<<8, 256, 0, stream>>>(W2, w2p, 128);

    // partition edges by dst bucket (no global atomics)
    hist_kernel<<<PB, 256, 0, stream>>>(dstp, hist, E, cpb, NB);
    scan1_kernel<<<nch2, 1024, 0, stream>>>(hist, offs, bsums, n2);
    scan23_add<<<(n2 + 255) / 256, 256, 0, stream>>>(offs, bsums, nch2, n2);
    scatter_kernel<<<PB, 256, 0, stream>>>(srcp, dstp, offs, part, E, cpb, NB);

    // rowptr + dinv directly from partition
    bucket_rowptr<<<NB, 256, 0, stream>>>(part, offs, rowptr, dinv, E, N, NB);
    bucket_fill<<<NB, 256, 0, stream>>>(part, offs, rowptr, csr, E, N, NB);

    // Layer 1
    prescale64_bf<<<(N * 8 + 255) / 256, 256, 0, stream>>>(x, dinv, y16, N);
    agg64_bf<<<aggblocks, 256, 0, stream>>>(y16, rowptr, csr, dinv, A16, N);
    mfma_gemm<64><<<(N + 63) / 64, 256, 0, stream>>>(A16, w1p, h16, stA, N);
    normrelu_bf<<<(N * 16 + 255) / 256, 256, 0, stream>>>(h16, stA, g1, be1, dinv, c16, N);

    // Layer 2
    agg128_bf<<<aggblocks, 256, 0, stream>>>(c16, rowptr, csr, dinv, A16, N);
    mfma_gemm<128><<<(N + 63) / 64, 256, 0, stream>>>(A16, w2p, h16, stB, N);

    // Pool (BN+ReLU fused, inline BN params)
    bounds_kernel<<<nb, 256, 0, stream>>>(batch, gstart, N, G);
    pool_bn_kernel<<<G, 128, 0, stream>>>(h16, stB, g2, be2, gstart, pooled, N);

    // Head (gemm + stats fused; BN inline in head)
    gemm_bias_stats<128><<<dim3((G + 31) / 32, 2), 256, 0, stream>>>(pooled, W3, b3, z, stC, G, 256);
    head_kernel<<<G, 256, 0, stream>>>(z, stC, g3, be3, W4, b4, out, G);
}

// Round 10
// 248.308 us; speedup vs baseline: 1.9539x; 1.0304x over previous
//
#include <hip/hip_runtime.h>
#include <hip/hip_bf16.h>

#define BN_EPS 1e-5
#define PB 256   // partition blocks for edge binning

typedef __attribute__((ext_vector_type(8))) short short8;
typedef __attribute__((ext_vector_type(4))) float floatx4;

// ---------------- bf16 helpers ----------------

__device__ __forceinline__ unsigned short f2bf(float f) {
    union { float f; unsigned u; } v; v.f = f;
    unsigned r = v.u + 0x7FFF + ((v.u >> 16) & 1);   // RNE
    return (unsigned short)(r >> 16);
}
__device__ __forceinline__ float bf2f(unsigned short h) {
    union { unsigned u; float f; } v; v.u = ((unsigned)h) << 16;
    return v.f;
}
__device__ __forceinline__ float lo16(unsigned u) { return bf2f((unsigned short)(u & 0xffff)); }
__device__ __forceinline__ float hi16(unsigned u) { return bf2f((unsigned short)(u >> 16)); }

// ---------------- fused setup: wpack(W1) | wpack(W2) | bounds | hist ----------------

__device__ __forceinline__ void wpack_body(const float* __restrict__ W, uint4* __restrict__ Wp,
                                           int K, int i) {
    if (i >= K * 16) return;
    int c = i & 127;
    int kb = i >> 7;
    unsigned short h[8];
#pragma unroll
    for (int j = 0; j < 8; ++j) h[j] = f2bf(W[(size_t)(kb * 8 + j) * 128 + c]);
    uint4 o;
    o.x = (unsigned)h[0] | ((unsigned)h[1] << 16);
    o.y = (unsigned)h[2] | ((unsigned)h[3] << 16);
    o.z = (unsigned)h[4] | ((unsigned)h[5] << 16);
    o.w = (unsigned)h[6] | ((unsigned)h[7] << 16);
    Wp[kb * 128 + c] = o;
}

__global__ void setup_kernel(const float* __restrict__ W1, uint4* __restrict__ w1p,
                             const float* __restrict__ W2, uint4* __restrict__ w2p,
                             const int* __restrict__ batch, int* __restrict__ gstart,
                             const int* __restrict__ dst, int* __restrict__ hist,
                             int N, int G, int E, int cpb, int NB, int nb) {
    __shared__ int h[256];
    int t = threadIdx.x;
    int b = blockIdx.x;
    if (b < 4) {                         // wpack W1 (K=64, 1024 elems)
        wpack_body(W1, w1p, 64, b * 256 + t);
    } else if (b < 12) {                 // wpack W2 (K=128, 2048 elems)
        wpack_body(W2, w2p, 128, (b - 4) * 256 + t);
    } else if (b < 12 + nb) {            // bounds
        int i = (b - 12) * 256 + t;
        if (i < N) {
            int bi = batch[i];
            int bp = (i == 0) ? -1 : batch[i - 1];
            for (int g = bp + 1; g <= bi; ++g) gstart[g] = i;
            if (i == N - 1) {
                for (int g = bi + 1; g <= G; ++g) gstart[g] = N;
            }
        }
    } else {                             // hist
        int blk = b - 12 - nb;           // 0..PB-1
        if (t < NB) h[t] = 0;
        __syncthreads();
        int base = blk * cpb;
        int end = base + cpb; if (end > E) end = E;
        int e = base + t * 4;
        for (; e + 3 < end; e += 1024) {
            int4 d = *(const int4*)(dst + e);
            atomicAdd(&h[d.x >> 8], 1);
            atomicAdd(&h[d.y >> 8], 1);
            atomicAdd(&h[d.z >> 8], 1);
            atomicAdd(&h[d.w >> 8], 1);
        }
        for (; e < end; ++e) atomicAdd(&h[dst[e] >> 8], 1);
        __syncthreads();
        if (t < NB) hist[t * PB + blk] = h[t];
    }
}

// ---------------- scans ----------------

__global__ void scan1_kernel(const int* __restrict__ in, int* __restrict__ part,
                             int* __restrict__ bsum, int n) {
    __shared__ int s[1024];
    int t = threadIdx.x;
    int i = blockIdx.x * 1024 + t;
    int v = (i < n) ? in[i] : 0;
    s[t] = v;
    __syncthreads();
    for (int off = 1; off < 1024; off <<= 1) {
        int x = (t >= off) ? s[t - off] : 0;
        __syncthreads();
        s[t] += x;
        __syncthreads();
    }
    if (i < n) part[i] = s[t] - v;
    if (t == 1023) bsum[blockIdx.x] = s[1023];
}

// fixup with inline exscan of <=64 block sums
__global__ void scan23_add(int* __restrict__ arr, const int* __restrict__ bsum,
                           int nb, int n) {
    __shared__ int s[64];
    int t = threadIdx.x;
    if (t < 64) s[t] = (t < nb) ? bsum[t] : 0;
    __syncthreads();
    for (int off = 1; off < 64; off <<= 1) {
        int x = (t < 64 && t >= off) ? s[t - off] : 0;
        __syncthreads();
        if (t < 64) s[t] += x;
        __syncthreads();
    }
    int i = blockIdx.x * blockDim.x + t;
    if (i < n) {
        int ch = i >> 10;
        int pre = (ch == 0) ? 0 : s[ch - 1];
        arr[i] += pre;
    }
}

// ---------------- CSR build ----------------

__global__ void scatter_kernel(const int* __restrict__ src, const int* __restrict__ dst,
                               const int* __restrict__ offs, unsigned* __restrict__ part,
                               int E, int cpb, int NB) {
    __shared__ int cur[256];
    int t = threadIdx.x;
    if (t < NB) cur[t] = offs[t * PB + blockIdx.x];
    __syncthreads();
    int base = blockIdx.x * cpb;
    int end = base + cpb; if (end > E) end = E;
    int e = base + t * 4;
    for (; e + 3 < end; e += 1024) {
        int4 d4 = *(const int4*)(dst + e);
        int4 s4 = *(const int4*)(src + e);
        int dd[4] = {d4.x, d4.y, d4.z, d4.w};
        int sv[4] = {s4.x, s4.y, s4.z, s4.w};
#pragma unroll
        for (int i = 0; i < 4; ++i) {
            int pos = atomicAdd(&cur[dd[i] >> 8], 1);
            part[pos] = ((unsigned)sv[i] << 8) | (unsigned)(dd[i] & 255);
        }
    }
    for (; e < end; ++e) {
        int d = dst[e];
        int pos = atomicAdd(&cur[d >> 8], 1);
        part[pos] = ((unsigned)src[e] << 8) | (unsigned)(d & 255);
    }
}

// one block per bucket: count (LDS) -> exscan (LDS) -> rowptr/dinv -> csr fill
// -> prescale this bucket's 256 nodes (y16 = bf16(x*dinv))
__global__ __launch_bounds__(256) void bucket_build(
    const unsigned* __restrict__ part, const int* __restrict__ offs,
    int* __restrict__ rowptr, float* __restrict__ dinv, int* __restrict__ csr,
    const float* __restrict__ x, unsigned short* __restrict__ y16,
    int E, int N, int NB) {
    __shared__ int cw[256], sc[256], cur[256];
    __shared__ float sd[256];
    int b = blockIdx.x;
    int t = threadIdx.x;
    cw[t] = 0;
    __syncthreads();
    int bstart = offs[b * PB];
    int bend = (b + 1 < NB) ? offs[(b + 1) * PB] : E;
    for (int e = bstart + t; e < bend; e += 256)
        atomicAdd(&cw[part[e] & 255u], 1);
    __syncthreads();
    int c = cw[t];
    sc[t] = c;
    __syncthreads();
    for (int off = 1; off < 256; off <<= 1) {
        int v = (t >= off) ? sc[t - off] : 0;
        __syncthreads();
        sc[t] += v;
        __syncthreads();
    }
    int node = (b << 8) + t;
    int start = bstart + sc[t] - c;
    float d = rsqrtf((float)(c + 1));    // +1 self loop
    cur[t] = start;
    sd[t] = d;
    if (node < N) {
        rowptr[node] = start;
        dinv[node] = d;
    }
    if (b == NB - 1 && t == 255) rowptr[N] = E;
    __syncthreads();
    for (int e = bstart + t; e < bend; e += 256) {
        unsigned pr = part[e];
        int pos = atomicAdd(&cur[pr & 255u], 1);
        csr[pos] = (int)(pr >> 8);
    }
    // prescale: y16[node][0..64) = bf16(x[node][c] * dinv[node]) for this bucket
    int base = b << 8;
    int nlocal = N - base; if (nlocal > 256) nlocal = 256;
    if (nlocal <= 0) return;
    for (int idx = t; idx < nlocal * 8; idx += 256) {
        int r = idx >> 3, k = idx & 7;
        int nd = base + r;
        float dd = sd[r];
        const float4* xp = (const float4*)(x + (size_t)nd * 64 + k * 8);
        float4 a = xp[0];
        float4 bb = xp[1];
        uint4 o;
        o.x = (unsigned)f2bf(a.x * dd) | ((unsigned)f2bf(a.y * dd) << 16);
        o.y = (unsigned)f2bf(a.z * dd) | ((unsigned)f2bf(a.w * dd) << 16);
        o.z = (unsigned)f2bf(bb.x * dd) | ((unsigned)f2bf(bb.y * dd) << 16);
        o.w = (unsigned)f2bf(bb.z * dd) | ((unsigned)f2bf(bb.w * dd) << 16);
        *(uint4*)(y16 + (size_t)nd * 64 + k * 8) = o;
    }
}

// ---------------- aggregation (round-6 proven form) ----------------

// 2 nodes per wave, 64 ch: half-wave per node, uint (2ch)/lane, unroll-8
__global__ __launch_bounds__(256) void agg64_bf(
    const unsigned short* __restrict__ y, const int* __restrict__ rowptr,
    const int* __restrict__ csr, const float* __restrict__ dinv,
    unsigned short* __restrict__ A16, int N) {
    int wv = (blockIdx.x * blockDim.x + threadIdx.x) >> 6;
    int lane = threadIdx.x & 63;
    int node = wv * 2 + (lane >> 5);
    if (node >= N) return;
    int cu = lane & 31;
    const unsigned* yp = (const unsigned*)y;     // 32 uints per row
    unsigned v = yp[(size_t)node * 32 + cu];
    float a0 = lo16(v), a1 = hi16(v);
    int b = rowptr[node], e = rowptr[node + 1];
    int i = b;
    for (; i + 7 < e; i += 8) {
        int s0 = csr[i], s1 = csr[i + 1], s2 = csr[i + 2], s3 = csr[i + 3];
        int s4 = csr[i + 4], s5 = csr[i + 5], s6 = csr[i + 6], s7 = csr[i + 7];
        unsigned v0 = yp[(size_t)s0 * 32 + cu];
        unsigned v1 = yp[(size_t)s1 * 32 + cu];
        unsigned v2 = yp[(size_t)s2 * 32 + cu];
        unsigned v3 = yp[(size_t)s3 * 32 + cu];
        unsigned v4 = yp[(size_t)s4 * 32 + cu];
        unsigned v5 = yp[(size_t)s5 * 32 + cu];
        unsigned v6 = yp[(size_t)s6 * 32 + cu];
        unsigned v7 = yp[(size_t)s7 * 32 + cu];
        a0 += ((lo16(v0) + lo16(v1)) + (lo16(v2) + lo16(v3)))
            + ((lo16(v4) + lo16(v5)) + (lo16(v6) + lo16(v7)));
        a1 += ((hi16(v0) + hi16(v1)) + (hi16(v2) + hi16(v3)))
            + ((hi16(v4) + hi16(v5)) + (hi16(v6) + hi16(v7)));
    }
    for (; i + 3 < e; i += 4) {
        int s0 = csr[i], s1 = csr[i + 1], s2 = csr[i + 2], s3 = csr[i + 3];
        unsigned v0 = yp[(size_t)s0 * 32 + cu];
        unsigned v1 = yp[(size_t)s1 * 32 + cu];
        unsigned v2 = yp[(size_t)s2 * 32 + cu];
        unsigned v3 = yp[(size_t)s3 * 32 + cu];
        a0 += (lo16(v0) + lo16(v1)) + (lo16(v2) + lo16(v3));
        a1 += (hi16(v0) + hi16(v1)) + (hi16(v2) + hi16(v3));
    }
    for (; i < e; ++i) {
        unsigned v0 = yp[(size_t)csr[i] * 32 + cu];
        a0 += lo16(v0);
        a1 += hi16(v0);
    }
    float d = dinv[node];
    ((unsigned*)A16)[(size_t)node * 32 + cu] =
        (unsigned)f2bf(a0 * d) | ((unsigned)f2bf(a1 * d) << 16);
}

// 2 nodes per wave, 128 ch: half-wave per node, uint2 (4ch)/lane, unroll-8
__global__ __launch_bounds__(256) void agg128_bf(
    const unsigned short* __restrict__ y, const int* __restrict__ rowptr,
    const int* __restrict__ csr, const float* __restrict__ dinv,
    unsigned short* __restrict__ A16, int N) {
    int wv = (blockIdx.x * blockDim.x + threadIdx.x) >> 6;
    int lane = threadIdx.x & 63;
    int node = wv * 2 + (lane >> 5);
    if (node >= N) return;
    int c2 = lane & 31;
    const uint2* yp = (const uint2*)y;           // 32 uint2 per row
    uint2 v = yp[(size_t)node * 32 + c2];
    float a0 = lo16(v.x), a1 = hi16(v.x), a2 = lo16(v.y), a3 = hi16(v.y);
    int b = rowptr[node], e = rowptr[node + 1];
    int i = b;
    for (; i + 7 < e; i += 8) {
        int s0 = csr[i], s1 = csr[i + 1], s2 = csr[i + 2], s3 = csr[i + 3];
        int s4 = csr[i + 4], s5 = csr[i + 5], s6 = csr[i + 6], s7 = csr[i + 7];
        uint2 v0 = yp[(size_t)s0 * 32 + c2];
        uint2 v1 = yp[(size_t)s1 * 32 + c2];
        uint2 v2 = yp[(size_t)s2 * 32 + c2];
        uint2 v3 = yp[(size_t)s3 * 32 + c2];
        uint2 v4 = yp[(size_t)s4 * 32 + c2];
        uint2 v5 = yp[(size_t)s5 * 32 + c2];
        uint2 v6 = yp[(size_t)s6 * 32 + c2];
        uint2 v7 = yp[(size_t)s7 * 32 + c2];
        a0 += ((lo16(v0.x) + lo16(v1.x)) + (lo16(v2.x) + lo16(v3.x)))
            + ((lo16(v4.x) + lo16(v5.x)) + (lo16(v6.x) + lo16(v7.x)));
        a1 += ((hi16(v0.x) + hi16(v1.x)) + (hi16(v2.x) + hi16(v3.x)))
            + ((hi16(v4.x) + hi16(v5.x)) + (hi16(v6.x) + hi16(v7.x)));
        a2 += ((lo16(v0.y) + lo16(v1.y)) + (lo16(v2.y) + lo16(v3.y)))
            + ((lo16(v4.y) + lo16(v5.y)) + (lo16(v6.y) + lo16(v7.y)));
        a3 += ((hi16(v0.y) + hi16(v1.y)) + (hi16(v2.y) + hi16(v3.y)))
            + ((hi16(v4.y) + hi16(v5.y)) + (hi16(v6.y) + hi16(v7.y)));
    }
    for (; i + 3 < e; i += 4) {
        int s0 = csr[i], s1 = csr[i + 1], s2 = csr[i + 2], s3 = csr[i + 3];
        uint2 v0 = yp[(size_t)s0 * 32 + c2];
        uint2 v1 = yp[(size_t)s1 * 32 + c2];
        uint2 v2 = yp[(size_t)s2 * 32 + c2];
        uint2 v3 = yp[(size_t)s3 * 32 + c2];
        a0 += (lo16(v0.x) + lo16(v1.x)) + (lo16(v2.x) + lo16(v3.x));
        a1 += (hi16(v0.x) + hi16(v1.x)) + (hi16(v2.x) + hi16(v3.x));
        a2 += (lo16(v0.y) + lo16(v1.y)) + (lo16(v2.y) + lo16(v3.y));
        a3 += (hi16(v0.y) + hi16(v1.y)) + (hi16(v2.y) + hi16(v3.y));
    }
    for (; i < e; ++i) {
        uint2 v0 = yp[(size_t)csr[i] * 32 + c2];
        a0 += lo16(v0.x);
        a1 += hi16(v0.x);
        a2 += lo16(v0.y);
        a3 += hi16(v0.y);
    }
    float d = dinv[node];
    uint2 o;
    o.x = (unsigned)f2bf(a0 * d) | ((unsigned)f2bf(a1 * d) << 16);
    o.y = (unsigned)f2bf(a2 * d) | ((unsigned)f2bf(a3 * d) << 16);
    ((uint2*)A16)[(size_t)node * 32 + c2] = o;
}

// ---------------- GEMMs + epilogue ----------------

// MFMA GEMM + fused column stats; output stored bf16 (stats from fp32 acc)
template <int K>
__global__ __launch_bounds__(256) void mfma_gemm(const unsigned short* __restrict__ A16,
                                                 const uint4* __restrict__ Bp,
                                                 unsigned short* __restrict__ out16,
                                                 double* __restrict__ st, int N) {
    constexpr int KS = K / 32;
    __shared__ float cs[128], cs2[128];
    if (threadIdx.x < 128) { cs[threadIdx.x] = 0.f; cs2[threadIdx.x] = 0.f; }
    int w = threadIdx.x >> 6, l = threadIdx.x & 63;
    int cl = l & 15, sub = l >> 4;
    int r0 = blockIdx.x * 64 + w * 16;
    int ra = r0 + cl; if (ra > N - 1) ra = N - 1;

    short8 a[KS];
    const unsigned short* ap = A16 + (size_t)ra * K + sub * 8;
#pragma unroll
    for (int ks = 0; ks < KS; ++ks) a[ks] = *(const short8*)(ap + ks * 32);

    floatx4 acc[8] = {};
#pragma unroll
    for (int cb = 0; cb < 8; ++cb) {
#pragma unroll
        for (int ks = 0; ks < KS; ++ks) {
            short8 b = *(const short8*)&Bp[(ks * 4 + sub) * 128 + cb * 16 + cl];
            acc[cb] = __builtin_amdgcn_mfma_f32_16x16x32_bf16(a[ks], b, acc[cb], 0, 0, 0);
        }
    }
    __syncthreads();   // cs/cs2 init visible
#pragma unroll
    for (int cb = 0; cb < 8; ++cb) {
        float s = 0.f, s2 = 0.f;
#pragma unroll
        for (int j = 0; j < 4; ++j) {
            int row = r0 + sub * 4 + j;
            if (row < N) {
                float val = acc[cb][j];
                out16[(size_t)row * 128 + cb * 16 + cl] = f2bf(val);
                s += val;
                s2 += val * val;
            }
        }
        atomicAdd(&cs[cb * 16 + cl], s);
        atomicAdd(&cs2[cb * 16 + cl], s2);
    }
    __syncthreads();
    if (threadIdx.x < 128) {
        atomicAdd(&st[threadIdx.x], (double)cs[threadIdx.x]);
        atomicAdd(&st[128 + threadIdx.x], (double)cs2[threadIdx.x]);
    }
}

// out16 = bf16(relu(h*sc+sh) * dinv[row]) from bf16 h; BN params computed in LDS from st
__global__ __launch_bounds__(256) void normrelu_bf(
    const unsigned short* __restrict__ h16, const double* __restrict__ st,
    const float* __restrict__ gamma, const float* __restrict__ beta,
    const float* __restrict__ dinv, unsigned short* __restrict__ out, int N) {
    __shared__ float2 ssl[128];
    if (threadIdx.x < 128) {
        int c = threadIdx.x;
        double mean = st[c] / N;
        double var = st[128 + c] / N - mean * mean;
        float sc = (float)((double)gamma[c] / sqrt(var + BN_EPS));
        float sh = beta[c] - (float)mean * sc;
        ssl[c] = make_float2(sc, sh);
    }
    __syncthreads();
    int t = blockIdx.x * blockDim.x + threadIdx.x;
    int total = N * 16;
    if (t >= total) return;
    int r = t >> 4;
    int j = (t & 15) << 3;
    float d = dinv[r];
    uint4 hv = ((const uint4*)h16)[t];
    float2 s0 = ssl[j], s1 = ssl[j + 1], s2 = ssl[j + 2], s3 = ssl[j + 3];
    float2 s4 = ssl[j + 4], s5 = ssl[j + 5], s6 = ssl[j + 6], s7 = ssl[j + 7];
    float v0 = fmaxf(lo16(hv.x) * s0.x + s0.y, 0.f) * d;
    float v1 = fmaxf(hi16(hv.x) * s1.x + s1.y, 0.f) * d;
    float v2 = fmaxf(lo16(hv.y) * s2.x + s2.y, 0.f) * d;
    float v3 = fmaxf(hi16(hv.y) * s3.x + s3.y, 0.f) * d;
    float v4 = fmaxf(lo16(hv.z) * s4.x + s4.y, 0.f) * d;
    float v5 = fmaxf(hi16(hv.z) * s5.x + s5.y, 0.f) * d;
    float v6 = fmaxf(lo16(hv.w) * s6.x + s6.y, 0.f) * d;
    float v7 = fmaxf(hi16(hv.w) * s7.x + s7.y, 0.f) * d;
    uint4 o;
    o.x = (unsigned)f2bf(v0) | ((unsigned)f2bf(v1) << 16);
    o.y = (unsigned)f2bf(v2) | ((unsigned)f2bf(v3) << 16);
    o.z = (unsigned)f2bf(v4) | ((unsigned)f2bf(v5) << 16);
    o.w = (unsigned)f2bf(v6) | ((unsigned)f2bf(v7) << 16);
    ((uint4*)out)[t] = o;
}

// per-graph mean of relu(bn(h16)); BN params inline from st (one col per thread)
__global__ void pool_bn_kernel(const unsigned short* __restrict__ h16,
                               const double* __restrict__ st,
                               const float* __restrict__ gamma, const float* __restrict__ beta,
                               const int* __restrict__ gstart, float* __restrict__ pooled,
                               int N) {
    int g = blockIdx.x;
    int c = threadIdx.x;
    double mean = st[c] / N;
    double var = st[128 + c] / N - mean * mean;
    float sc = (float)((double)gamma[c] / sqrt(var + BN_EPS));
    float sh = beta[c] - (float)mean * sc;
    int b = gstart[g], e = gstart[g + 1];
    float acc = 0.f;
    int r = b;
    for (; r + 1 < e; r += 2) {
        float v0 = bf2f(h16[(size_t)r * 128 + c]);
        float v1 = bf2f(h16[(size_t)(r + 1) * 128 + c]);
        acc += fmaxf(v0 * sc + sh, 0.f) + fmaxf(v1 * sc + sh, 0.f);
    }
    if (r < e) acc += fmaxf(bf2f(h16[(size_t)r * 128 + c]) * sc + sh, 0.f);
    pooled[(size_t)g * 128 + c] = acc / fmaxf((float)(e - b), 1.0f);
}

// head gemm (fp32) + fused column stats
template <int K>
__global__ __launch_bounds__(256) void gemm_bias_stats(const float* __restrict__ A,
                                                       const float* __restrict__ W,
                                                       const float* __restrict__ bias,
                                                       float* __restrict__ out,
                                                       double* __restrict__ st,
                                                       int N, int C) {
    __shared__ float Wl[K * 128];
    __shared__ float cs[128], cs2[128];
    if (threadIdx.x < 128) { cs[threadIdx.x] = 0.f; cs2[threadIdx.x] = 0.f; }
    const int ct = blockIdx.y << 7;
    for (int idx = threadIdx.x; idx < K * 128; idx += 256) {
        int kk = idx >> 7, cc = idx & 127;
        Wl[idx] = W[(size_t)kk * C + ct + cc];
    }
    __syncthreads();
    const int cq = (threadIdx.x & 31) << 2;
    const int rg = threadIdx.x >> 5;
    const int r0 = blockIdx.x * 32 + (rg << 2);

    const float* Ap[4];
#pragma unroll
    for (int i = 0; i < 4; ++i) {
        int r = r0 + i;
        Ap[i] = A + (size_t)(r < N ? r : 0) * K;
    }
    float acc[4][4] = {};
#pragma unroll 4
    for (int k = 0; k < K; ++k) {
        float a0 = Ap[0][k];
        float a1 = Ap[1][k];
        float a2 = Ap[2][k];
        float a3 = Ap[3][k];
        float4 w = *(const float4*)&Wl[k * 128 + cq];
        acc[0][0] += a0 * w.x; acc[0][1] += a0 * w.y; acc[0][2] += a0 * w.z; acc[0][3] += a0 * w.w;
        acc[1][0] += a1 * w.x; acc[1][1] += a1 * w.y; acc[1][2] += a1 * w.z; acc[1][3] += a1 * w.w;
        acc[2][0] += a2 * w.x; acc[2][1] += a2 * w.y; acc[2][2] += a2 * w.z; acc[2][3] += a2 * w.w;
        acc[3][0] += a3 * w.x; acc[3][1] += a3 * w.y; acc[3][2] += a3 * w.z; acc[3][3] += a3 * w.w;
    }
    float4 bv = *(const float4*)&bias[ct + cq];
    float s[4] = {}, s2[4] = {};
#pragma unroll
    for (int i = 0; i < 4; ++i) {
        int r = r0 + i;
        if (r < N) {
            float o0 = acc[i][0] + bv.x, o1 = acc[i][1] + bv.y;
            float o2 = acc[i][2] + bv.z, o3 = acc[i][3] + bv.w;
            *(float4*)&out[(size_t)r * C + ct + cq] = make_float4(o0, o1, o2, o3);
            s[0] += o0; s2[0] += o0 * o0;
            s[1] += o1; s2[1] += o1 * o1;
            s[2] += o2; s2[2] += o2 * o2;
            s[3] += o3; s2[3] += o3 * o3;
        }
    }
#pragma unroll
    for (int jj = 0; jj < 4; ++jj) {
        atomicAdd(&cs[cq + jj], s[jj]);
        atomicAdd(&cs2[cq + jj], s2[jj]);
    }
    __syncthreads();
    if (threadIdx.x < 128) {
        atomicAdd(&st[ct + threadIdx.x], (double)cs[threadIdx.x]);
        atomicAdd(&st[C + ct + threadIdx.x], (double)cs2[threadIdx.x]);
    }
}

// final: out[g][j] = sum_c relu(bn(z))[g][c] * W4[c][j] + b4[j]; BN inline from st
__global__ void head_kernel(const float* __restrict__ z, const double* __restrict__ st,
                            const float* __restrict__ gamma, const float* __restrict__ beta,
                            const float* __restrict__ W4, const float* __restrict__ b4,
                            float* __restrict__ out, int G) {
    __shared__ float zr[256];
    int g = blockIdx.x;
    int t = threadIdx.x;
    double mean = st[t] / G;
    double var = st[256 + t] / G - mean * mean;
    float sc = (float)((double)gamma[t] / sqrt(var + BN_EPS));
    float sh = beta[t] - (float)mean * sc;
    float v = z[(size_t)g * 256 + t];
    zr[t] = fmaxf(v * sc + sh, 0.f);
    __syncthreads();
    int j = t >> 4;
    int part = t & 15;
    if (j < 10) {
        float acc = 0.f;
#pragma unroll
        for (int k = 0; k < 16; ++k) {
            int c = part + k * 16;
            acc += zr[c] * W4[c * 10 + j];
        }
#pragma unroll
        for (int off = 8; off; off >>= 1) acc += __shfl_down(acc, off);
        if (part == 0) out[(size_t)g * 10 + j] = acc + b4[j];
    }
}

// ---------------- launch ----------------

extern "C" void kernel_launch(void* const* d_in, const int* in_sizes, int n_in,
                              void* d_out, int out_size, void* d_ws, size_t ws_size,
                              hipStream_t stream) {
    const int N = in_sizes[0] / 64;
    const int E = in_sizes[1] / 2;
    const int G = out_size / 10;

    const float* x     = (const float*)d_in[0];
    const int*   ei    = (const int*)d_in[1];
    const int*   batch = (const int*)d_in[2];
    const float* W1 = (const float*)d_in[3];
    const float* g1 = (const float*)d_in[5];
    const float* be1 = (const float*)d_in[6];
    const float* W2 = (const float*)d_in[7];
    const float* g2 = (const float*)d_in[9];
    const float* be2 = (const float*)d_in[10];
    const float* W3 = (const float*)d_in[11];
    const float* b3 = (const float*)d_in[12];
    const float* g3 = (const float*)d_in[13];
    const float* be3 = (const float*)d_in[14];
    const float* W4 = (const float*)d_in[15];
    const float* b4 = (const float*)d_in[16];
    float* out = (float*)d_out;

    const int* srcp = ei;        // edge_index[0]
    const int* dstp = ei + E;    // edge_index[1]

    // workspace layout
    char* p = (char*)d_ws;
    auto alloc = [&](size_t bytes) {
        void* r = (void*)p;
        p += (bytes + 255) & ~(size_t)255;
        return r;
    };
    unsigned short* A16 = (unsigned short*)alloc((size_t)N * 128 * 2);
    unsigned short* h16 = (unsigned short*)alloc((size_t)N * 128 * 2);   // gemm out bf16
    char* R3  = (char*)alloc((size_t)N * 128 * 4);   // c16 | y16
    int* csr      = (int*)alloc((size_t)E * 4);
    unsigned* part = (unsigned*)alloc((size_t)E * 4);
    int* rowptr = (int*)alloc((size_t)(N + 1) * 4);
    float* dinv = (float*)alloc((size_t)N * 4);
    int* hist   = (int*)alloc((size_t)256 * PB * 4);
    int* offs   = (int*)alloc((size_t)256 * PB * 4);
    int* bsums  = (int*)alloc(64 * 4);
    uint4* w1p  = (uint4*)alloc((size_t)64 * 128 * 2);
    uint4* w2p  = (uint4*)alloc((size_t)128 * 128 * 2);
    int* gstart = (int*)alloc((size_t)(G + 1) * 4);
    float* pooled = (float*)alloc((size_t)G * 128 * 4);
    float* z      = (float*)alloc((size_t)G * 256 * 4);
    double* st    = (double*)alloc(1024 * 8);
    (void)ws_size; (void)n_in;

    unsigned short* c16 = (unsigned short*)R3;                         // [N*128] bf16
    unsigned short* y16 = (unsigned short*)(R3 + (size_t)N * 128 * 2); // [N*64] bf16

    double* stA = st;
    double* stB = st + 256;
    double* stC = st + 512;

    hipMemsetAsync(st, 0, 1024 * 8, stream);

    const int nb = (N + 255) / 256;
    const int NB = (N + 255) >> 8;
    const int cpb = (((E + PB - 1) / PB) + 3) & ~3;
    const int n2 = NB * PB;
    const int nch2 = (n2 + 1023) / 1024;
    const int aggblocks = (N + 7) / 8;   // 4 waves/block, 2 nodes/wave

    // fused setup: wpack W1 (4 blocks) | wpack W2 (8) | bounds (nb) | hist (PB)
    setup_kernel<<<4 + 8 + nb + PB, 256, 0, stream>>>(W1, w1p, W2, w2p, batch, gstart,
                                                      dstp, hist, N, G, E, cpb, NB, nb);
    scan1_kernel<<<nch2, 1024, 0, stream>>>(hist, offs, bsums, n2);
    scan23_add<<<(n2 + 255) / 256, 256, 0, stream>>>(offs, bsums, nch2, n2);
    scatter_kernel<<<PB, 256, 0, stream>>>(srcp, dstp, offs, part, E, cpb, NB);

    // count + rowptr + dinv + csr fill + prescale, one block per bucket
    bucket_build<<<NB, 256, 0, stream>>>(part, offs, rowptr, dinv, csr, x, y16, E, N, NB);

    // Layer 1
    agg64_bf<<<aggblocks, 256, 0, stream>>>(y16, rowptr, csr, dinv, A16, N);
    mfma_gemm<64><<<(N + 63) / 64, 256, 0, stream>>>(A16, w1p, h16, stA, N);
    normrelu_bf<<<(N * 16 + 255) / 256, 256, 0, stream>>>(h16, stA, g1, be1, dinv, c16, N);

    // Layer 2
    agg128_bf<<<aggblocks, 256, 0, stream>>>(c16, rowptr, csr, dinv, A16, N);
    mfma_gemm<128><<<(N + 63) / 64, 256, 0, stream>>>(A16, w2p, h16, stB, N);

    // Pool (BN+ReLU fused, inline BN params)
    pool_bn_kernel<<<G, 128, 0, stream>>>(h16, stB, g2, be2, gstart, pooled, N);

    // Head (gemm + stats fused; BN inline in head)
    gemm_bias_stats<128><<<dim3((G + 31) / 32, 2), 256, 0, stream>>>(pooled, W3, b3, z, stC, G, 256);
    head_kernel<<<G, 256, 0, stream>>>(z, stC, g3, be3, W4, b4, out, G);
}

// Round 11
// 243.294 us; speedup vs baseline: 1.9942x; 1.0206x over previous
//
#include <hip/hip_runtime.h>
#include <hip/hip_bf16.h>

#define BN_EPS 1e-5
#define PB 256   // partition blocks for edge binning

typedef __attribute__((ext_vector_type(8))) short short8;
typedef __attribute__((ext_vector_type(4))) float floatx4;

// ---------------- bf16 helpers ----------------

__device__ __forceinline__ unsigned short f2bf(float f) {
    union { float f; unsigned u; } v; v.f = f;
    unsigned r = v.u + 0x7FFF + ((v.u >> 16) & 1);   // RNE
    return (unsigned short)(r >> 16);
}
__device__ __forceinline__ float bf2f(unsigned short h) {
    union { unsigned u; float f; } v; v.u = ((unsigned)h) << 16;
    return v.f;
}
__device__ __forceinline__ float lo16(unsigned u) { return bf2f((unsigned short)(u & 0xffff)); }
__device__ __forceinline__ float hi16(unsigned u) { return bf2f((unsigned short)(u >> 16)); }

// ---------------- fused setup: wpack(W1) | wpack(W2) | st-zero | bounds | hist ----------------

__device__ __forceinline__ void wpack_body(const float* __restrict__ W, uint4* __restrict__ Wp,
                                           int K, int i) {
    if (i >= K * 16) return;
    int c = i & 127;
    int kb = i >> 7;
    unsigned short h[8];
#pragma unroll
    for (int j = 0; j < 8; ++j) h[j] = f2bf(W[(size_t)(kb * 8 + j) * 128 + c]);
    uint4 o;
    o.x = (unsigned)h[0] | ((unsigned)h[1] << 16);
    o.y = (unsigned)h[2] | ((unsigned)h[3] << 16);
    o.z = (unsigned)h[4] | ((unsigned)h[5] << 16);
    o.w = (unsigned)h[6] | ((unsigned)h[7] << 16);
    Wp[kb * 128 + c] = o;
}

__global__ void setup_kernel(const float* __restrict__ W1, uint4* __restrict__ w1p,
                             const float* __restrict__ W2, uint4* __restrict__ w2p,
                             double* __restrict__ st,
                             const int* __restrict__ batch, int* __restrict__ gstart,
                             const int* __restrict__ dst, int* __restrict__ hist,
                             int N, int G, int E, int cpb, int NB, int nb) {
    __shared__ int h[256];
    int t = threadIdx.x;
    int b = blockIdx.x;
    if (b < 4) {                         // wpack W1 (K=64, 1024 elems)
        wpack_body(W1, w1p, 64, b * 256 + t);
    } else if (b < 12) {                 // wpack W2 (K=128, 2048 elems)
        wpack_body(W2, w2p, 128, (b - 4) * 256 + t);
    } else if (b == 12) {                // zero stats accumulators (1024 doubles)
        st[t] = 0.0;
        st[256 + t] = 0.0;
        st[512 + t] = 0.0;
        st[768 + t] = 0.0;
    } else if (b < 13 + nb) {            // bounds
        int i = (b - 13) * 256 + t;
        if (i < N) {
            int bi = batch[i];
            int bp = (i == 0) ? -1 : batch[i - 1];
            for (int g = bp + 1; g <= bi; ++g) gstart[g] = i;
            if (i == N - 1) {
                for (int g = bi + 1; g <= G; ++g) gstart[g] = N;
            }
        }
    } else {                             // hist
        int blk = b - 13 - nb;           // 0..PB-1
        if (t < NB) h[t] = 0;
        __syncthreads();
        int base = blk * cpb;
        int end = base + cpb; if (end > E) end = E;
        int e = base + t * 4;
        for (; e + 3 < end; e += 1024) {
            int4 d = *(const int4*)(dst + e);
            atomicAdd(&h[d.x >> 8], 1);
            atomicAdd(&h[d.y >> 8], 1);
            atomicAdd(&h[d.z >> 8], 1);
            atomicAdd(&h[d.w >> 8], 1);
        }
        for (; e < end; ++e) atomicAdd(&h[dst[e] >> 8], 1);
        __syncthreads();
        if (t < NB) hist[t * PB + blk] = h[t];
    }
}

// ---------------- scan ----------------

__global__ void scan1_kernel(const int* __restrict__ in, int* __restrict__ part,
                             int* __restrict__ bsum, int n) {
    __shared__ int s[1024];
    int t = threadIdx.x;
    int i = blockIdx.x * 1024 + t;
    int v = (i < n) ? in[i] : 0;
    s[t] = v;
    __syncthreads();
    for (int off = 1; off < 1024; off <<= 1) {
        int x = (t >= off) ? s[t - off] : 0;
        __syncthreads();
        s[t] += x;
        __syncthreads();
    }
    if (i < n) part[i] = s[t] - v;
    if (t == 1023) bsum[blockIdx.x] = s[1023];
}

// LDS inclusive scan of <=64 bsums; all 256 threads participate (syncthreads-based)
__device__ __forceinline__ void bsum_scan(const int* __restrict__ bsum, int nch,
                                          int* __restrict__ pre, int t) {
    if (t < 64) pre[t] = (t < nch) ? bsum[t] : 0;
    __syncthreads();
    for (int off = 1; off < 64; off <<= 1) {
        int x = (t < 64 && t >= off) ? pre[t - off] : 0;
        __syncthreads();
        if (t < 64) pre[t] += x;
        __syncthreads();
    }
}

// ---------------- CSR build ----------------

// scatter with inline bsum fixup (offs holds scan1 partials)
__global__ void scatter_kernel(const int* __restrict__ src, const int* __restrict__ dst,
                               const int* __restrict__ offs, const int* __restrict__ bsum,
                               unsigned* __restrict__ part,
                               int E, int cpb, int NB, int nch) {
    __shared__ int cur[256];
    __shared__ int pre[64];
    int t = threadIdx.x;
    bsum_scan(bsum, nch, pre, t);
    if (t < NB) {
        int idx = t * PB + blockIdx.x;
        int ch = idx >> 10;
        cur[t] = offs[idx] + ((ch == 0) ? 0 : pre[ch - 1]);
    }
    __syncthreads();
    int base = blockIdx.x * cpb;
    int end = base + cpb; if (end > E) end = E;
    int e = base + t * 4;
    for (; e + 3 < end; e += 1024) {
        int4 d4 = *(const int4*)(dst + e);
        int4 s4 = *(const int4*)(src + e);
        int dd[4] = {d4.x, d4.y, d4.z, d4.w};
        int sv[4] = {s4.x, s4.y, s4.z, s4.w};
#pragma unroll
        for (int i = 0; i < 4; ++i) {
            int pos = atomicAdd(&cur[dd[i] >> 8], 1);
            part[pos] = ((unsigned)sv[i] << 8) | (unsigned)(dd[i] & 255);
        }
    }
    for (; e < end; ++e) {
        int d = dst[e];
        int pos = atomicAdd(&cur[d >> 8], 1);
        part[pos] = ((unsigned)src[e] << 8) | (unsigned)(d & 255);
    }
}

// one block per bucket: count -> exscan -> rowptr/dinv -> csr fill -> prescale.
// offs partials fixed up inline via bsum scan.
__global__ __launch_bounds__(256) void bucket_build(
    const unsigned* __restrict__ part, const int* __restrict__ offs,
    const int* __restrict__ bsum,
    int* __restrict__ rowptr, float* __restrict__ dinv, int* __restrict__ csr,
    const float* __restrict__ x, unsigned short* __restrict__ y16,
    int E, int N, int NB, int nch) {
    __shared__ int cw[256], sc[256], cur[256];
    __shared__ float sd[256];
    __shared__ int pre[64];
    int b = blockIdx.x;
    int t = threadIdx.x;
    bsum_scan(bsum, nch, pre, t);
    cw[t] = 0;
    __syncthreads();
    int i0 = b * PB;
    int ch0 = i0 >> 10;
    int bstart = offs[i0] + ((ch0 == 0) ? 0 : pre[ch0 - 1]);
    int bend = E;
    if (b + 1 < NB) {
        int i1 = (b + 1) * PB;
        int ch1 = i1 >> 10;
        bend = offs[i1] + ((ch1 == 0) ? 0 : pre[ch1 - 1]);
    }
    for (int e = bstart + t; e < bend; e += 256)
        atomicAdd(&cw[part[e] & 255u], 1);
    __syncthreads();
    int c = cw[t];
    sc[t] = c;
    __syncthreads();
    for (int off = 1; off < 256; off <<= 1) {
        int v = (t >= off) ? sc[t - off] : 0;
        __syncthreads();
        sc[t] += v;
        __syncthreads();
    }
    int node = (b << 8) + t;
    int start = bstart + sc[t] - c;
    float d = rsqrtf((float)(c + 1));    // +1 self loop
    cur[t] = start;
    sd[t] = d;
    if (node < N) {
        rowptr[node] = start;
        dinv[node] = d;
    }
    if (b == NB - 1 && t == 255) rowptr[N] = E;
    __syncthreads();
    for (int e = bstart + t; e < bend; e += 256) {
        unsigned pr = part[e];
        int pos = atomicAdd(&cur[pr & 255u], 1);
        csr[pos] = (int)(pr >> 8);
    }
    // prescale: y16[node][0..64) = bf16(x[node][c] * dinv[node]) for this bucket
    int base = b << 8;
    int nlocal = N - base; if (nlocal > 256) nlocal = 256;
    if (nlocal <= 0) return;
    for (int idx = t; idx < nlocal * 8; idx += 256) {
        int r = idx >> 3, k = idx & 7;
        int nd = base + r;
        float dd = sd[r];
        const float4* xp = (const float4*)(x + (size_t)nd * 64 + k * 8);
        float4 a = xp[0];
        float4 bb = xp[1];
        uint4 o;
        o.x = (unsigned)f2bf(a.x * dd) | ((unsigned)f2bf(a.y * dd) << 16);
        o.y = (unsigned)f2bf(a.z * dd) | ((unsigned)f2bf(a.w * dd) << 16);
        o.z = (unsigned)f2bf(bb.x * dd) | ((unsigned)f2bf(bb.y * dd) << 16);
        o.w = (unsigned)f2bf(bb.z * dd) | ((unsigned)f2bf(bb.w * dd) << 16);
        *(uint4*)(y16 + (size_t)nd * 64 + k * 8) = o;
    }
}

// ---------------- aggregation ----------------

// 2 nodes per wave, 64 ch: half-wave per node, uint (2ch)/lane, unroll-8 (proven form)
__global__ __launch_bounds__(256) void agg64_bf(
    const unsigned short* __restrict__ y, const int* __restrict__ rowptr,
    const int* __restrict__ csr, const float* __restrict__ dinv,
    unsigned short* __restrict__ A16, int N) {
    int wv = (blockIdx.x * blockDim.x + threadIdx.x) >> 6;
    int lane = threadIdx.x & 63;
    int node = wv * 2 + (lane >> 5);
    if (node >= N) return;
    int cu = lane & 31;
    const unsigned* yp = (const unsigned*)y;     // 32 uints per row
    unsigned v = yp[(size_t)node * 32 + cu];
    float a0 = lo16(v), a1 = hi16(v);
    int b = rowptr[node], e = rowptr[node + 1];
    int i = b;
    for (; i + 7 < e; i += 8) {
        int s0 = csr[i], s1 = csr[i + 1], s2 = csr[i + 2], s3 = csr[i + 3];
        int s4 = csr[i + 4], s5 = csr[i + 5], s6 = csr[i + 6], s7 = csr[i + 7];
        unsigned v0 = yp[(size_t)s0 * 32 + cu];
        unsigned v1 = yp[(size_t)s1 * 32 + cu];
        unsigned v2 = yp[(size_t)s2 * 32 + cu];
        unsigned v3 = yp[(size_t)s3 * 32 + cu];
        unsigned v4 = yp[(size_t)s4 * 32 + cu];
        unsigned v5 = yp[(size_t)s5 * 32 + cu];
        unsigned v6 = yp[(size_t)s6 * 32 + cu];
        unsigned v7 = yp[(size_t)s7 * 32 + cu];
        a0 += ((lo16(v0) + lo16(v1)) + (lo16(v2) + lo16(v3)))
            + ((lo16(v4) + lo16(v5)) + (lo16(v6) + lo16(v7)));
        a1 += ((hi16(v0) + hi16(v1)) + (hi16(v2) + hi16(v3)))
            + ((hi16(v4) + hi16(v5)) + (hi16(v6) + hi16(v7)));
    }
    for (; i + 3 < e; i += 4) {
        int s0 = csr[i], s1 = csr[i + 1], s2 = csr[i + 2], s3 = csr[i + 3];
        unsigned v0 = yp[(size_t)s0 * 32 + cu];
        unsigned v1 = yp[(size_t)s1 * 32 + cu];
        unsigned v2 = yp[(size_t)s2 * 32 + cu];
        unsigned v3 = yp[(size_t)s3 * 32 + cu];
        a0 += (lo16(v0) + lo16(v1)) + (lo16(v2) + lo16(v3));
        a1 += (hi16(v0) + hi16(v1)) + (hi16(v2) + hi16(v3));
    }
    for (; i < e; ++i) {
        unsigned v0 = yp[(size_t)csr[i] * 32 + cu];
        a0 += lo16(v0);
        a1 += hi16(v0);
    }
    float d = dinv[node];
    ((unsigned*)A16)[(size_t)node * 32 + cu] =
        (unsigned)f2bf(a0 * d) | ((unsigned)f2bf(a1 * d) << 16);
}

// 2 nodes per wave, 128 ch: half-wave per node, uint2 (4ch)/lane, unroll-16 for MLP
__global__ __launch_bounds__(256) void agg128_bf(
    const unsigned short* __restrict__ y, const int* __restrict__ rowptr,
    const int* __restrict__ csr, const float* __restrict__ dinv,
    unsigned short* __restrict__ A16, int N) {
    int wv = (blockIdx.x * blockDim.x + threadIdx.x) >> 6;
    int lane = threadIdx.x & 63;
    int node = wv * 2 + (lane >> 5);
    if (node >= N) return;
    int c2 = lane & 31;
    const uint2* yp = (const uint2*)y;           // 32 uint2 per row
    uint2 v = yp[(size_t)node * 32 + c2];
    float a0 = lo16(v.x), a1 = hi16(v.x), a2 = lo16(v.y), a3 = hi16(v.y);
    int b = rowptr[node], e = rowptr[node + 1];
    int i = b;
    for (; i + 15 < e; i += 16) {
        int s[16];
#pragma unroll
        for (int k = 0; k < 16; ++k) s[k] = csr[i + k];
        uint2 w[16];
#pragma unroll
        for (int k = 0; k < 16; ++k) w[k] = yp[(size_t)s[k] * 32 + c2];
#pragma unroll
        for (int k = 0; k < 16; ++k) {
            a0 += lo16(w[k].x);
            a1 += hi16(w[k].x);
            a2 += lo16(w[k].y);
            a3 += hi16(w[k].y);
        }
    }
    for (; i + 3 < e; i += 4) {
        int s0 = csr[i], s1 = csr[i + 1], s2 = csr[i + 2], s3 = csr[i + 3];
        uint2 v0 = yp[(size_t)s0 * 32 + c2];
        uint2 v1 = yp[(size_t)s1 * 32 + c2];
        uint2 v2 = yp[(size_t)s2 * 32 + c2];
        uint2 v3 = yp[(size_t)s3 * 32 + c2];
        a0 += (lo16(v0.x) + lo16(v1.x)) + (lo16(v2.x) + lo16(v3.x));
        a1 += (hi16(v0.x) + hi16(v1.x)) + (hi16(v2.x) + hi16(v3.x));
        a2 += (lo16(v0.y) + lo16(v1.y)) + (lo16(v2.y) + lo16(v3.y));
        a3 += (hi16(v0.y) + hi16(v1.y)) + (hi16(v2.y) + hi16(v3.y));
    }
    for (; i < e; ++i) {
        uint2 v0 = yp[(size_t)csr[i] * 32 + c2];
        a0 += lo16(v0.x);
        a1 += hi16(v0.x);
        a2 += lo16(v0.y);
        a3 += hi16(v0.y);
    }
    float d = dinv[node];
    uint2 o;
    o.x = (unsigned)f2bf(a0 * d) | ((unsigned)f2bf(a1 * d) << 16);
    o.y = (unsigned)f2bf(a2 * d) | ((unsigned)f2bf(a3 * d) << 16);
    ((uint2*)A16)[(size_t)node * 32 + c2] = o;
}

// ---------------- GEMMs + epilogue ----------------

// MFMA GEMM + fused column stats; output stored bf16 (stats from fp32 acc)
template <int K>
__global__ __launch_bounds__(256) void mfma_gemm(const unsigned short* __restrict__ A16,
                                                 const uint4* __restrict__ Bp,
                                                 unsigned short* __restrict__ out16,
                                                 double* __restrict__ st, int N) {
    constexpr int KS = K / 32;
    __shared__ float cs[128], cs2[128];
    if (threadIdx.x < 128) { cs[threadIdx.x] = 0.f; cs2[threadIdx.x] = 0.f; }
    int w = threadIdx.x >> 6, l = threadIdx.x & 63;
    int cl = l & 15, sub = l >> 4;
    int r0 = blockIdx.x * 64 + w * 16;
    int ra = r0 + cl; if (ra > N - 1) ra = N - 1;

    short8 a[KS];
    const unsigned short* ap = A16 + (size_t)ra * K + sub * 8;
#pragma unroll
    for (int ks = 0; ks < KS; ++ks) a[ks] = *(const short8*)(ap + ks * 32);

    floatx4 acc[8] = {};
#pragma unroll
    for (int cb = 0; cb < 8; ++cb) {
#pragma unroll
        for (int ks = 0; ks < KS; ++ks) {
            short8 b = *(const short8*)&Bp[(ks * 4 + sub) * 128 + cb * 16 + cl];
            acc[cb] = __builtin_amdgcn_mfma_f32_16x16x32_bf16(a[ks], b, acc[cb], 0, 0, 0);
        }
    }
    __syncthreads();   // cs/cs2 init visible
#pragma unroll
    for (int cb = 0; cb < 8; ++cb) {
        float s = 0.f, s2 = 0.f;
#pragma unroll
        for (int j = 0; j < 4; ++j) {
            int row = r0 + sub * 4 + j;
            if (row < N) {
                float val = acc[cb][j];
                out16[(size_t)row * 128 + cb * 16 + cl] = f2bf(val);
                s += val;
                s2 += val * val;
            }
        }
        atomicAdd(&cs[cb * 16 + cl], s);
        atomicAdd(&cs2[cb * 16 + cl], s2);
    }
    __syncthreads();
    if (threadIdx.x < 128) {
        atomicAdd(&st[threadIdx.x], (double)cs[threadIdx.x]);
        atomicAdd(&st[128 + threadIdx.x], (double)cs2[threadIdx.x]);
    }
}

// out16 = bf16(relu(h*sc+sh) * dinv[row]) from bf16 h; BN params computed in LDS from st
__global__ __launch_bounds__(256) void normrelu_bf(
    const unsigned short* __restrict__ h16, const double* __restrict__ st,
    const float* __restrict__ gamma, const float* __restrict__ beta,
    const float* __restrict__ dinv, unsigned short* __restrict__ out, int N) {
    __shared__ float2 ssl[128];
    if (threadIdx.x < 128) {
        int c = threadIdx.x;
        double mean = st[c] / N;
        double var = st[128 + c] / N - mean * mean;
        float sc = (float)((double)gamma[c] / sqrt(var + BN_EPS));
        float sh = beta[c] - (float)mean * sc;
        ssl[c] = make_float2(sc, sh);
    }
    __syncthreads();
    int t = blockIdx.x * blockDim.x + threadIdx.x;
    int total = N * 16;
    if (t >= total) return;
    int r = t >> 4;
    int j = (t & 15) << 3;
    float d = dinv[r];
    uint4 hv = ((const uint4*)h16)[t];
    float2 s0 = ssl[j], s1 = ssl[j + 1], s2 = ssl[j + 2], s3 = ssl[j + 3];
    float2 s4 = ssl[j + 4], s5 = ssl[j + 5], s6 = ssl[j + 6], s7 = ssl[j + 7];
    float v0 = fmaxf(lo16(hv.x) * s0.x + s0.y, 0.f) * d;
    float v1 = fmaxf(hi16(hv.x) * s1.x + s1.y, 0.f) * d;
    float v2 = fmaxf(lo16(hv.y) * s2.x + s2.y, 0.f) * d;
    float v3 = fmaxf(hi16(hv.y) * s3.x + s3.y, 0.f) * d;
    float v4 = fmaxf(lo16(hv.z) * s4.x + s4.y, 0.f) * d;
    float v5 = fmaxf(hi16(hv.z) * s5.x + s5.y, 0.f) * d;
    float v6 = fmaxf(lo16(hv.w) * s6.x + s6.y, 0.f) * d;
    float v7 = fmaxf(hi16(hv.w) * s7.x + s7.y, 0.f) * d;
    uint4 o;
    o.x = (unsigned)f2bf(v0) | ((unsigned)f2bf(v1) << 16);
    o.y = (unsigned)f2bf(v2) | ((unsigned)f2bf(v3) << 16);
    o.z = (unsigned)f2bf(v4) | ((unsigned)f2bf(v5) << 16);
    o.w = (unsigned)f2bf(v6) | ((unsigned)f2bf(v7) << 16);
    ((uint4*)out)[t] = o;
}

// per-graph mean of relu(bn(h16)); BN params inline from st (one col per thread)
__global__ void pool_bn_kernel(const unsigned short* __restrict__ h16,
                               const double* __restrict__ st,
                               const float* __restrict__ gamma, const float* __restrict__ beta,
                               const int* __restrict__ gstart, float* __restrict__ pooled,
                               int N) {
    int g = blockIdx.x;
    int c = threadIdx.x;
    double mean = st[c] / N;
    double var = st[128 + c] / N - mean * mean;
    float sc = (float)((double)gamma[c] / sqrt(var + BN_EPS));
    float sh = beta[c] - (float)mean * sc;
    int b = gstart[g], e = gstart[g + 1];
    float acc = 0.f;
    int r = b;
    for (; r + 1 < e; r += 2) {
        float v0 = bf2f(h16[(size_t)r * 128 + c]);
        float v1 = bf2f(h16[(size_t)(r + 1) * 128 + c]);
        acc += fmaxf(v0 * sc + sh, 0.f) + fmaxf(v1 * sc + sh, 0.f);
    }
    if (r < e) acc += fmaxf(bf2f(h16[(size_t)r * 128 + c]) * sc + sh, 0.f);
    pooled[(size_t)g * 128 + c] = acc / fmaxf((float)(e - b), 1.0f);
}

// head gemm (fp32) + fused column stats
template <int K>
__global__ __launch_bounds__(256) void gemm_bias_stats(const float* __restrict__ A,
                                                       const float* __restrict__ W,
                                                       const float* __restrict__ bias,
                                                       float* __restrict__ out,
                                                       double* __restrict__ st,
                                                       int N, int C) {
    __shared__ float Wl[K * 128];
    __shared__ float cs[128], cs2[128];
    if (threadIdx.x < 128) { cs[threadIdx.x] = 0.f; cs2[threadIdx.x] = 0.f; }
    const int ct = blockIdx.y << 7;
    for (int idx = threadIdx.x; idx < K * 128; idx += 256) {
        int kk = idx >> 7, cc = idx & 127;
        Wl[idx] = W[(size_t)kk * C + ct + cc];
    }
    __syncthreads();
    const int cq = (threadIdx.x & 31) << 2;
    const int rg = threadIdx.x >> 5;
    const int r0 = blockIdx.x * 32 + (rg << 2);

    const float* Ap[4];
#pragma unroll
    for (int i = 0; i < 4; ++i) {
        int r = r0 + i;
        Ap[i] = A + (size_t)(r < N ? r : 0) * K;
    }
    float acc[4][4] = {};
#pragma unroll 4
    for (int k = 0; k < K; ++k) {
        float a0 = Ap[0][k];
        float a1 = Ap[1][k];
        float a2 = Ap[2][k];
        float a3 = Ap[3][k];
        float4 w = *(const float4*)&Wl[k * 128 + cq];
        acc[0][0] += a0 * w.x; acc[0][1] += a0 * w.y; acc[0][2] += a0 * w.z; acc[0][3] += a0 * w.w;
        acc[1][0] += a1 * w.x; acc[1][1] += a1 * w.y; acc[1][2] += a1 * w.z; acc[1][3] += a1 * w.w;
        acc[2][0] += a2 * w.x; acc[2][1] += a2 * w.y; acc[2][2] += a2 * w.z; acc[2][3] += a2 * w.w;
        acc[3][0] += a3 * w.x; acc[3][1] += a3 * w.y; acc[3][2] += a3 * w.z; acc[3][3] += a3 * w.w;
    }
    float4 bv = *(const float4*)&bias[ct + cq];
    float s[4] = {}, s2[4] = {};
#pragma unroll
    for (int i = 0; i < 4; ++i) {
        int r = r0 + i;
        if (r < N) {
            float o0 = acc[i][0] + bv.x, o1 = acc[i][1] + bv.y;
            float o2 = acc[i][2] + bv.z, o3 = acc[i][3] + bv.w;
            *(float4*)&out[(size_t)r * C + ct + cq] = make_float4(o0, o1, o2, o3);
            s[0] += o0; s2[0] += o0 * o0;
            s[1] += o1; s2[1] += o1 * o1;
            s[2] += o2; s2[2] += o2 * o2;
            s[3] += o3; s2[3] += o3 * o3;
        }
    }
#pragma unroll
    for (int jj = 0; jj < 4; ++jj) {
        atomicAdd(&cs[cq + jj], s[jj]);
        atomicAdd(&cs2[cq + jj], s2[jj]);
    }
    __syncthreads();
    if (threadIdx.x < 128) {
        atomicAdd(&st[ct + threadIdx.x], (double)cs[threadIdx.x]);
        atomicAdd(&st[C + ct + threadIdx.x], (double)cs2[threadIdx.x]);
    }
}

// final: out[g][j] = sum_c relu(bn(z))[g][c] * W4[c][j] + b4[j]; BN inline from st
__global__ void head_kernel(const float* __restrict__ z, const double* __restrict__ st,
                            const float* __restrict__ gamma, const float* __restrict__ beta,
                            const float* __restrict__ W4, const float* __restrict__ b4,
                            float* __restrict__ out, int G) {
    __shared__ float zr[256];
    int g = blockIdx.x;
    int t = threadIdx.x;
    double mean = st[t] / G;
    double var = st[256 + t] / G - mean * mean;
    float sc = (float)((double)gamma[t] / sqrt(var + BN_EPS));
    float sh = beta[t] - (float)mean * sc;
    float v = z[(size_t)g * 256 + t];
    zr[t] = fmaxf(v * sc + sh, 0.f);
    __syncthreads();
    int j = t >> 4;
    int part = t & 15;
    if (j < 10) {
        float acc = 0.f;
#pragma unroll
        for (int k = 0; k < 16; ++k) {
            int c = part + k * 16;
            acc += zr[c] * W4[c * 10 + j];
        }
#pragma unroll
        for (int off = 8; off; off >>= 1) acc += __shfl_down(acc, off);
        if (part == 0) out[(size_t)g * 10 + j] = acc + b4[j];
    }
}

// ---------------- launch ----------------

extern "C" void kernel_launch(void* const* d_in, const int* in_sizes, int n_in,
                              void* d_out, int out_size, void* d_ws, size_t ws_size,
                              hipStream_t stream) {
    const int N = in_sizes[0] / 64;
    const int E = in_sizes[1] / 2;
    const int G = out_size / 10;

    const float* x     = (const float*)d_in[0];
    const int*   ei    = (const int*)d_in[1];
    const int*   batch = (const int*)d_in[2];
    const float* W1 = (const float*)d_in[3];
    const float* g1 = (const float*)d_in[5];
    const float* be1 = (const float*)d_in[6];
    const float* W2 = (const float*)d_in[7];
    const float* g2 = (const float*)d_in[9];
    const float* be2 = (const float*)d_in[10];
    const float* W3 = (const float*)d_in[11];
    const float* b3 = (const float*)d_in[12];
    const float* g3 = (const float*)d_in[13];
    const float* be3 = (const float*)d_in[14];
    const float* W4 = (const float*)d_in[15];
    const float* b4 = (const float*)d_in[16];
    float* out = (float*)d_out;

    const int* srcp = ei;        // edge_index[0]
    const int* dstp = ei + E;    // edge_index[1]

    // workspace layout
    char* p = (char*)d_ws;
    auto alloc = [&](size_t bytes) {
        void* r = (void*)p;
        p += (bytes + 255) & ~(size_t)255;
        return r;
    };
    unsigned short* A16 = (unsigned short*)alloc((size_t)N * 128 * 2);
    unsigned short* h16 = (unsigned short*)alloc((size_t)N * 128 * 2);   // gemm out bf16
    char* R3  = (char*)alloc((size_t)N * 128 * 4);   // c16 | y16
    int* csr      = (int*)alloc((size_t)E * 4);
    unsigned* part = (unsigned*)alloc((size_t)E * 4);
    int* rowptr = (int*)alloc((size_t)(N + 1) * 4);
    float* dinv = (float*)alloc((size_t)N * 4);
    int* hist   = (int*)alloc((size_t)256 * PB * 4);
    int* offs   = (int*)alloc((size_t)256 * PB * 4);
    int* bsums  = (int*)alloc(64 * 4);
    uint4* w1p  = (uint4*)alloc((size_t)64 * 128 * 2);
    uint4* w2p  = (uint4*)alloc((size_t)128 * 128 * 2);
    int* gstart = (int*)alloc((size_t)(G + 1) * 4);
    float* pooled = (float*)alloc((size_t)G * 128 * 4);
    float* z      = (float*)alloc((size_t)G * 256 * 4);
    double* st    = (double*)alloc(1024 * 8);
    (void)ws_size; (void)n_in;

    unsigned short* c16 = (unsigned short*)R3;                         // [N*128] bf16
    unsigned short* y16 = (unsigned short*)(R3 + (size_t)N * 128 * 2); // [N*64] bf16

    double* stA = st;
    double* stB = st + 256;
    double* stC = st + 512;

    const int nb = (N + 255) / 256;
    const int NB = (N + 255) >> 8;
    const int cpb = (((E + PB - 1) / PB) + 3) & ~3;
    const int n2 = NB * PB;
    const int nch2 = (n2 + 1023) / 1024;
    const int aggblocks = (N + 7) / 8;   // 4 waves/block, 2 nodes/wave

    // fused setup: wpack W1 (4) | wpack W2 (8) | st-zero (1) | bounds (nb) | hist (PB)
    setup_kernel<<<13 + nb + PB, 256, 0, stream>>>(W1, w1p, W2, w2p, st, batch, gstart,
                                                   dstp, hist, N, G, E, cpb, NB, nb);
    scan1_kernel<<<nch2, 1024, 0, stream>>>(hist, offs, bsums, n2);
    scatter_kernel<<<PB, 256, 0, stream>>>(srcp, dstp, offs, bsums, part, E, cpb, NB, nch2);

    // count + rowptr + dinv + csr fill + prescale, one block per bucket
    bucket_build<<<NB, 256, 0, stream>>>(part, offs, bsums, rowptr, dinv, csr, x, y16,
                                         E, N, NB, nch2);

    // Layer 1
    agg64_bf<<<aggblocks, 256, 0, stream>>>(y16, rowptr, csr, dinv, A16, N);
    mfma_gemm<64><<<(N + 63) / 64, 256, 0, stream>>>(A16, w1p, h16, stA, N);
    normrelu_bf<<<(N * 16 + 255) / 256, 256, 0, stream>>>(h16, stA, g1, be1, dinv, c16, N);

    // Layer 2
    agg128_bf<<<aggblocks, 256, 0, stream>>>(c16, rowptr, csr, dinv, A16, N);
    mfma_gemm<128><<<(N + 63) / 64, 256, 0, stream>>>(A16, w2p, h16, stB, N);

    // Pool (BN+ReLU fused, inline BN params)
    pool_bn_kernel<<<G, 128, 0, stream>>>(h16, stB, g2, be2, gstart, pooled, N);

    // Head (gemm + stats fused; BN inline in head)
    gemm_bias_stats<128><<<dim3((G + 31) / 32, 2), 256, 0, stream>>>(pooled, W3, b3, z, stC, G, 256);
    head_kernel<<<G, 256, 0, stream>>>(z, stC, g3, be3, W4, b4, out, G);
}

// Round 12
// 240.298 us; speedup vs baseline: 2.0190x; 1.0125x over previous
//
#include <hip/hip_runtime.h>
#include <hip/hip_bf16.h>

#define BN_EPS 1e-5
#define PB 256   // partition blocks for edge binning

typedef __attribute__((ext_vector_type(8))) short short8;
typedef __attribute__((ext_vector_type(4))) float floatx4;

// ---------------- bf16 helpers ----------------

__device__ __forceinline__ unsigned short f2bf(float f) {
    union { float f; unsigned u; } v; v.f = f;
    unsigned r = v.u + 0x7FFF + ((v.u >> 16) & 1);   // RNE
    return (unsigned short)(r >> 16);
}
__device__ __forceinline__ float bf2f(unsigned short h) {
    union { unsigned u; float f; } v; v.u = ((unsigned)h) << 16;
    return v.f;
}
__device__ __forceinline__ float lo16(unsigned u) { return bf2f((unsigned short)(u & 0xffff)); }
__device__ __forceinline__ float hi16(unsigned u) { return bf2f((unsigned short)(u >> 16)); }

// ---------------- fused setup: wpack(W1) | wpack(W2) | st-zero | bounds | hist ----------------

__device__ __forceinline__ void wpack_body(const float* __restrict__ W, uint4* __restrict__ Wp,
                                           int K, int i) {
    if (i >= K * 16) return;
    int c = i & 127;
    int kb = i >> 7;
    unsigned short h[8];
#pragma unroll
    for (int j = 0; j < 8; ++j) h[j] = f2bf(W[(size_t)(kb * 8 + j) * 128 + c]);
    uint4 o;
    o.x = (unsigned)h[0] | ((unsigned)h[1] << 16);
    o.y = (unsigned)h[2] | ((unsigned)h[3] << 16);
    o.z = (unsigned)h[4] | ((unsigned)h[5] << 16);
    o.w = (unsigned)h[6] | ((unsigned)h[7] << 16);
    Wp[kb * 128 + c] = o;
}

__global__ void setup_kernel(const float* __restrict__ W1, uint4* __restrict__ w1p,
                             const float* __restrict__ W2, uint4* __restrict__ w2p,
                             double* __restrict__ st,
                             const int* __restrict__ batch, int* __restrict__ gstart,
                             const int* __restrict__ dst, int* __restrict__ hist,
                             int N, int G, int E, int cpb, int NB, int nb) {
    __shared__ int h[256];
    int t = threadIdx.x;
    int b = blockIdx.x;
    if (b < 4) {                         // wpack W1 (K=64, 1024 elems)
        wpack_body(W1, w1p, 64, b * 256 + t);
    } else if (b < 12) {                 // wpack W2 (K=128, 2048 elems)
        wpack_body(W2, w2p, 128, (b - 4) * 256 + t);
    } else if (b == 12) {                // zero stats accumulators (1024 doubles)
        st[t] = 0.0;
        st[256 + t] = 0.0;
        st[512 + t] = 0.0;
        st[768 + t] = 0.0;
    } else if (b < 13 + nb) {            // bounds
        int i = (b - 13) * 256 + t;
        if (i < N) {
            int bi = batch[i];
            int bp = (i == 0) ? -1 : batch[i - 1];
            for (int g = bp + 1; g <= bi; ++g) gstart[g] = i;
            if (i == N - 1) {
                for (int g = bi + 1; g <= G; ++g) gstart[g] = N;
            }
        }
    } else {                             // hist
        int blk = b - 13 - nb;           // 0..PB-1
        if (t < NB) h[t] = 0;
        __syncthreads();
        int base = blk * cpb;
        int end = base + cpb; if (end > E) end = E;
        int e = base + t * 4;
        for (; e + 3 < end; e += 1024) {
            int4 d = *(const int4*)(dst + e);
            atomicAdd(&h[d.x >> 8], 1);
            atomicAdd(&h[d.y >> 8], 1);
            atomicAdd(&h[d.z >> 8], 1);
            atomicAdd(&h[d.w >> 8], 1);
        }
        for (; e < end; ++e) atomicAdd(&h[dst[e] >> 8], 1);
        __syncthreads();
        if (t < NB) hist[t * PB + blk] = h[t];
    }
}

// ---------------- scan ----------------

__global__ void scan1_kernel(const int* __restrict__ in, int* __restrict__ part,
                             int* __restrict__ bsum, int n) {
    __shared__ int s[1024];
    int t = threadIdx.x;
    int i = blockIdx.x * 1024 + t;
    int v = (i < n) ? in[i] : 0;
    s[t] = v;
    __syncthreads();
    for (int off = 1; off < 1024; off <<= 1) {
        int x = (t >= off) ? s[t - off] : 0;
        __syncthreads();
        s[t] += x;
        __syncthreads();
    }
    if (i < n) part[i] = s[t] - v;
    if (t == 1023) bsum[blockIdx.x] = s[1023];
}

// LDS inclusive scan of <=64 bsums; all 256 threads participate (syncthreads-based)
__device__ __forceinline__ void bsum_scan(const int* __restrict__ bsum, int nch,
                                          int* __restrict__ pre, int t) {
    if (t < 64) pre[t] = (t < nch) ? bsum[t] : 0;
    __syncthreads();
    for (int off = 1; off < 64; off <<= 1) {
        int x = (t < 64 && t >= off) ? pre[t - off] : 0;
        __syncthreads();
        if (t < 64) pre[t] += x;
        __syncthreads();
    }
}

// ---------------- CSR build ----------------

// scatter with inline bsum fixup (offs holds scan1 partials)
__global__ void scatter_kernel(const int* __restrict__ src, const int* __restrict__ dst,
                               const int* __restrict__ offs, const int* __restrict__ bsum,
                               unsigned* __restrict__ part,
                               int E, int cpb, int NB, int nch) {
    __shared__ int cur[256];
    __shared__ int pre[64];
    int t = threadIdx.x;
    bsum_scan(bsum, nch, pre, t);
    if (t < NB) {
        int idx = t * PB + blockIdx.x;
        int ch = idx >> 10;
        cur[t] = offs[idx] + ((ch == 0) ? 0 : pre[ch - 1]);
    }
    __syncthreads();
    int base = blockIdx.x * cpb;
    int end = base + cpb; if (end > E) end = E;
    int e = base + t * 4;
    for (; e + 3 < end; e += 1024) {
        int4 d4 = *(const int4*)(dst + e);
        int4 s4 = *(const int4*)(src + e);
        int dd[4] = {d4.x, d4.y, d4.z, d4.w};
        int sv[4] = {s4.x, s4.y, s4.z, s4.w};
#pragma unroll
        for (int i = 0; i < 4; ++i) {
            int pos = atomicAdd(&cur[dd[i] >> 8], 1);
            part[pos] = ((unsigned)sv[i] << 8) | (unsigned)(dd[i] & 255);
        }
    }
    for (; e < end; ++e) {
        int d = dst[e];
        int pos = atomicAdd(&cur[d >> 8], 1);
        part[pos] = ((unsigned)src[e] << 8) | (unsigned)(d & 255);
    }
}

// one block per bucket: count -> exscan -> rowptr/dinv -> csr fill -> prescale.
__global__ __launch_bounds__(256) void bucket_build(
    const unsigned* __restrict__ part, const int* __restrict__ offs,
    const int* __restrict__ bsum,
    int* __restrict__ rowptr, float* __restrict__ dinv, int* __restrict__ csr,
    const float* __restrict__ x, unsigned short* __restrict__ y16,
    int E, int N, int NB, int nch) {
    __shared__ int cw[256], sc[256], cur[256];
    __shared__ float sd[256];
    __shared__ int pre[64];
    int b = blockIdx.x;
    int t = threadIdx.x;
    bsum_scan(bsum, nch, pre, t);
    cw[t] = 0;
    __syncthreads();
    int i0 = b * PB;
    int ch0 = i0 >> 10;
    int bstart = offs[i0] + ((ch0 == 0) ? 0 : pre[ch0 - 1]);
    int bend = E;
    if (b + 1 < NB) {
        int i1 = (b + 1) * PB;
        int ch1 = i1 >> 10;
        bend = offs[i1] + ((ch1 == 0) ? 0 : pre[ch1 - 1]);
    }
    for (int e = bstart + t; e < bend; e += 256)
        atomicAdd(&cw[part[e] & 255u], 1);
    __syncthreads();
    int c = cw[t];
    sc[t] = c;
    __syncthreads();
    for (int off = 1; off < 256; off <<= 1) {
        int v = (t >= off) ? sc[t - off] : 0;
        __syncthreads();
        sc[t] += v;
        __syncthreads();
    }
    int node = (b << 8) + t;
    int start = bstart + sc[t] - c;
    float d = rsqrtf((float)(c + 1));    // +1 self loop
    cur[t] = start;
    sd[t] = d;
    if (node < N) {
        rowptr[node] = start;
        dinv[node] = d;
    }
    if (b == NB - 1 && t == 255) rowptr[N] = E;
    __syncthreads();
    for (int e = bstart + t; e < bend; e += 256) {
        unsigned pr = part[e];
        int pos = atomicAdd(&cur[pr & 255u], 1);
        csr[pos] = (int)(pr >> 8);
    }
    // prescale: y16[node][0..64) = bf16(x[node][c] * dinv[node]) for this bucket
    int base = b << 8;
    int nlocal = N - base; if (nlocal > 256) nlocal = 256;
    if (nlocal <= 0) return;
    for (int idx = t; idx < nlocal * 8; idx += 256) {
        int r = idx >> 3, k = idx & 7;
        int nd = base + r;
        float dd = sd[r];
        const float4* xp = (const float4*)(x + (size_t)nd * 64 + k * 8);
        float4 a = xp[0];
        float4 bb = xp[1];
        uint4 o;
        o.x = (unsigned)f2bf(a.x * dd) | ((unsigned)f2bf(a.y * dd) << 16);
        o.y = (unsigned)f2bf(a.z * dd) | ((unsigned)f2bf(a.w * dd) << 16);
        o.z = (unsigned)f2bf(bb.x * dd) | ((unsigned)f2bf(bb.y * dd) << 16);
        o.w = (unsigned)f2bf(bb.z * dd) | ((unsigned)f2bf(bb.w * dd) << 16);
        *(uint4*)(y16 + (size_t)nd * 64 + k * 8) = o;
    }
}

// ---------------- aggregation (proven unroll-8 forms) ----------------

// 2 nodes per wave, 64 ch: half-wave per node, uint (2ch)/lane, unroll-8
__global__ __launch_bounds__(256) void agg64_bf(
    const unsigned short* __restrict__ y, const int* __restrict__ rowptr,
    const int* __restrict__ csr, const float* __restrict__ dinv,
    unsigned short* __restrict__ A16, int N) {
    int wv = (blockIdx.x * blockDim.x + threadIdx.x) >> 6;
    int lane = threadIdx.x & 63;
    int node = wv * 2 + (lane >> 5);
    if (node >= N) return;
    int cu = lane & 31;
    const unsigned* yp = (const unsigned*)y;     // 32 uints per row
    unsigned v = yp[(size_t)node * 32 + cu];
    float a0 = lo16(v), a1 = hi16(v);
    int b = rowptr[node], e = rowptr[node + 1];
    int i = b;
    for (; i + 7 < e; i += 8) {
        int s0 = csr[i], s1 = csr[i + 1], s2 = csr[i + 2], s3 = csr[i + 3];
        int s4 = csr[i + 4], s5 = csr[i + 5], s6 = csr[i + 6], s7 = csr[i + 7];
        unsigned v0 = yp[(size_t)s0 * 32 + cu];
        unsigned v1 = yp[(size_t)s1 * 32 + cu];
        unsigned v2 = yp[(size_t)s2 * 32 + cu];
        unsigned v3 = yp[(size_t)s3 * 32 + cu];
        unsigned v4 = yp[(size_t)s4 * 32 + cu];
        unsigned v5 = yp[(size_t)s5 * 32 + cu];
        unsigned v6 = yp[(size_t)s6 * 32 + cu];
        unsigned v7 = yp[(size_t)s7 * 32 + cu];
        a0 += ((lo16(v0) + lo16(v1)) + (lo16(v2) + lo16(v3)))
            + ((lo16(v4) + lo16(v5)) + (lo16(v6) + lo16(v7)));
        a1 += ((hi16(v0) + hi16(v1)) + (hi16(v2) + hi16(v3)))
            + ((hi16(v4) + hi16(v5)) + (hi16(v6) + hi16(v7)));
    }
    for (; i + 3 < e; i += 4) {
        int s0 = csr[i], s1 = csr[i + 1], s2 = csr[i + 2], s3 = csr[i + 3];
        unsigned v0 = yp[(size_t)s0 * 32 + cu];
        unsigned v1 = yp[(size_t)s1 * 32 + cu];
        unsigned v2 = yp[(size_t)s2 * 32 + cu];
        unsigned v3 = yp[(size_t)s3 * 32 + cu];
        a0 += (lo16(v0) + lo16(v1)) + (lo16(v2) + lo16(v3));
        a1 += (hi16(v0) + hi16(v1)) + (hi16(v2) + hi16(v3));
    }
    for (; i < e; ++i) {
        unsigned v0 = yp[(size_t)csr[i] * 32 + cu];
        a0 += lo16(v0);
        a1 += hi16(v0);
    }
    float d = dinv[node];
    ((unsigned*)A16)[(size_t)node * 32 + cu] =
        (unsigned)f2bf(a0 * d) | ((unsigned)f2bf(a1 * d) << 16);
}

// 2 nodes per wave, 128 ch: half-wave per node, uint2 (4ch)/lane, unroll-8
__global__ __launch_bounds__(256) void agg128_bf(
    const unsigned short* __restrict__ y, const int* __restrict__ rowptr,
    const int* __restrict__ csr, const float* __restrict__ dinv,
    unsigned short* __restrict__ A16, int N) {
    int wv = (blockIdx.x * blockDim.x + threadIdx.x) >> 6;
    int lane = threadIdx.x & 63;
    int node = wv * 2 + (lane >> 5);
    if (node >= N) return;
    int c2 = lane & 31;
    const uint2* yp = (const uint2*)y;           // 32 uint2 per row
    uint2 v = yp[(size_t)node * 32 + c2];
    float a0 = lo16(v.x), a1 = hi16(v.x), a2 = lo16(v.y), a3 = hi16(v.y);
    int b = rowptr[node], e = rowptr[node + 1];
    int i = b;
    for (; i + 7 < e; i += 8) {
        int s0 = csr[i], s1 = csr[i + 1], s2 = csr[i + 2], s3 = csr[i + 3];
        int s4 = csr[i + 4], s5 = csr[i + 5], s6 = csr[i + 6], s7 = csr[i + 7];
        uint2 v0 = yp[(size_t)s0 * 32 + c2];
        uint2 v1 = yp[(size_t)s1 * 32 + c2];
        uint2 v2 = yp[(size_t)s2 * 32 + c2];
        uint2 v3 = yp[(size_t)s3 * 32 + c2];
        uint2 v4 = yp[(size_t)s4 * 32 + c2];
        uint2 v5 = yp[(size_t)s5 * 32 + c2];
        uint2 v6 = yp[(size_t)s6 * 32 + c2];
        uint2 v7 = yp[(size_t)s7 * 32 + c2];
        a0 += ((lo16(v0.x) + lo16(v1.x)) + (lo16(v2.x) + lo16(v3.x)))
            + ((lo16(v4.x) + lo16(v5.x)) + (lo16(v6.x) + lo16(v7.x)));
        a1 += ((hi16(v0.x) + hi16(v1.x)) + (hi16(v2.x) + hi16(v3.x)))
            + ((hi16(v4.x) + hi16(v5.x)) + (hi16(v6.x) + hi16(v7.x)));
        a2 += ((lo16(v0.y) + lo16(v1.y)) + (lo16(v2.y) + lo16(v3.y)))
            + ((lo16(v4.y) + lo16(v5.y)) + (lo16(v6.y) + lo16(v7.y)));
        a3 += ((hi16(v0.y) + hi16(v1.y)) + (hi16(v2.y) + hi16(v3.y)))
            + ((hi16(v4.y) + hi16(v5.y)) + (hi16(v6.y) + hi16(v7.y)));
    }
    for (; i + 3 < e; i += 4) {
        int s0 = csr[i], s1 = csr[i + 1], s2 = csr[i + 2], s3 = csr[i + 3];
        uint2 v0 = yp[(size_t)s0 * 32 + c2];
        uint2 v1 = yp[(size_t)s1 * 32 + c2];
        uint2 v2 = yp[(size_t)s2 * 32 + c2];
        uint2 v3 = yp[(size_t)s3 * 32 + c2];
        a0 += (lo16(v0.x) + lo16(v1.x)) + (lo16(v2.x) + lo16(v3.x));
        a1 += (hi16(v0.x) + hi16(v1.x)) + (hi16(v2.x) + hi16(v3.x));
        a2 += (lo16(v0.y) + lo16(v1.y)) + (lo16(v2.y) + lo16(v3.y));
        a3 += (hi16(v0.y) + hi16(v1.y)) + (hi16(v2.y) + hi16(v3.y));
    }
    for (; i < e; ++i) {
        uint2 v0 = yp[(size_t)csr[i] * 32 + c2];
        a0 += lo16(v0.x);
        a1 += hi16(v0.x);
        a2 += lo16(v0.y);
        a3 += hi16(v0.y);
    }
    float d = dinv[node];
    uint2 o;
    o.x = (unsigned)f2bf(a0 * d) | ((unsigned)f2bf(a1 * d) << 16);
    o.y = (unsigned)f2bf(a2 * d) | ((unsigned)f2bf(a3 * d) << 16);
    ((uint2*)A16)[(size_t)node * 32 + c2] = o;
}

// ---------------- GEMMs + epilogue ----------------

// MFMA GEMM + fused column stats; output stored bf16 (stats from fp32 acc)
template <int K>
__global__ __launch_bounds__(256) void mfma_gemm(const unsigned short* __restrict__ A16,
                                                 const uint4* __restrict__ Bp,
                                                 unsigned short* __restrict__ out16,
                                                 double* __restrict__ st, int N) {
    constexpr int KS = K / 32;
    __shared__ float cs[128], cs2[128];
    if (threadIdx.x < 128) { cs[threadIdx.x] = 0.f; cs2[threadIdx.x] = 0.f; }
    int w = threadIdx.x >> 6, l = threadIdx.x & 63;
    int cl = l & 15, sub = l >> 4;
    int r0 = blockIdx.x * 64 + w * 16;
    int ra = r0 + cl; if (ra > N - 1) ra = N - 1;

    short8 a[KS];
    const unsigned short* ap = A16 + (size_t)ra * K + sub * 8;
#pragma unroll
    for (int ks = 0; ks < KS; ++ks) a[ks] = *(const short8*)(ap + ks * 32);

    floatx4 acc[8] = {};
#pragma unroll
    for (int cb = 0; cb < 8; ++cb) {
#pragma unroll
        for (int ks = 0; ks < KS; ++ks) {
            short8 b = *(const short8*)&Bp[(ks * 4 + sub) * 128 + cb * 16 + cl];
            acc[cb] = __builtin_amdgcn_mfma_f32_16x16x32_bf16(a[ks], b, acc[cb], 0, 0, 0);
        }
    }
    __syncthreads();   // cs/cs2 init visible
#pragma unroll
    for (int cb = 0; cb < 8; ++cb) {
        float s = 0.f, s2 = 0.f;
#pragma unroll
        for (int j = 0; j < 4; ++j) {
            int row = r0 + sub * 4 + j;
            if (row < N) {
                float val = acc[cb][j];
                out16[(size_t)row * 128 + cb * 16 + cl] = f2bf(val);
                s += val;
                s2 += val * val;
            }
        }
        atomicAdd(&cs[cb * 16 + cl], s);
        atomicAdd(&cs2[cb * 16 + cl], s2);
    }
    __syncthreads();
    if (threadIdx.x < 128) {
        atomicAdd(&st[threadIdx.x], (double)cs[threadIdx.x]);
        atomicAdd(&st[128 + threadIdx.x], (double)cs2[threadIdx.x]);
    }
}

// out16 = bf16(relu(h*sc+sh) * dinv[row]) from bf16 h; BN params computed in LDS from st
__global__ __launch_bounds__(256) void normrelu_bf(
    const unsigned short* __restrict__ h16, const double* __restrict__ st,
    const float* __restrict__ gamma, const float* __restrict__ beta,
    const float* __restrict__ dinv, unsigned short* __restrict__ out, int N) {
    __shared__ float2 ssl[128];
    if (threadIdx.x < 128) {
        int c = threadIdx.x;
        double mean = st[c] / N;
        double var = st[128 + c] / N - mean * mean;
        float sc = (float)((double)gamma[c] / sqrt(var + BN_EPS));
        float sh = beta[c] - (float)mean * sc;
        ssl[c] = make_float2(sc, sh);
    }
    __syncthreads();
    int t = blockIdx.x * blockDim.x + threadIdx.x;
    int total = N * 16;
    if (t >= total) return;
    int r = t >> 4;
    int j = (t & 15) << 3;
    float d = dinv[r];
    uint4 hv = ((const uint4*)h16)[t];
    float2 s0 = ssl[j], s1 = ssl[j + 1], s2 = ssl[j + 2], s3 = ssl[j + 3];
    float2 s4 = ssl[j + 4], s5 = ssl[j + 5], s6 = ssl[j + 6], s7 = ssl[j + 7];
    float v0 = fmaxf(lo16(hv.x) * s0.x + s0.y, 0.f) * d;
    float v1 = fmaxf(hi16(hv.x) * s1.x + s1.y, 0.f) * d;
    float v2 = fmaxf(lo16(hv.y) * s2.x + s2.y, 0.f) * d;
    float v3 = fmaxf(hi16(hv.y) * s3.x + s3.y, 0.f) * d;
    float v4 = fmaxf(lo16(hv.z) * s4.x + s4.y, 0.f) * d;
    float v5 = fmaxf(hi16(hv.z) * s5.x + s5.y, 0.f) * d;
    float v6 = fmaxf(lo16(hv.w) * s6.x + s6.y, 0.f) * d;
    float v7 = fmaxf(hi16(hv.w) * s7.x + s7.y, 0.f) * d;
    uint4 o;
    o.x = (unsigned)f2bf(v0) | ((unsigned)f2bf(v1) << 16);
    o.y = (unsigned)f2bf(v2) | ((unsigned)f2bf(v3) << 16);
    o.z = (unsigned)f2bf(v4) | ((unsigned)f2bf(v5) << 16);
    o.w = (unsigned)f2bf(v6) | ((unsigned)f2bf(v7) << 16);
    ((uint4*)out)[t] = o;
}

// per-graph mean of relu(bn(h16)); BN params inline from st (one col per thread)
__global__ void pool_bn_kernel(const unsigned short* __restrict__ h16,
                               const double* __restrict__ st,
                               const float* __restrict__ gamma, const float* __restrict__ beta,
                               const int* __restrict__ gstart, float* __restrict__ pooled,
                               int N) {
    int g = blockIdx.x;
    int c = threadIdx.x;
    double mean = st[c] / N;
    double var = st[128 + c] / N - mean * mean;
    float sc = (float)((double)gamma[c] / sqrt(var + BN_EPS));
    float sh = beta[c] - (float)mean * sc;
    int b = gstart[g], e = gstart[g + 1];
    float acc = 0.f;
    int r = b;
    for (; r + 1 < e; r += 2) {
        float v0 = bf2f(h16[(size_t)r * 128 + c]);
        float v1 = bf2f(h16[(size_t)(r + 1) * 128 + c]);
        acc += fmaxf(v0 * sc + sh, 0.f) + fmaxf(v1 * sc + sh, 0.f);
    }
    if (r < e) acc += fmaxf(bf2f(h16[(size_t)r * 128 + c]) * sc + sh, 0.f);
    pooled[(size_t)g * 128 + c] = acc / fmaxf((float)(e - b), 1.0f);
}

// head gemm (fp32) + fused column stats
template <int K>
__global__ __launch_bounds__(256) void gemm_bias_stats(const float* __restrict__ A,
                                                       const float* __restrict__ W,
                                                       const float* __restrict__ bias,
                                                       float* __restrict__ out,
                                                       double* __restrict__ st,
                                                       int N, int C) {
    __shared__ float Wl[K * 128];
    __shared__ float cs[128], cs2[128];
    if (threadIdx.x < 128) { cs[threadIdx.x] = 0.f; cs2[threadIdx.x] = 0.f; }
    const int ct = blockIdx.y << 7;
    for (int idx = threadIdx.x; idx < K * 128; idx += 256) {
        int kk = idx >> 7, cc = idx & 127;
        Wl[idx] = W[(size_t)kk * C + ct + cc];
    }
    __syncthreads();
    const int cq = (threadIdx.x & 31) << 2;
    const int rg = threadIdx.x >> 5;
    const int r0 = blockIdx.x * 32 + (rg << 2);

    const float* Ap[4];
#pragma unroll
    for (int i = 0; i < 4; ++i) {
        int r = r0 + i;
        Ap[i] = A + (size_t)(r < N ? r : 0) * K;
    }
    float acc[4][4] = {};
#pragma unroll 4
    for (int k = 0; k < K; ++k) {
        float a0 = Ap[0][k];
        float a1 = Ap[1][k];
        float a2 = Ap[2][k];
        float a3 = Ap[3][k];
        float4 w = *(const float4*)&Wl[k * 128 + cq];
        acc[0][0] += a0 * w.x; acc[0][1] += a0 * w.y; acc[0][2] += a0 * w.z; acc[0][3] += a0 * w.w;
        acc[1][0] += a1 * w.x; acc[1][1] += a1 * w.y; acc[1][2] += a1 * w.z; acc[1][3] += a1 * w.w;
        acc[2][0] += a2 * w.x; acc[2][1] += a2 * w.y; acc[2][2] += a2 * w.z; acc[2][3] += a2 * w.w;
        acc[3][0] += a3 * w.x; acc[3][1] += a3 * w.y; acc[3][2] += a3 * w.z; acc[3][3] += a3 * w.w;
    }
    float4 bv = *(const float4*)&bias[ct + cq];
    float s[4] = {}, s2[4] = {};
#pragma unroll
    for (int i = 0; i < 4; ++i) {
        int r = r0 + i;
        if (r < N) {
            float o0 = acc[i][0] + bv.x, o1 = acc[i][1] + bv.y;
            float o2 = acc[i][2] + bv.z, o3 = acc[i][3] + bv.w;
            *(float4*)&out[(size_t)r * C + ct + cq] = make_float4(o0, o1, o2, o3);
            s[0] += o0; s2[0] += o0 * o0;
            s[1] += o1; s2[1] += o1 * o1;
            s[2] += o2; s2[2] += o2 * o2;
            s[3] += o3; s2[3] += o3 * o3;
        }
    }
#pragma unroll
    for (int jj = 0; jj < 4; ++jj) {
        atomicAdd(&cs[cq + jj], s[jj]);
        atomicAdd(&cs2[cq + jj], s2[jj]);
    }
    __syncthreads();
    if (threadIdx.x < 128) {
        atomicAdd(&st[ct + threadIdx.x], (double)cs[threadIdx.x]);
        atomicAdd(&st[C + ct + threadIdx.x], (double)cs2[threadIdx.x]);
    }
}

// final: out[g][j] = sum_c relu(bn(z))[g][c] * W4[c][j] + b4[j]; BN inline from st
__global__ void head_kernel(const float* __restrict__ z, const double* __restrict__ st,
                            const float* __restrict__ gamma, const float* __restrict__ beta,
                            const float* __restrict__ W4, const float* __restrict__ b4,
                            float* __restrict__ out, int G) {
    __shared__ float zr[256];
    int g = blockIdx.x;
    int t = threadIdx.x;
    double mean = st[t] / G;
    double var = st[256 + t] / G - mean * mean;
    float sc = (float)((double)gamma[t] / sqrt(var + BN_EPS));
    float sh = beta[t] - (float)mean * sc;
    float v = z[(size_t)g * 256 + t];
    zr[t] = fmaxf(v * sc + sh, 0.f);
    __syncthreads();
    int j = t >> 4;
    int part = t & 15;
    if (j < 10) {
        float acc = 0.f;
#pragma unroll
        for (int k = 0; k < 16; ++k) {
            int c = part + k * 16;
            acc += zr[c] * W4[c * 10 + j];
        }
#pragma unroll
        for (int off = 8; off; off >>= 1) acc += __shfl_down(acc, off);
        if (part == 0) out[(size_t)g * 10 + j] = acc + b4[j];
    }
}

// ---------------- launch ----------------

extern "C" void kernel_launch(void* const* d_in, const int* in_sizes, int n_in,
                              void* d_out, int out_size, void* d_ws, size_t ws_size,
                              hipStream_t stream) {
    const int N = in_sizes[0] / 64;
    const int E = in_sizes[1] / 2;
    const int G = out_size / 10;

    const float* x     = (const float*)d_in[0];
    const int*   ei    = (const int*)d_in[1];
    const int*   batch = (const int*)d_in[2];
    const float* W1 = (const float*)d_in[3];
    const float* g1 = (const float*)d_in[5];
    const float* be1 = (const float*)d_in[6];
    const float* W2 = (const float*)d_in[7];
    const float* g2 = (const float*)d_in[9];
    const float* be2 = (const float*)d_in[10];
    const float* W3 = (const float*)d_in[11];
    const float* b3 = (const float*)d_in[12];
    const float* g3 = (const float*)d_in[13];
    const float* be3 = (const float*)d_in[14];
    const float* W4 = (const float*)d_in[15];
    const float* b4 = (const float*)d_in[16];
    float* out = (float*)d_out;

    const int* srcp = ei;        // edge_index[0]
    const int* dstp = ei + E;    // edge_index[1]

    // workspace layout
    char* p = (char*)d_ws;
    auto alloc = [&](size_t bytes) {
        void* r = (void*)p;
        p += (bytes + 255) & ~(size_t)255;
        return r;
    };
    unsigned short* A16 = (unsigned short*)alloc((size_t)N * 128 * 2);
    unsigned short* h16 = (unsigned short*)alloc((size_t)N * 128 * 2);   // gemm out bf16
    char* R3  = (char*)alloc((size_t)N * 128 * 4);   // c16 | y16
    int* csr      = (int*)alloc((size_t)E * 4);
    unsigned* part = (unsigned*)alloc((size_t)E * 4);
    int* rowptr = (int*)alloc((size_t)(N + 1) * 4);
    float* dinv = (float*)alloc((size_t)N * 4);
    int* hist   = (int*)alloc((size_t)256 * PB * 4);
    int* offs   = (int*)alloc((size_t)256 * PB * 4);
    int* bsums  = (int*)alloc(64 * 4);
    uint4* w1p  = (uint4*)alloc((size_t)64 * 128 * 2);
    uint4* w2p  = (uint4*)alloc((size_t)128 * 128 * 2);
    int* gstart = (int*)alloc((size_t)(G + 1) * 4);
    float* pooled = (float*)alloc((size_t)G * 128 * 4);
    float* z      = (float*)alloc((size_t)G * 256 * 4);
    double* st    = (double*)alloc(1024 * 8);
    (void)ws_size; (void)n_in;

    unsigned short* c16 = (unsigned short*)R3;                         // [N*128] bf16
    unsigned short* y16 = (unsigned short*)(R3 + (size_t)N * 128 * 2); // [N*64] bf16

    double* stA = st;
    double* stB = st + 256;
    double* stC = st + 512;

    const int nb = (N + 255) / 256;
    const int NB = (N + 255) >> 8;
    const int cpb = (((E + PB - 1) / PB) + 3) & ~3;
    const int n2 = NB * PB;
    const int nch2 = (n2 + 1023) / 1024;
    const int aggblocks = (N + 7) / 8;   // 4 waves/block, 2 nodes/wave

    // fused setup: wpack W1 (4) | wpack W2 (8) | st-zero (1) | bounds (nb) | hist (PB)
    setup_kernel<<<13 + nb + PB, 256, 0, stream>>>(W1, w1p, W2, w2p, st, batch, gstart,
                                                   dstp, hist, N, G, E, cpb, NB, nb);
    scan1_kernel<<<nch2, 1024, 0, stream>>>(hist, offs, bsums, n2);
    scatter_kernel<<<PB, 256, 0, stream>>>(srcp, dstp, offs, bsums, part, E, cpb, NB, nch2);

    // count + rowptr + dinv + csr fill + prescale, one block per bucket
    bucket_build<<<NB, 256, 0, stream>>>(part, offs, bsums, rowptr, dinv, csr, x, y16,
                                         E, N, NB, nch2);

    // Layer 1
    agg64_bf<<<aggblocks, 256, 0, stream>>>(y16, rowptr, csr, dinv, A16, N);
    mfma_gemm<64><<<(N + 63) / 64, 256, 0, stream>>>(A16, w1p, h16, stA, N);
    normrelu_bf<<<(N * 16 + 255) / 256, 256, 0, stream>>>(h16, stA, g1, be1, dinv, c16, N);

    // Layer 2
    agg128_bf<<<aggblocks, 256, 0, stream>>>(c16, rowptr, csr, dinv, A16, N);
    mfma_gemm<128><<<(N + 63) / 64, 256, 0, stream>>>(A16, w2p, h16, stB, N);

    // Pool (BN+ReLU fused, inline BN params)
    pool_bn_kernel<<<G, 128, 0, stream>>>(h16, stB, g2, be2, gstart, pooled, N);

    // Head (gemm + stats fused; BN inline in head)
    gemm_bias_stats<128><<<dim3((G + 31) / 32, 2), 256, 0, stream>>>(pooled, W3, b3, z, stC, G, 256);
    head_kernel<<<G, 256, 0, stream>>>(z, stC, g3, be3, W4, b4, out, G);
}